// Round 1
// baseline (6871.520 us; speedup 1.0000x reference)
//
#include <hip/hip_runtime.h>
#include <hip/hip_bf16.h>
#include <cstdint>

#define BIGF 1e30f
constexpr int LB   = 4096;           // L = H*W
constexpr int NB   = 8;              // batch
constexpr int MROWS = NB * LB;       // 32768 pixel rows
constexpr int LSP  = 4104;           // level-start stride per batch

// ---------------- helpers ----------------
__device__ __forceinline__ float warp_sum(float v) {
#pragma unroll
  for (int off = 32; off; off >>= 1) v += __shfl_xor(v, off);
  return v;
}

__device__ __forceinline__ float block_sum256(float v) {
  __shared__ float sm[4];
  v = warp_sum(v);
  __syncthreads();                       // protect sm from previous call
  if ((threadIdx.x & 63) == 0) sm[threadIdx.x >> 6] = v;
  __syncthreads();
  return sm[0] + sm[1] + sm[2] + sm[3];
}

// ---------------- LayerNorm over last dim 128 ----------------
__global__ __launch_bounds__(256) void ln128_kernel(
    const float* __restrict__ X, const float* __restrict__ g,
    const float* __restrict__ bb, float* __restrict__ O, float eps) {
  int wave = threadIdx.x >> 6, lane = threadIdx.x & 63;
  int row = blockIdx.x * 4 + wave;
  const float* xr = X + (size_t)row * 128;
  float x0 = xr[lane], x1 = xr[lane + 64];
  float mu = warp_sum(x0 + x1) * (1.0f / 128.0f);
  float d0 = x0 - mu, d1 = x1 - mu;
  float var = warp_sum(d0 * d0 + d1 * d1) * (1.0f / 128.0f);
  float s = 1.0f / sqrtf(var + eps);
  float* orow = O + (size_t)row * 128;
  orow[lane]      = d0 * s * g[lane]      + bb[lane];
  orow[lane + 64] = d1 * s * g[lane + 64] + bb[lane + 64];
}

// ---------------- generic f32 GEMM: C = A[M,K] @ W[N,K]^T, fused epilogues ----------------
// EPI 1: split+silu (N=512): n<256 -> C[m*256+n], n>=256 -> C2[m*256+n-256]=silu
// EPI 2: C = acc + addsrc               (residual add)
// EPI 3: C = gelu(acc + bias)           (tanh approx)
// EPI 4: C = acc + bias + addsrc        (final output)
template<int EPI>
__global__ __launch_bounds__(256) void gemm_kernel(
    const float* __restrict__ A, const float* __restrict__ W,
    float* __restrict__ C, float* __restrict__ C2,
    const float* __restrict__ bias, const float* __restrict__ addsrc,
    int M, int N, int K) {
  __shared__ float As[32][68];
  __shared__ float Bs[32][68];
  int t = threadIdx.x;
  int tx = t & 15, ty = t >> 4;
  int bm = blockIdx.y * 64, bn = blockIdx.x * 64;
  float acc[4][4] = {};
  for (int k0 = 0; k0 < K; k0 += 32) {
#pragma unroll
    for (int hh = 0; hh < 2; ++hh) {
      int q = t + hh * 256;
      int r = q >> 3, kc = q & 7;
      float4 a4 = reinterpret_cast<const float4*>(A + (size_t)(bm + r) * K + k0)[kc];
      float4 b4 = reinterpret_cast<const float4*>(W + (size_t)(bn + r) * K + k0)[kc];
      As[kc * 4 + 0][r] = a4.x; As[kc * 4 + 1][r] = a4.y;
      As[kc * 4 + 2][r] = a4.z; As[kc * 4 + 3][r] = a4.w;
      Bs[kc * 4 + 0][r] = b4.x; Bs[kc * 4 + 1][r] = b4.y;
      Bs[kc * 4 + 2][r] = b4.z; Bs[kc * 4 + 3][r] = b4.w;
    }
    __syncthreads();
#pragma unroll
    for (int kk = 0; kk < 32; ++kk) {
      float4 av = *reinterpret_cast<const float4*>(&As[kk][ty * 4]);
      float4 bv = *reinterpret_cast<const float4*>(&Bs[kk][tx * 4]);
      float aa[4] = {av.x, av.y, av.z, av.w};
      float bbv[4] = {bv.x, bv.y, bv.z, bv.w};
#pragma unroll
      for (int i = 0; i < 4; ++i)
#pragma unroll
        for (int j = 0; j < 4; ++j) acc[i][j] += aa[i] * bbv[j];
    }
    __syncthreads();
  }
#pragma unroll
  for (int i = 0; i < 4; ++i) {
    int m = bm + ty * 4 + i;
#pragma unroll
    for (int j = 0; j < 4; ++j) {
      int n = bn + tx * 4 + j;
      float v = acc[i][j];
      if (EPI == 1) {
        if (n < 256) C[(size_t)m * 256 + n] = v;
        else C2[(size_t)m * 256 + (n - 256)] = v / (1.0f + expf(-v));
      } else if (EPI == 2) {
        C[(size_t)m * N + n] = v + addsrc[(size_t)m * N + n];
      } else if (EPI == 3) {
        float u = v + bias[n];
        C[(size_t)m * N + n] =
            0.5f * u * (1.0f + tanhf(0.7978845608028654f * (u + 0.044715f * u * u * u)));
      } else if (EPI == 4) {
        C[(size_t)m * N + n] = v + bias[n] + addsrc[(size_t)m * N + n];
      }
    }
  }
}

// ---------------- depthwise conv3x3 + silu + x_dbl/dts/deltaA/feat ----------------
__global__ __launch_bounds__(256) void convfeat_kernel(
    const float* __restrict__ xcpre, const float* __restrict__ cw,
    const float* __restrict__ xw, const float* __restrict__ dtw,
    const float* __restrict__ dtb, const float* __restrict__ alogs,
    float* __restrict__ xs, float* __restrict__ dA, float* __restrict__ feat,
    float* __restrict__ Cs, float* __restrict__ ssq) {
  int m = blockIdx.x;
  int d = threadIdx.x;
  int l = m & (LB - 1), b = m >> 12;
  int r = l >> 6, c = l & 63;
  float acc = 0.f;
#pragma unroll
  for (int ky = 0; ky < 3; ++ky) {
    int rr = r + ky - 1;
    if (rr < 0 || rr > 63) continue;
#pragma unroll
    for (int kx = 0; kx < 3; ++kx) {
      int cc = c + kx - 1;
      if (cc < 0 || cc > 63) continue;
      int ml = (b << 12) + (rr << 6) + cc;
      acc += xcpre[(size_t)ml * 256 + d] * cw[d * 9 + ky * 3 + kx];
    }
  }
  float xv = acc / (1.0f + expf(-acc));        // silu
  xs[(size_t)m * 256 + d] = xv;
  float p[11];
#pragma unroll
  for (int i = 0; i < 10; ++i) p[i] = xv * xw[i * 256 + d];
  p[10] = xv * xv;
  __shared__ float sm[4][11];
#pragma unroll
  for (int i = 0; i < 11; ++i) p[i] = warp_sum(p[i]);
  int wv = d >> 6;
  if ((d & 63) == 0) {
    for (int i = 0; i < 11; ++i) sm[wv][i] = p[i];
  }
  __syncthreads();
  float red[11];
#pragma unroll
  for (int i = 0; i < 11; ++i) red[i] = sm[0][i] + sm[1][i] + sm[2][i] + sm[3][i];
  float xdt = dtb[d];
#pragma unroll
  for (int rr2 = 0; rr2 < 8; ++rr2) xdt += red[rr2] * dtw[d * 8 + rr2];
  float sp = fmaxf(xdt, 0.f) + log1pf(expf(-fabsf(xdt)));   // softplus
  float As_ = -expf(alogs[d]);
  dA[(size_t)m * 256 + d] = expf(sp * As_);
  feat[(size_t)m * 256 + d] = sp * red[8] * xv;
  if (d == 0) { Cs[m] = red[9]; ssq[m] = red[10]; }
}

// ---------------- grid edge weights wr/wd ----------------
__global__ __launch_bounds__(256) void gridw_kernel(
    const float* __restrict__ xs, const float* __restrict__ ssq,
    float* __restrict__ wrg, float* __restrict__ wdg) {
  int m = blockIdx.x, d = threadIdx.x;
  int l = m & (LB - 1);
  int r = l >> 6, c = l & 63;
  float a = xs[(size_t)m * 256 + d];
  float br = (c < 63) ? xs[(size_t)(m + 1) * 256 + d] : 0.f;
  float bd = (r < 63) ? xs[(size_t)(m + 64) * 256 + d] : 0.f;
  float s1 = warp_sum(a * br);
  float s2 = warp_sum(a * bd);
  __shared__ float sm[4][2];
  int wv = d >> 6;
  if ((d & 63) == 0) { sm[wv][0] = s1; sm[wv][1] = s2; }
  __syncthreads();
  if (d == 0) {
    float dotr = sm[0][0] + sm[1][0] + sm[2][0] + sm[3][0];
    float dotd = sm[0][1] + sm[1][1] + sm[2][1] + sm[3][1];
    float na = sqrtf(ssq[m]);
    float wrv = BIGF, wdv = BIGF;
    if (c < 63) { float den = fmaxf(na * sqrtf(ssq[m + 1]), 1e-8f);  wrv = expf(-(dotr / den)); }
    if (r < 63) { float den = fmaxf(na * sqrtf(ssq[m + 64]), 1e-8f); wdv = expf(-(dotd / den)); }
    wrg[m] = wrv; wdg[m] = wdv;
  }
}

// ---------------- Prim MST (exact reference semantics) + level build ----------------
// One wave per batch. Lane k owns grid row k's min (val,idx) packed in u64.
__global__ __launch_bounds__(64) void mst_kernel(
    const float* __restrict__ wr_g, const float* __restrict__ wd_g,
    int* __restrict__ par_g, int* __restrict__ levn_g, int* __restrict__ levs_g) {
  __shared__ float wrs[4096];
  __shared__ float wds[4096];
  __shared__ float dist[4096];
  __shared__ int   pd[4096];     // par (low 12) | depth (high bits)
  int b = blockIdx.x, lane = threadIdx.x;
  const float* wrb = wr_g + b * 4096;
  const float* wdb = wd_g + b * 4096;
  for (int i = 0; i < 64; ++i) {
    int idx = i * 64 + lane;
    wrs[idx] = wrb[idx];
    wds[idx] = wdb[idx];
    dist[idx] = BIGF;
    pd[idx] = 0;
  }
  __syncthreads();
  if (lane == 0) dist[0] = -1.0f;
  __syncthreads();
  unsigned long long segkey =
      ((unsigned long long)__float_as_uint(BIGF) << 32) | (unsigned)(lane * 64);
  for (int t = 0; t < 4096; ++t) {
    int v;
    if (t == 0) v = 0;
    else {
      unsigned long long k = segkey;
#pragma unroll
      for (int off = 32; off; off >>= 1) {
        unsigned long long o = __shfl_xor(k, off);
        if (o < k) k = o;
      }
      v = (int)(k & 0xFFFFFFFFull);
    }
    int sv = v >> 6, c = v & 63;
    int pv = pd[v] & 4095;
    int dpv = pd[pv] >> 12;
    if (lane == 0) {
      dist[v] = -BIGF;                                   // mark in-tree
      if (t > 0) pd[v] = (pd[v] & 4095) | ((dpv + 1) << 12);
    }
    // recompute owner row sv (v removed)
    int idx2 = (sv << 6) + lane;
    float d2 = dist[idx2];
    float val2 = (d2 < -2.0f) ? BIGF : d2;
    unsigned long long k2 =
        ((unsigned long long)__float_as_uint(val2) << 32) | (unsigned)idx2;
#pragma unroll
    for (int off = 32; off; off >>= 1) {
      unsigned long long o = __shfl_xor(k2, off);
      if (o < k2) k2 = o;
    }
    if (lane == sv) segkey = k2;
    // neighbor relaxations (all lanes compute redundantly)
    float w0 = wrs[v];
    float w1 = wrs[(v > 0) ? v - 1 : 0];
    float w2 = wds[v];
    float w3 = wds[(v >= 64) ? v - 64 : 0];
    int   uu[4]; float ww[4]; bool vb[4];
    uu[0] = v + 1;  ww[0] = w0; vb[0] = (c < 63);
    uu[1] = v - 1;  ww[1] = w1; vb[1] = (c > 0);
    uu[2] = v + 64; ww[2] = w2; vb[2] = (sv < 63);
    uu[3] = v - 64; ww[3] = w3; vb[3] = (sv > 0);
#pragma unroll
    for (int i = 0; i < 4; ++i) {
      int uc = uu[i]; uc = uc < 0 ? 0 : (uc > 4095 ? 4095 : uc);
      float du = dist[uc];
      bool better = vb[i] && (ww[i] < du);
      if (better && lane == i) { dist[uc] = ww[i]; pd[uc] = v; }
      int s = uc >> 6;
      if (better && lane == s) {
        unsigned long long nk =
            ((unsigned long long)__float_as_uint(ww[i]) << 32) | (unsigned)uc;
        if (nk < segkey) segkey = nk;
      }
    }
  }
  __syncthreads();
  // ----- level build -----
  int* cnt  = (int*)wrs;
  int* offs = (int*)wds;
  for (int i = 0; i < 64; ++i) cnt[i * 64 + lane] = 0;
  __syncthreads();
  int maxd = 0;
  for (int i = 0; i < 64; ++i) {
    int dp = pd[i * 64 + lane] >> 12;
    maxd = max(maxd, dp);
    atomicAdd(&cnt[dp], 1);
  }
#pragma unroll
  for (int off = 32; off; off >>= 1) maxd = max(maxd, __shfl_xor(maxd, off));
  __syncthreads();
  int s = 0;
  for (int i = 0; i < 64; ++i) {
    int idx = lane * 64 + i;
    int tv = cnt[idx];
    offs[idx] = s;
    s += tv;
  }
  int incl = s;
  for (int off = 1; off < 64; off <<= 1) {
    int nv = __shfl_up(incl, off);
    if (lane >= off) incl += nv;
  }
  int base = incl - s;
  for (int i = 0; i < 64; ++i) offs[lane * 64 + i] += base;
  __syncthreads();
  for (int idx = lane; idx <= maxd; idx += 64) levs_g[b * LSP + idx] = offs[idx];
  if (lane == 0) {
    levs_g[b * LSP + maxd + 1] = 4096;
    levs_g[b * LSP + 4098] = maxd + 1;
  }
  __syncthreads();
  for (int i = 0; i < 64; ++i) {
    int vnode = i * 64 + lane;
    int dp = pd[vnode] >> 12;
    int pos = atomicAdd(&offs[dp], 1);
    levn_g[b * 4096 + pos] = vnode;
  }
  for (int i = 0; i < 64; ++i) {
    int idx = i * 64 + lane;
    par_g[b * 4096 + idx] = pd[idx] & 4095;
  }
}

// ---------------- level-parallel tree scan (up gather + down), deterministic ----------------
__global__ __launch_bounds__(1024) void scan_kernel(
    float* __restrict__ buf, const float* __restrict__ ew,
    const int* __restrict__ par_g, const int* __restrict__ levn_g,
    const int* __restrict__ levs_g) {
  int b = blockIdx.x;
  int nd = threadIdx.x >> 8, d = threadIdx.x & 255;
  const int* levs = levs_g + b * LSP;
  const int* levn = levn_g + b * 4096;
  const int* par  = par_g + b * 4096;
  int nlev = levs[4098];
  size_t base = (size_t)b * 4096;
  // up: parents at level L gather children (level L+1): child u of p iff par[u]==p
  for (int lev = nlev - 2; lev >= 0; --lev) {
    int s = levs[lev], e = levs[lev + 1];
    for (int j = s + nd; j < e; j += 4) {
      int p = levn[j];
      int r = p >> 6, c = p & 63;
      size_t ip = (base + p) * 256 + d;
      float acc = buf[ip];
      int uu[4] = {p - 64, p - 1, p + 1, p + 64};
      bool vb[4] = {r > 0, c > 0, c < 63, r < 63};
#pragma unroll
      for (int i2 = 0; i2 < 4; ++i2) {
        if (vb[i2]) {
          int u = uu[i2];
          if (par[u] == p && u != 0) {
            size_t iu = (base + u) * 256 + d;
            acc += ew[iu] * buf[iu];
          }
        }
      }
      buf[ip] = acc;
    }
    __syncthreads();
  }
  // down: out[v] = up[v] + w*(out[p] - w*up[v]); in-place (root keeps up[root])
  for (int lev = 1; lev < nlev; ++lev) {
    int s = levs[lev], e = levs[lev + 1];
    for (int j = s + nd; j < e; j += 4) {
      int v = levn[j];
      int p = par[v];
      size_t iv = (base + v) * 256 + d;
      size_t ip = (base + p) * 256 + d;
      float w = ew[iv];
      float uv = buf[iv];
      float op = buf[ip];
      buf[iv] = uv + w * (op - w * uv);
    }
    __syncthreads();
  }
}

// ---------------- post-scan: LN(d=256) -> *Cs + ds*xs -> LN -> *z ----------------
__global__ __launch_bounds__(256) void post_kernel(
    const float* __restrict__ buf, const float* __restrict__ Cs,
    const float* __restrict__ xs, const float* __restrict__ ds,
    const float* __restrict__ hng, const float* __restrict__ hnb,
    const float* __restrict__ ong, const float* __restrict__ onb,
    float* __restrict__ zya) {
  int m = blockIdx.x, d = threadIdx.x;
  size_t idx = (size_t)m * 256 + d;
  float fo = buf[idx];
  float mu = block_sum256(fo) * (1.f / 256.f);
  float dv = fo - mu;
  float var = block_sum256(dv * dv) * (1.f / 256.f);
  float ho = dv * (1.0f / sqrtf(var + 1e-5f)) * hng[d] + hnb[d];
  float y = ho * Cs[m] + ds[d] * xs[idx];
  float mu2 = block_sum256(y) * (1.f / 256.f);
  float dy = y - mu2;
  float var2 = block_sum256(dy * dy) * (1.f / 256.f);
  float y2 = dy * (1.0f / sqrtf(var2 + 1e-5f)) * ong[d] + onb[d];
  zya[idx] = y2 * zya[idx];     // ya = y * z (in place over z)
}

// ---------------- launcher ----------------
extern "C" void kernel_launch(void* const* d_in, const int* in_sizes, int n_in,
                              void* d_out, int out_size, void* d_ws, size_t ws_size,
                              hipStream_t stream) {
  (void)in_sizes; (void)n_in; (void)out_size; (void)ws_size;
  const float* x      = (const float*)d_in[0];
  const float* ln1g   = (const float*)d_in[1];
  const float* ln1b   = (const float*)d_in[2];
  const float* ln2g   = (const float*)d_in[3];
  const float* ln2b   = (const float*)d_in[4];
  const float* w_in   = (const float*)d_in[5];
  const float* conv_w = (const float*)d_in[6];
  const float* xw     = (const float*)d_in[7];
  const float* dtw    = (const float*)d_in[8];
  const float* dtb    = (const float*)d_in[9];
  const float* alogs  = (const float*)d_in[10];
  const float* dsv    = (const float*)d_in[11];
  const float* hng    = (const float*)d_in[12];
  const float* hnb    = (const float*)d_in[13];
  const float* ong    = (const float*)d_in[14];
  const float* onb    = (const float*)d_in[15];
  const float* w_out  = (const float*)d_in[16];
  const float* mw1    = (const float*)d_in[17];
  const float* mb1    = (const float*)d_in[18];
  const float* mw2    = (const float*)d_in[19];
  const float* mb2    = (const float*)d_in[20];

  char* ws = (char*)d_ws;
  float* h    = (float*)(ws + 0);            // 16MB (h, later x1)
  float* z    = (float*)(ws + 16777216);     // 33.5MB (z, later ya in-place)
  float* xcp  = (float*)(ws + 50331648);     // 33.5MB (xc_pre, later h2)
  float* xs   = (float*)(ws + 83886080);     // 33.5MB (xs; +dA reused as 67MB mlp mid)
  float* dA   = (float*)(ws + 117440512);    // 33.5MB
  float* feat = (float*)(ws + 150994944);    // 33.5MB (feat -> up/out buf)
  float* Cs   = (float*)(ws + 184549376);
  float* ssq  = (float*)(ws + 184680448);
  float* wr   = (float*)(ws + 184811520);
  float* wd   = (float*)(ws + 184942592);
  int*   par  = (int*)(ws + 185073664);
  int*   levn = (int*)(ws + 185204736);
  int*   levs = (int*)(ws + 185335808);
  float* midg = xs;      // 67MB spans xs+dA (both dead by then)
  float* x1   = h;
  float* h2   = xcp;

  ln128_kernel<<<MROWS / 4, 256, 0, stream>>>(x, ln1g, ln1b, h, 1e-6f);
  gemm_kernel<1><<<dim3(8, 512), 256, 0, stream>>>(h, w_in, xcp, z, nullptr, nullptr,
                                                   MROWS, 512, 128);
  convfeat_kernel<<<MROWS, 256, 0, stream>>>(xcp, conv_w, xw, dtw, dtb, alogs,
                                             xs, dA, feat, Cs, ssq);
  gridw_kernel<<<MROWS, 256, 0, stream>>>(xs, ssq, wr, wd);
  mst_kernel<<<NB, 64, 0, stream>>>(wr, wd, par, levn, levs);
  scan_kernel<<<NB, 1024, 0, stream>>>(feat, dA, par, levn, levs);
  post_kernel<<<MROWS, 256, 0, stream>>>(feat, Cs, xs, dsv, hng, hnb, ong, onb, z);
  gemm_kernel<2><<<dim3(2, 512), 256, 0, stream>>>(z, w_out, x1, nullptr, nullptr, x,
                                                   MROWS, 128, 256);
  ln128_kernel<<<MROWS / 4, 256, 0, stream>>>(x1, ln2g, ln2b, h2, 1e-6f);
  gemm_kernel<3><<<dim3(8, 512), 256, 0, stream>>>(h2, mw1, midg, nullptr, mb1, nullptr,
                                                   MROWS, 512, 128);
  gemm_kernel<4><<<dim3(2, 512), 256, 0, stream>>>(midg, mw2, (float*)d_out, nullptr,
                                                   mb2, x1, MROWS, 128, 512);
}

// Round 2
// 3545.649 us; speedup vs baseline: 1.9380x; 1.9380x over previous
//
#include <hip/hip_runtime.h>
#include <hip/hip_bf16.h>
#include <cstdint>

#define BIGF 1e30f
constexpr int LB   = 4096;           // L = H*W
constexpr int NB   = 8;              // batch
constexpr int MROWS = NB * LB;       // 32768 pixel rows
constexpr int LSP  = 4104;           // level-start stride per batch

// ---------------- helpers ----------------
__device__ __forceinline__ float warp_sum(float v) {
#pragma unroll
  for (int off = 32; off; off >>= 1) v += __shfl_xor(v, off);
  return v;
}

__device__ __forceinline__ float block_sum256(float v) {
  __shared__ float sm[4];
  v = warp_sum(v);
  __syncthreads();
  if ((threadIdx.x & 63) == 0) sm[threadIdx.x >> 6] = v;
  __syncthreads();
  return sm[0] + sm[1] + sm[2] + sm[3];
}

// DPP min-reduce across 64 lanes (VALU latency, no LDS). Result broadcast via readlane.
template <int CTRL>
__device__ __forceinline__ float dppmin(float x) {
  int r = __builtin_amdgcn_update_dpp(__float_as_int(BIGF), __float_as_int(x),
                                      CTRL, 0xf, 0xf, false);
  return fminf(x, __int_as_float(r));
}
__device__ __forceinline__ float wave_min64(float x) {
  x = dppmin<0x111>(x);   // row_shr:1
  x = dppmin<0x112>(x);   // row_shr:2
  x = dppmin<0x114>(x);   // row_shr:4
  x = dppmin<0x118>(x);   // row_shr:8
  x = dppmin<0x142>(x);   // row_bcast:15
  x = dppmin<0x143>(x);   // row_bcast:31
  return __int_as_float(__builtin_amdgcn_readlane(__float_as_int(x), 63));
}

// ---------------- LayerNorm over last dim 128 ----------------
__global__ __launch_bounds__(256) void ln128_kernel(
    const float* __restrict__ X, const float* __restrict__ g,
    const float* __restrict__ bb, float* __restrict__ O, float eps) {
  int wave = threadIdx.x >> 6, lane = threadIdx.x & 63;
  int row = blockIdx.x * 4 + wave;
  const float* xr = X + (size_t)row * 128;
  float x0 = xr[lane], x1 = xr[lane + 64];
  float mu = warp_sum(x0 + x1) * (1.0f / 128.0f);
  float d0 = x0 - mu, d1 = x1 - mu;
  float var = warp_sum(d0 * d0 + d1 * d1) * (1.0f / 128.0f);
  float s = 1.0f / sqrtf(var + eps);
  float* orow = O + (size_t)row * 128;
  orow[lane]      = d0 * s * g[lane]      + bb[lane];
  orow[lane + 64] = d1 * s * g[lane + 64] + bb[lane + 64];
}

// ---------------- generic f32 GEMM: C = A[M,K] @ W[N,K]^T, fused epilogues ----------------
template<int EPI>
__global__ __launch_bounds__(256) void gemm_kernel(
    const float* __restrict__ A, const float* __restrict__ W,
    float* __restrict__ C, float* __restrict__ C2,
    const float* __restrict__ bias, const float* __restrict__ addsrc,
    int M, int N, int K) {
  __shared__ float As[32][68];
  __shared__ float Bs[32][68];
  int t = threadIdx.x;
  int tx = t & 15, ty = t >> 4;
  int bm = blockIdx.y * 64, bn = blockIdx.x * 64;
  float acc[4][4] = {};
  for (int k0 = 0; k0 < K; k0 += 32) {
#pragma unroll
    for (int hh = 0; hh < 2; ++hh) {
      int q = t + hh * 256;
      int r = q >> 3, kc = q & 7;
      float4 a4 = reinterpret_cast<const float4*>(A + (size_t)(bm + r) * K + k0)[kc];
      float4 b4 = reinterpret_cast<const float4*>(W + (size_t)(bn + r) * K + k0)[kc];
      As[kc * 4 + 0][r] = a4.x; As[kc * 4 + 1][r] = a4.y;
      As[kc * 4 + 2][r] = a4.z; As[kc * 4 + 3][r] = a4.w;
      Bs[kc * 4 + 0][r] = b4.x; Bs[kc * 4 + 1][r] = b4.y;
      Bs[kc * 4 + 2][r] = b4.z; Bs[kc * 4 + 3][r] = b4.w;
    }
    __syncthreads();
#pragma unroll
    for (int kk = 0; kk < 32; ++kk) {
      float4 av = *reinterpret_cast<const float4*>(&As[kk][ty * 4]);
      float4 bv = *reinterpret_cast<const float4*>(&Bs[kk][tx * 4]);
      float aa[4] = {av.x, av.y, av.z, av.w};
      float bbv[4] = {bv.x, bv.y, bv.z, bv.w};
#pragma unroll
      for (int i = 0; i < 4; ++i)
#pragma unroll
        for (int j = 0; j < 4; ++j) acc[i][j] += aa[i] * bbv[j];
    }
    __syncthreads();
  }
#pragma unroll
  for (int i = 0; i < 4; ++i) {
    int m = bm + ty * 4 + i;
#pragma unroll
    for (int j = 0; j < 4; ++j) {
      int n = bn + tx * 4 + j;
      float v = acc[i][j];
      if (EPI == 1) {
        if (n < 256) C[(size_t)m * 256 + n] = v;
        else C2[(size_t)m * 256 + (n - 256)] = v / (1.0f + expf(-v));
      } else if (EPI == 2) {
        C[(size_t)m * N + n] = v + addsrc[(size_t)m * N + n];
      } else if (EPI == 3) {
        float u = v + bias[n];
        C[(size_t)m * N + n] =
            0.5f * u * (1.0f + tanhf(0.7978845608028654f * (u + 0.044715f * u * u * u)));
      } else if (EPI == 4) {
        C[(size_t)m * N + n] = v + bias[n] + addsrc[(size_t)m * N + n];
      }
    }
  }
}

// ---------------- depthwise conv3x3 + silu + x_dbl/dts/deltaA/feat ----------------
__global__ __launch_bounds__(256) void convfeat_kernel(
    const float* __restrict__ xcpre, const float* __restrict__ cw,
    const float* __restrict__ xw, const float* __restrict__ dtw,
    const float* __restrict__ dtb, const float* __restrict__ alogs,
    float* __restrict__ xs, float* __restrict__ dA, float* __restrict__ feat,
    float* __restrict__ Cs, float* __restrict__ ssq) {
  int m = blockIdx.x;
  int d = threadIdx.x;
  int l = m & (LB - 1), b = m >> 12;
  int r = l >> 6, c = l & 63;
  float acc = 0.f;
#pragma unroll
  for (int ky = 0; ky < 3; ++ky) {
    int rr = r + ky - 1;
    if (rr < 0 || rr > 63) continue;
#pragma unroll
    for (int kx = 0; kx < 3; ++kx) {
      int cc = c + kx - 1;
      if (cc < 0 || cc > 63) continue;
      int ml = (b << 12) + (rr << 6) + cc;
      acc += xcpre[(size_t)ml * 256 + d] * cw[d * 9 + ky * 3 + kx];
    }
  }
  float xv = acc / (1.0f + expf(-acc));        // silu
  xs[(size_t)m * 256 + d] = xv;
  float p[11];
#pragma unroll
  for (int i = 0; i < 10; ++i) p[i] = xv * xw[i * 256 + d];
  p[10] = xv * xv;
  __shared__ float sm[4][11];
#pragma unroll
  for (int i = 0; i < 11; ++i) p[i] = warp_sum(p[i]);
  int wv = d >> 6;
  if ((d & 63) == 0) {
    for (int i = 0; i < 11; ++i) sm[wv][i] = p[i];
  }
  __syncthreads();
  float red[11];
#pragma unroll
  for (int i = 0; i < 11; ++i) red[i] = sm[0][i] + sm[1][i] + sm[2][i] + sm[3][i];
  float xdt = dtb[d];
#pragma unroll
  for (int rr2 = 0; rr2 < 8; ++rr2) xdt += red[rr2] * dtw[d * 8 + rr2];
  float sp = fmaxf(xdt, 0.f) + log1pf(expf(-fabsf(xdt)));   // softplus
  float As_ = -expf(alogs[d]);
  dA[(size_t)m * 256 + d] = expf(sp * As_);
  feat[(size_t)m * 256 + d] = sp * red[8] * xv;
  if (d == 0) { Cs[m] = red[9]; ssq[m] = red[10]; }
}

// ---------------- grid edge weights wr/wd ----------------
__global__ __launch_bounds__(256) void gridw_kernel(
    const float* __restrict__ xs, const float* __restrict__ ssq,
    float* __restrict__ wrg, float* __restrict__ wdg) {
  int m = blockIdx.x, d = threadIdx.x;
  int l = m & (LB - 1);
  int r = l >> 6, c = l & 63;
  float a = xs[(size_t)m * 256 + d];
  float br = (c < 63) ? xs[(size_t)(m + 1) * 256 + d] : 0.f;
  float bd = (r < 63) ? xs[(size_t)(m + 64) * 256 + d] : 0.f;
  float s1 = warp_sum(a * br);
  float s2 = warp_sum(a * bd);
  __shared__ float sm[4][2];
  int wv = d >> 6;
  if ((d & 63) == 0) { sm[wv][0] = s1; sm[wv][1] = s2; }
  __syncthreads();
  if (d == 0) {
    float dotr = sm[0][0] + sm[1][0] + sm[2][0] + sm[3][0];
    float dotd = sm[0][1] + sm[1][1] + sm[2][1] + sm[3][1];
    float na = sqrtf(ssq[m]);
    float wrv = BIGF, wdv = BIGF;
    if (c < 63) { float den = fmaxf(na * sqrtf(ssq[m + 1]), 1e-8f);  wrv = expf(-(dotr / den)); }
    if (r < 63) { float den = fmaxf(na * sqrtf(ssq[m + 64]), 1e-8f); wdv = expf(-(dotd / den)); }
    wrg[m] = wrv; wdg[m] = wdv;
  }
}

// ---------------- Prim MST (exact reference semantics) + depth + level build ----------------
// One wave per batch. Lane k owns grid row k's frontier min (segval, segidx).
__global__ __launch_bounds__(64) void mst_kernel(
    const float* __restrict__ wr_g, const float* __restrict__ wd_g,
    int* __restrict__ par_g, int* __restrict__ levn_g, int* __restrict__ levs_g) {
  __shared__ float wrs[4096];
  __shared__ float wds[4096];
  __shared__ float dist[4096];
  __shared__ int   par_l[4096];
  int b = blockIdx.x, lane = threadIdx.x;
  const float* wrb = wr_g + b * 4096;
  const float* wdb = wd_g + b * 4096;
  for (int i = 0; i < 64; ++i) {
    int idx = i * 64 + lane;
    wrs[idx] = wrb[idx];
    wds[idx] = wdb[idx];
    dist[idx] = BIGF;
    par_l[idx] = 0;
  }
  __syncthreads();
  float segval = BIGF;
  int   segidx = lane * 64;
  for (int t = 0; t < 4096; ++t) {
    // ---- global argmin over row minima (DPP, first-index tie-break) ----
    float m = wave_min64(segval);
    unsigned long long bm = __ballot(segval == m);
    int ml = __ffsll((unsigned long long)bm) - 1;
    int v = __builtin_amdgcn_readlane(segidx, ml);
    if (t == 0) v = 0;
    int sv = v >> 6, c = v & 63;
    if (lane == 0) dist[v] = -BIGF;          // mark in-tree (future iters)
    // ---- recompute row sv's min (v excluded via select, not the write) ----
    int idx2 = (sv << 6) + lane;
    float d2 = dist[idx2];
    float val2 = (idx2 == v || d2 < 0.f) ? BIGF : d2;
    float rm = wave_min64(val2);
    unsigned long long bm2 = __ballot(val2 == rm);
    int rl = __ffsll((unsigned long long)bm2) - 1;
    // ---- neighbor relaxations ----
    float w0 = wrs[v];
    float w1 = wrs[(v > 0) ? v - 1 : 0];
    float w2 = wds[v];
    float w3 = wds[(v >= 64) ? v - 64 : 0];
    int uc0 = (v < 4095) ? v + 1 : 4095;
    int uc1 = (v > 0) ? v - 1 : 0;
    int uc2 = (v < 4032) ? v + 64 : v;
    int uc3 = (v >= 64) ? v - 64 : 0;
    float du0 = dist[uc0], du1 = dist[uc1], du2 = dist[uc2], du3 = dist[uc3];
    bool b0 = (c < 63) && (w0 < du0);
    bool b1 = (c > 0)  && (w1 < du1);
    bool b2 = (sv < 63) && (w2 < du2);
    bool b3 = (sv > 0)  && (w3 < du3);
    if (lane == 0 && b0) { dist[uc0] = w0; par_l[uc0] = v; }
    if (lane == 1 && b1) { dist[uc1] = w1; par_l[uc1] = v; }
    if (lane == 2 && b2) { dist[uc2] = w2; par_l[uc2] = v; }
    if (lane == 3 && b3) { dist[uc3] = w3; par_l[uc3] = v; }
    // ---- fold into per-row keys ----
    if (lane == sv) {
      segval = rm; segidx = (sv << 6) + rl;
      if (b1 && (w1 < segval || (w1 == segval && uc1 < segidx))) { segval = w1; segidx = uc1; }
      if (b0 && (w0 < segval || (w0 == segval && uc0 < segidx))) { segval = w0; segidx = uc0; }
    }
    if (lane == sv + 1 && b2) {
      if (w2 < segval || (w2 == segval && uc2 < segidx)) { segval = w2; segidx = uc2; }
    }
    if (lane == sv - 1 && b3) {
      if (w3 < segval || (w3 == segval && uc3 < segidx)) { segval = w3; segidx = uc3; }
    }
  }
  __syncthreads();
  // ----- depths via pointer doubling (12 passes, 8-way pipelined) -----
  int* anc = (int*)wrs;
  int* dep = (int*)wds;
  for (int g = 0; g < 64; ++g) {
    int i = g * 64 + lane;
    anc[i] = par_l[i];
    dep[i] = (i == 0) ? 0 : 1;
  }
  __syncthreads();
  for (int pass = 0; pass < 12; ++pass) {
    for (int g = 0; g < 64; g += 8) {
      int a[8], d0[8], na[8], nd[8];
#pragma unroll
      for (int q = 0; q < 8; ++q) {
        int i = (g + q) * 64 + lane;
        a[q] = anc[i]; d0[q] = dep[i];
      }
#pragma unroll
      for (int q = 0; q < 8; ++q) {
        na[q] = anc[a[q]]; nd[q] = d0[q] + dep[a[q]];
      }
#pragma unroll
      for (int q = 0; q < 8; ++q) {
        int i = (g + q) * 64 + lane;
        anc[i] = na[q]; dep[i] = nd[q];
      }
    }
    __syncthreads();
  }
  // ----- level histogram + offsets -----
  int maxd = 0;
  int* cnt = (int*)dist;
  for (int g = 0; g < 64; ++g) cnt[g * 64 + lane] = 0;
  __syncthreads();
  for (int g = 0; g < 64; ++g) {
    int dp = dep[g * 64 + lane];
    maxd = max(maxd, dp);
    atomicAdd(&cnt[dp], 1);
  }
#pragma unroll
  for (int off = 32; off; off >>= 1) maxd = max(maxd, __shfl_xor(maxd, off));
  __syncthreads();
  int* offs = (int*)wrs;   // anc is dead
  int s = 0;
  for (int i2 = 0; i2 < 64; ++i2) {
    int idx = lane * 64 + i2;
    int tv = cnt[idx];
    offs[idx] = s;
    s += tv;
  }
  int incl = s;
  for (int off = 1; off < 64; off <<= 1) {
    int nv = __shfl_up(incl, off);
    if (lane >= off) incl += nv;
  }
  int base = incl - s;
  for (int i2 = 0; i2 < 64; ++i2) offs[lane * 64 + i2] += base;
  __syncthreads();
  for (int idx = lane; idx <= maxd; idx += 64) levs_g[b * LSP + idx] = offs[idx];
  if (lane == 0) {
    levs_g[b * LSP + maxd + 1] = 4096;
    levs_g[b * LSP + 4098] = maxd + 1;
  }
  __syncthreads();
  for (int g = 0; g < 64; ++g) {
    int vnode = g * 64 + lane;
    int dp = dep[vnode];
    int pos = atomicAdd(&offs[dp], 1);
    levn_g[b * 4096 + pos] = vnode;
  }
  for (int g = 0; g < 64; ++g) {
    int idx = g * 64 + lane;
    par_g[b * 4096 + idx] = par_l[idx];
  }
}

// ---------------- level-parallel tree scan, channel-split across blocks ----------------
// grid (NB, 8): block (b, cs) handles channels [cs*32, cs*32+32), 32 node-slots.
__global__ __launch_bounds__(1024) void scan_kernel(
    float* __restrict__ buf, const float* __restrict__ ew,
    const int* __restrict__ par_g, const int* __restrict__ levn_g,
    const int* __restrict__ levs_g) {
  int b = blockIdx.x;
  int d = blockIdx.y * 32 + (threadIdx.x & 31);
  int slot = threadIdx.x >> 5;                   // 0..31
  const int* levs = levs_g + b * LSP;
  const int* levn = levn_g + b * 4096;
  const int* par  = par_g + b * 4096;
  int nlev = levs[4098];
  size_t base = (size_t)b * 4096;
  // up: parents at level L gather children (level L+1)
  for (int lev = nlev - 2; lev >= 0; --lev) {
    int s = levs[lev], e = levs[lev + 1];
    for (int j = s + slot; j < e; j += 32) {
      int p = levn[j];
      int r = p >> 6, c = p & 63;
      size_t ip = (base + p) * 256 + d;
      float acc = buf[ip];
      int uu[4] = {p - 64, p - 1, p + 1, p + 64};
      bool vb[4] = {r > 0, c > 0, c < 63, r < 63};
#pragma unroll
      for (int i2 = 0; i2 < 4; ++i2) {
        if (vb[i2]) {
          int u = uu[i2];
          if (par[u] == p && u != 0) {
            size_t iu = (base + u) * 256 + d;
            acc += ew[iu] * buf[iu];
          }
        }
      }
      buf[ip] = acc;
    }
    __syncthreads();
  }
  // down: out[v] = up[v] + w*(out[p] - w*up[v])
  for (int lev = 1; lev < nlev; ++lev) {
    int s = levs[lev], e = levs[lev + 1];
    for (int j = s + slot; j < e; j += 32) {
      int v = levn[j];
      int p = par[v];
      size_t iv = (base + v) * 256 + d;
      size_t ip = (base + p) * 256 + d;
      float w = ew[iv];
      float uv = buf[iv];
      float op = buf[ip];
      buf[iv] = uv + w * (op - w * uv);
    }
    __syncthreads();
  }
}

// ---------------- post-scan: LN(d=256) -> *Cs + ds*xs -> LN -> *z ----------------
__global__ __launch_bounds__(256) void post_kernel(
    const float* __restrict__ buf, const float* __restrict__ Cs,
    const float* __restrict__ xs, const float* __restrict__ ds,
    const float* __restrict__ hng, const float* __restrict__ hnb,
    const float* __restrict__ ong, const float* __restrict__ onb,
    float* __restrict__ zya) {
  int m = blockIdx.x, d = threadIdx.x;
  size_t idx = (size_t)m * 256 + d;
  float fo = buf[idx];
  float mu = block_sum256(fo) * (1.f / 256.f);
  float dv = fo - mu;
  float var = block_sum256(dv * dv) * (1.f / 256.f);
  float ho = dv * (1.0f / sqrtf(var + 1e-5f)) * hng[d] + hnb[d];
  float y = ho * Cs[m] + ds[d] * xs[idx];
  float mu2 = block_sum256(y) * (1.f / 256.f);
  float dy = y - mu2;
  float var2 = block_sum256(dy * dy) * (1.f / 256.f);
  float y2 = dy * (1.0f / sqrtf(var2 + 1e-5f)) * ong[d] + onb[d];
  zya[idx] = y2 * zya[idx];     // ya = y * z (in place over z)
}

// ---------------- launcher ----------------
extern "C" void kernel_launch(void* const* d_in, const int* in_sizes, int n_in,
                              void* d_out, int out_size, void* d_ws, size_t ws_size,
                              hipStream_t stream) {
  (void)in_sizes; (void)n_in; (void)out_size; (void)ws_size;
  const float* x      = (const float*)d_in[0];
  const float* ln1g   = (const float*)d_in[1];
  const float* ln1b   = (const float*)d_in[2];
  const float* ln2g   = (const float*)d_in[3];
  const float* ln2b   = (const float*)d_in[4];
  const float* w_in   = (const float*)d_in[5];
  const float* conv_w = (const float*)d_in[6];
  const float* xw     = (const float*)d_in[7];
  const float* dtw    = (const float*)d_in[8];
  const float* dtb    = (const float*)d_in[9];
  const float* alogs  = (const float*)d_in[10];
  const float* dsv    = (const float*)d_in[11];
  const float* hng    = (const float*)d_in[12];
  const float* hnb    = (const float*)d_in[13];
  const float* ong    = (const float*)d_in[14];
  const float* onb    = (const float*)d_in[15];
  const float* w_out  = (const float*)d_in[16];
  const float* mw1    = (const float*)d_in[17];
  const float* mb1    = (const float*)d_in[18];
  const float* mw2    = (const float*)d_in[19];
  const float* mb2    = (const float*)d_in[20];

  char* ws = (char*)d_ws;
  float* h    = (float*)(ws + 0);            // 16MB (h, later x1)
  float* z    = (float*)(ws + 16777216);     // 33.5MB (z, later ya in-place)
  float* xcp  = (float*)(ws + 50331648);     // 33.5MB (xc_pre, later h2)
  float* xs   = (float*)(ws + 83886080);     // 33.5MB
  float* dA   = (float*)(ws + 117440512);    // 33.5MB
  float* feat = (float*)(ws + 150994944);    // 33.5MB (feat -> up/out buf)
  float* Cs   = (float*)(ws + 184549376);
  float* ssq  = (float*)(ws + 184680448);
  float* wr   = (float*)(ws + 184811520);
  float* wd   = (float*)(ws + 184942592);
  int*   par  = (int*)(ws + 185073664);
  int*   levn = (int*)(ws + 185204736);
  int*   levs = (int*)(ws + 185335808);
  float* midg = xs;      // 67MB spans xs+dA (both dead by then)
  float* x1   = h;
  float* h2   = xcp;

  ln128_kernel<<<MROWS / 4, 256, 0, stream>>>(x, ln1g, ln1b, h, 1e-6f);
  gemm_kernel<1><<<dim3(8, 512), 256, 0, stream>>>(h, w_in, xcp, z, nullptr, nullptr,
                                                   MROWS, 512, 128);
  convfeat_kernel<<<MROWS, 256, 0, stream>>>(xcp, conv_w, xw, dtw, dtb, alogs,
                                             xs, dA, feat, Cs, ssq);
  gridw_kernel<<<MROWS, 256, 0, stream>>>(xs, ssq, wr, wd);
  mst_kernel<<<NB, 64, 0, stream>>>(wr, wd, par, levn, levs);
  scan_kernel<<<dim3(NB, 8), 1024, 0, stream>>>(feat, dA, par, levn, levs);
  post_kernel<<<MROWS, 256, 0, stream>>>(feat, Cs, xs, dsv, hng, hnb, ong, onb, z);
  gemm_kernel<2><<<dim3(2, 512), 256, 0, stream>>>(z, w_out, x1, nullptr, nullptr, x,
                                                   MROWS, 128, 256);
  ln128_kernel<<<MROWS / 4, 256, 0, stream>>>(x1, ln2g, ln2b, h2, 1e-6f);
  gemm_kernel<3><<<dim3(8, 512), 256, 0, stream>>>(h2, mw1, midg, nullptr, mb1, nullptr,
                                                   MROWS, 512, 128);
  gemm_kernel<4><<<dim3(2, 512), 256, 0, stream>>>(midg, mw2, (float*)d_out, nullptr,
                                                   mb2, x1, MROWS, 128, 512);
}

// Round 4
// 1691.587 us; speedup vs baseline: 4.0622x; 2.0960x over previous
//
#include <hip/hip_runtime.h>
#include <hip/hip_bf16.h>
#include <cstdint>

#define BIGF 1e30f
constexpr int LB   = 4096;           // L = H*W
constexpr int NB   = 8;              // batch
constexpr int MROWS = NB * LB;       // 32768 pixel rows
constexpr int LSP  = 4104;           // level-start stride per batch

// ---------------- helpers ----------------
__device__ __forceinline__ float warp_sum(float v) {
#pragma unroll
  for (int off = 32; off; off >>= 1) v += __shfl_xor(v, off);
  return v;
}

__device__ __forceinline__ float block_sum256(float v) {
  __shared__ float sm[4];
  v = warp_sum(v);
  __syncthreads();
  if ((threadIdx.x & 63) == 0) sm[threadIdx.x >> 6] = v;
  __syncthreads();
  return sm[0] + sm[1] + sm[2] + sm[3];
}

// ---------------- LayerNorm over last dim 128 ----------------
__global__ __launch_bounds__(256) void ln128_kernel(
    const float* __restrict__ X, const float* __restrict__ g,
    const float* __restrict__ bb, float* __restrict__ O, float eps) {
  int wave = threadIdx.x >> 6, lane = threadIdx.x & 63;
  int row = blockIdx.x * 4 + wave;
  const float* xr = X + (size_t)row * 128;
  float x0 = xr[lane], x1 = xr[lane + 64];
  float mu = warp_sum(x0 + x1) * (1.0f / 128.0f);
  float d0 = x0 - mu, d1 = x1 - mu;
  float var = warp_sum(d0 * d0 + d1 * d1) * (1.0f / 128.0f);
  float s = 1.0f / sqrtf(var + eps);
  float* orow = O + (size_t)row * 128;
  orow[lane]      = d0 * s * g[lane]      + bb[lane];
  orow[lane + 64] = d1 * s * g[lane + 64] + bb[lane + 64];
}

// ---------------- generic f32 GEMM: C = A[M,K] @ W[N,K]^T, fused epilogues ----------------
template<int EPI>
__global__ __launch_bounds__(256) void gemm_kernel(
    const float* __restrict__ A, const float* __restrict__ W,
    float* __restrict__ C, float* __restrict__ C2,
    const float* __restrict__ bias, const float* __restrict__ addsrc,
    int M, int N, int K) {
  __shared__ float As[32][68];
  __shared__ float Bs[32][68];
  int t = threadIdx.x;
  int tx = t & 15, ty = t >> 4;
  int bm = blockIdx.y * 64, bn = blockIdx.x * 64;
  float acc[4][4] = {};
  for (int k0 = 0; k0 < K; k0 += 32) {
#pragma unroll
    for (int hh = 0; hh < 2; ++hh) {
      int q = t + hh * 256;
      int r = q >> 3, kc = q & 7;
      float4 a4 = reinterpret_cast<const float4*>(A + (size_t)(bm + r) * K + k0)[kc];
      float4 b4 = reinterpret_cast<const float4*>(W + (size_t)(bn + r) * K + k0)[kc];
      As[kc * 4 + 0][r] = a4.x; As[kc * 4 + 1][r] = a4.y;
      As[kc * 4 + 2][r] = a4.z; As[kc * 4 + 3][r] = a4.w;
      Bs[kc * 4 + 0][r] = b4.x; Bs[kc * 4 + 1][r] = b4.y;
      Bs[kc * 4 + 2][r] = b4.z; Bs[kc * 4 + 3][r] = b4.w;
    }
    __syncthreads();
#pragma unroll
    for (int kk = 0; kk < 32; ++kk) {
      float4 av = *reinterpret_cast<const float4*>(&As[kk][ty * 4]);
      float4 bv = *reinterpret_cast<const float4*>(&Bs[kk][tx * 4]);
      float aa[4] = {av.x, av.y, av.z, av.w};
      float bbv[4] = {bv.x, bv.y, bv.z, bv.w};
#pragma unroll
      for (int i = 0; i < 4; ++i)
#pragma unroll
        for (int j = 0; j < 4; ++j) acc[i][j] += aa[i] * bbv[j];
    }
    __syncthreads();
  }
#pragma unroll
  for (int i = 0; i < 4; ++i) {
    int m = bm + ty * 4 + i;
#pragma unroll
    for (int j = 0; j < 4; ++j) {
      int n = bn + tx * 4 + j;
      float v = acc[i][j];
      if (EPI == 1) {
        if (n < 256) C[(size_t)m * 256 + n] = v;
        else C2[(size_t)m * 256 + (n - 256)] = v / (1.0f + expf(-v));
      } else if (EPI == 2) {
        C[(size_t)m * N + n] = v + addsrc[(size_t)m * N + n];
      } else if (EPI == 3) {
        float u = v + bias[n];
        C[(size_t)m * N + n] =
            0.5f * u * (1.0f + tanhf(0.7978845608028654f * (u + 0.044715f * u * u * u)));
      } else if (EPI == 4) {
        C[(size_t)m * N + n] = v + bias[n] + addsrc[(size_t)m * N + n];
      }
    }
  }
}

// ---------------- depthwise conv3x3 + silu + x_dbl/dts/deltaA/feat ----------------
__global__ __launch_bounds__(256) void convfeat_kernel(
    const float* __restrict__ xcpre, const float* __restrict__ cw,
    const float* __restrict__ xw, const float* __restrict__ dtw,
    const float* __restrict__ dtb, const float* __restrict__ alogs,
    float* __restrict__ xs, float* __restrict__ dA, float* __restrict__ feat,
    float* __restrict__ Cs, float* __restrict__ ssq) {
  int m = blockIdx.x;
  int d = threadIdx.x;
  int l = m & (LB - 1), b = m >> 12;
  int r = l >> 6, c = l & 63;
  float acc = 0.f;
#pragma unroll
  for (int ky = 0; ky < 3; ++ky) {
    int rr = r + ky - 1;
    if (rr < 0 || rr > 63) continue;
#pragma unroll
    for (int kx = 0; kx < 3; ++kx) {
      int cc = c + kx - 1;
      if (cc < 0 || cc > 63) continue;
      int ml = (b << 12) + (rr << 6) + cc;
      acc += xcpre[(size_t)ml * 256 + d] * cw[d * 9 + ky * 3 + kx];
    }
  }
  float xv = acc / (1.0f + expf(-acc));        // silu
  xs[(size_t)m * 256 + d] = xv;
  float p[11];
#pragma unroll
  for (int i = 0; i < 10; ++i) p[i] = xv * xw[i * 256 + d];
  p[10] = xv * xv;
  __shared__ float sm[4][11];
#pragma unroll
  for (int i = 0; i < 11; ++i) p[i] = warp_sum(p[i]);
  int wv = d >> 6;
  if ((d & 63) == 0) {
    for (int i = 0; i < 11; ++i) sm[wv][i] = p[i];
  }
  __syncthreads();
  float red[11];
#pragma unroll
  for (int i = 0; i < 11; ++i) red[i] = sm[0][i] + sm[1][i] + sm[2][i] + sm[3][i];
  float xdt = dtb[d];
#pragma unroll
  for (int rr2 = 0; rr2 < 8; ++rr2) xdt += red[rr2] * dtw[d * 8 + rr2];
  float sp = fmaxf(xdt, 0.f) + log1pf(expf(-fabsf(xdt)));   // softplus
  float As_ = -expf(alogs[d]);
  dA[(size_t)m * 256 + d] = expf(sp * As_);
  feat[(size_t)m * 256 + d] = sp * red[8] * xv;
  if (d == 0) { Cs[m] = red[9]; ssq[m] = red[10]; }
}

// ---------------- grid edge weights wr/wd ----------------
__global__ __launch_bounds__(256) void gridw_kernel(
    const float* __restrict__ xs, const float* __restrict__ ssq,
    float* __restrict__ wrg, float* __restrict__ wdg) {
  int m = blockIdx.x, d = threadIdx.x;
  int l = m & (LB - 1);
  int r = l >> 6, c = l & 63;
  float a = xs[(size_t)m * 256 + d];
  float br = (c < 63) ? xs[(size_t)(m + 1) * 256 + d] : 0.f;
  float bd = (r < 63) ? xs[(size_t)(m + 64) * 256 + d] : 0.f;
  float s1 = warp_sum(a * br);
  float s2 = warp_sum(a * bd);
  __shared__ float sm[4][2];
  int wv = d >> 6;
  if ((d & 63) == 0) { sm[wv][0] = s1; sm[wv][1] = s2; }
  __syncthreads();
  if (d == 0) {
    float dotr = sm[0][0] + sm[1][0] + sm[2][0] + sm[3][0];
    float dotd = sm[0][1] + sm[1][1] + sm[2][1] + sm[3][1];
    float na = sqrtf(ssq[m]);
    float wrv = BIGF, wdv = BIGF;
    if (c < 63) { float den = fmaxf(na * sqrtf(ssq[m + 1]), 1e-8f);  wrv = expf(-(dotr / den)); }
    if (r < 63) { float den = fmaxf(na * sqrtf(ssq[m + 64]), 1e-8f); wdv = expf(-(dotd / den)); }
    wrg[m] = wrv; wdg[m] = wdv;
  }
}

// ---------------- Boruvka MST (unique MST == Prim's tree) + BFS root + levels ----------------
// One 1024-thread block per batch. Edge ids: e<4096 -> right edge at v=e (c<63),
// e>=4096 -> down edge at v=e-4096 (r<63).
__global__ __launch_bounds__(1024) void mst_kernel(
    const float* __restrict__ wr_g, const float* __restrict__ wd_g,
    int* __restrict__ par_g, int* __restrict__ levn_g, int* __restrict__ levs_g) {
  __shared__ float wrs[4096];
  __shared__ float wds[4096];
  __shared__ int comp[4096];
  __shared__ int lnk[4096];
  __shared__ unsigned int bestw[4096];
  __shared__ int beste[4096];
  __shared__ unsigned char flagR[4096];
  __shared__ unsigned char flagD[4096];
  __shared__ int ncomp_s, nlab_s;
  __shared__ int wred[16];
  int b = blockIdx.x, tid = threadIdx.x;
  const float* wrb = wr_g + b * 4096;
  const float* wdb = wd_g + b * 4096;
  for (int k = 0; k < 4; ++k) {
    int i = tid + k * 1024;
    wrs[i] = wrb[i]; wds[i] = wdb[i];
    comp[i] = i; flagR[i] = 0; flagD[i] = 0;
  }
  __syncthreads();
  // ---- Boruvka phases ----
  for (int phase = 0; phase < 13; ++phase) {
    for (int k = 0; k < 4; ++k) {
      int c = tid + k * 1024;
      bestw[c] = 0xFFFFFFFFu; beste[c] = 0x7FFFFFFF; lnk[c] = c;
    }
    if (tid == 0) ncomp_s = 0;
    __syncthreads();
    // pass A: per-component min weight
    for (int k = 0; k < 8; ++k) {
      int e = tid + k * 1024;
      int v = e & 4095;
      bool isR = e < 4096;
      int c = v & 63, r = v >> 6;
      bool valid = isR ? (c < 63) : (r < 63);
      if (valid) {
        int u = isR ? v + 1 : v + 64;
        int ca = comp[v], cb = comp[u];
        if (ca != cb) {
          unsigned wbits = __float_as_uint(isR ? wrs[v] : wds[v]);
          atomicMin(&bestw[ca], wbits);
          atomicMin(&bestw[cb], wbits);
        }
      }
    }
    __syncthreads();
    // pass B: min edge id among tied-min weights (deterministic)
    for (int k = 0; k < 8; ++k) {
      int e = tid + k * 1024;
      int v = e & 4095;
      bool isR = e < 4096;
      int c = v & 63, r = v >> 6;
      bool valid = isR ? (c < 63) : (r < 63);
      if (valid) {
        int u = isR ? v + 1 : v + 64;
        int ca = comp[v], cb = comp[u];
        if (ca != cb) {
          unsigned wbits = __float_as_uint(isR ? wrs[v] : wds[v]);
          if (wbits == bestw[ca]) atomicMin(&beste[ca], e);
          if (wbits == bestw[cb]) atomicMin(&beste[cb], e);
        }
      }
    }
    __syncthreads();
    // hook + flag chosen edges
    for (int k = 0; k < 4; ++k) {
      int cc = tid + k * 1024;
      int e = beste[cc];
      if (e != 0x7FFFFFFF) {
        int v = e & 4095;
        bool isR = e < 4096;
        int u = isR ? v + 1 : v + 64;
        if (isR) flagR[v] = 1; else flagD[v] = 1;
        int ca = comp[v], cb = comp[u];
        lnk[cc] = (ca == cc) ? cb : ca;
      }
    }
    __syncthreads();
    // break 2-cycles (smaller label becomes root)
    for (int k = 0; k < 4; ++k) {
      int cc = tid + k * 1024;
      int l = lnk[cc];
      if (l != cc && lnk[l] == cc && cc < l) lnk[cc] = cc;
    }
    __syncthreads();
    // pointer jumping
    for (int it = 0; it < 12; ++it) {
      for (int k = 0; k < 4; ++k) {
        int cc = tid + k * 1024;
        lnk[cc] = lnk[lnk[cc]];
      }
      __syncthreads();
    }
    // relabel + count roots
    for (int k = 0; k < 4; ++k) {
      int i = tid + k * 1024;
      comp[i] = lnk[comp[i]];
      if (comp[i] == i) atomicAdd(&ncomp_s, 1);
    }
    __syncthreads();
    if (ncomp_s <= 1) break;
    __syncthreads();
  }
  // ---- BFS rooting at node 0 (level-synchronous, race-free) ----
  int* dep = (int*)bestw;
  int* par = beste;
  for (int k = 0; k < 4; ++k) {
    int i = tid + k * 1024;
    dep[i] = (i == 0) ? 0 : -1;
    par[i] = 0;
  }
  if (tid == 0) nlab_s = 1;
  __syncthreads();
  for (int lev = 0; lev < 4096; ++lev) {
    for (int k = 0; k < 4; ++k) {
      int v = tid + k * 1024;
      if (dep[v] == -1) {
        int c = v & 63, r = v >> 6;
        int pu = -1;
        if (c < 63 && flagR[v]      && dep[v + 1]  == lev) pu = v + 1;
        if (c > 0  && flagR[v - 1]  && dep[v - 1]  == lev) pu = v - 1;
        if (r < 63 && flagD[v]      && dep[v + 64] == lev) pu = v + 64;
        if (r > 0  && flagD[v - 64] && dep[v - 64] == lev) pu = v - 64;
        if (pu >= 0) { dep[v] = lev + 1; par[v] = pu; atomicAdd(&nlab_s, 1); }
      }
    }
    __syncthreads();
    if (nlab_s == 4096) break;
    __syncthreads();
  }
  // ---- max depth ----
  int md = 0;
  for (int k = 0; k < 4; ++k) md = max(md, dep[tid + k * 1024]);
#pragma unroll
  for (int off = 32; off; off >>= 1) md = max(md, __shfl_xor(md, off));
  if ((tid & 63) == 0) wred[tid >> 6] = md;
  __syncthreads();
  if (tid == 0) {
    int m = 0;
    for (int i = 0; i < 16; ++i) m = max(m, wred[i]);
    wred[0] = m;
  }
  __syncthreads();
  int maxd = wred[0];
  __syncthreads();
  // ---- histogram + exclusive prefix over 4096 depth buckets ----
  int* cnt = comp;
  int* offs = lnk;
  for (int k = 0; k < 4; ++k) cnt[tid + k * 1024] = 0;
  __syncthreads();
  for (int k = 0; k < 4; ++k) atomicAdd(&cnt[dep[tid + k * 1024]], 1);
  __syncthreads();
  int base4 = tid * 4;
  int c0 = cnt[base4], c1 = cnt[base4 + 1], c2 = cnt[base4 + 2], c3 = cnt[base4 + 3];
  int tsum = c0 + c1 + c2 + c3;
  int lane = tid & 63, wid = tid >> 6;
  int iv = tsum;
  for (int off = 1; off < 64; off <<= 1) {
    int n = __shfl_up(iv, off);
    if (lane >= off) iv += n;
  }
  if (lane == 63) wred[wid] = iv;
  __syncthreads();
  if (tid == 0) {
    int acc = 0;
    for (int i = 0; i < 16; ++i) { int t = wred[i]; wred[i] = acc; acc += t; }
  }
  __syncthreads();
  int excl = iv - tsum + wred[wid];
  offs[base4]     = excl;
  offs[base4 + 1] = excl + c0;
  offs[base4 + 2] = excl + c0 + c1;
  offs[base4 + 3] = excl + c0 + c1 + c2;
  __syncthreads();
  for (int idx = tid; idx <= maxd; idx += 1024) levs_g[b * LSP + idx] = offs[idx];
  if (tid == 0) {
    levs_g[b * LSP + maxd + 1] = 4096;
    levs_g[b * LSP + 4098] = maxd + 1;
  }
  __syncthreads();   // RACE FIX: levs_g copy must finish reading offs before scatter mutates it
  // ---- scatter nodes by level ----
  for (int k = 0; k < 4; ++k) {
    int v2 = tid + k * 1024;
    int pos = atomicAdd(&offs[dep[v2]], 1);
    levn_g[b * 4096 + pos] = v2;
  }
  for (int k = 0; k < 4; ++k) {
    int i = tid + k * 1024;
    par_g[b * 4096 + i] = par[i];
  }
}

// ---------------- level-parallel tree scan, channel-split across blocks ----------------
__global__ __launch_bounds__(1024) void scan_kernel(
    float* __restrict__ buf, const float* __restrict__ ew,
    const int* __restrict__ par_g, const int* __restrict__ levn_g,
    const int* __restrict__ levs_g) {
  int b = blockIdx.x;
  int d = blockIdx.y * 32 + (threadIdx.x & 31);
  int slot = threadIdx.x >> 5;                   // 0..31
  const int* levs = levs_g + b * LSP;
  const int* levn = levn_g + b * 4096;
  const int* par  = par_g + b * 4096;
  int nlev = levs[4098];
  size_t base = (size_t)b * 4096;
  // up: parents at level L gather children (level L+1)
  for (int lev = nlev - 2; lev >= 0; --lev) {
    int s = levs[lev], e = levs[lev + 1];
    for (int j = s + slot; j < e; j += 32) {
      int p = levn[j];
      int r = p >> 6, c = p & 63;
      size_t ip = (base + p) * 256 + d;
      float acc = buf[ip];
      int uu[4] = {p - 64, p - 1, p + 1, p + 64};
      bool vb[4] = {r > 0, c > 0, c < 63, r < 63};
#pragma unroll
      for (int i2 = 0; i2 < 4; ++i2) {
        if (vb[i2]) {
          int u = uu[i2];
          if (par[u] == p && u != 0) {
            size_t iu = (base + u) * 256 + d;
            acc += ew[iu] * buf[iu];
          }
        }
      }
      buf[ip] = acc;
    }
    __syncthreads();
  }
  // down: out[v] = up[v] + w*(out[p] - w*up[v])
  for (int lev = 1; lev < nlev; ++lev) {
    int s = levs[lev], e = levs[lev + 1];
    for (int j = s + slot; j < e; j += 32) {
      int v = levn[j];
      int p = par[v];
      size_t iv = (base + v) * 256 + d;
      size_t ip = (base + p) * 256 + d;
      float w = ew[iv];
      float uv = buf[iv];
      float op = buf[ip];
      buf[iv] = uv + w * (op - w * uv);
    }
    __syncthreads();
  }
}

// ---------------- post-scan: LN(d=256) -> *Cs + ds*xs -> LN -> *z ----------------
__global__ __launch_bounds__(256) void post_kernel(
    const float* __restrict__ buf, const float* __restrict__ Cs,
    const float* __restrict__ xs, const float* __restrict__ ds,
    const float* __restrict__ hng, const float* __restrict__ hnb,
    const float* __restrict__ ong, const float* __restrict__ onb,
    float* __restrict__ zya) {
  int m = blockIdx.x, d = threadIdx.x;
  size_t idx = (size_t)m * 256 + d;
  float fo = buf[idx];
  float mu = block_sum256(fo) * (1.f / 256.f);
  float dv = fo - mu;
  float var = block_sum256(dv * dv) * (1.f / 256.f);
  float ho = dv * (1.0f / sqrtf(var + 1e-5f)) * hng[d] + hnb[d];
  float y = ho * Cs[m] + ds[d] * xs[idx];
  float mu2 = block_sum256(y) * (1.f / 256.f);
  float dy = y - mu2;
  float var2 = block_sum256(dy * dy) * (1.f / 256.f);
  float y2 = dy * (1.0f / sqrtf(var2 + 1e-5f)) * ong[d] + onb[d];
  zya[idx] = y2 * zya[idx];     // ya = y * z (in place over z)
}

// ---------------- launcher ----------------
extern "C" void kernel_launch(void* const* d_in, const int* in_sizes, int n_in,
                              void* d_out, int out_size, void* d_ws, size_t ws_size,
                              hipStream_t stream) {
  (void)in_sizes; (void)n_in; (void)out_size; (void)ws_size;
  const float* x      = (const float*)d_in[0];
  const float* ln1g   = (const float*)d_in[1];
  const float* ln1b   = (const float*)d_in[2];
  const float* ln2g   = (const float*)d_in[3];
  const float* ln2b   = (const float*)d_in[4];
  const float* w_in   = (const float*)d_in[5];
  const float* conv_w = (const float*)d_in[6];
  const float* xw     = (const float*)d_in[7];
  const float* dtw    = (const float*)d_in[8];
  const float* dtb    = (const float*)d_in[9];
  const float* alogs  = (const float*)d_in[10];
  const float* dsv    = (const float*)d_in[11];
  const float* hng    = (const float*)d_in[12];
  const float* hnb    = (const float*)d_in[13];
  const float* ong    = (const float*)d_in[14];
  const float* onb    = (const float*)d_in[15];
  const float* w_out  = (const float*)d_in[16];
  const float* mw1    = (const float*)d_in[17];
  const float* mb1    = (const float*)d_in[18];
  const float* mw2    = (const float*)d_in[19];
  const float* mb2    = (const float*)d_in[20];

  char* ws = (char*)d_ws;
  float* h    = (float*)(ws + 0);            // 16MB (h, later x1)
  float* z    = (float*)(ws + 16777216);     // 33.5MB (z, later ya in-place)
  float* xcp  = (float*)(ws + 50331648);     // 33.5MB (xc_pre, later h2)
  float* xs   = (float*)(ws + 83886080);     // 33.5MB
  float* dA   = (float*)(ws + 117440512);    // 33.5MB
  float* feat = (float*)(ws + 150994944);    // 33.5MB (feat -> up/out buf)
  float* Cs   = (float*)(ws + 184549376);
  float* ssq  = (float*)(ws + 184680448);
  float* wr   = (float*)(ws + 184811520);
  float* wd   = (float*)(ws + 184942592);
  int*   par  = (int*)(ws + 185073664);
  int*   levn = (int*)(ws + 185204736);
  int*   levs = (int*)(ws + 185335808);
  float* midg = xs;      // 67MB spans xs+dA (both dead by then)
  float* x1   = h;
  float* h2   = xcp;

  ln128_kernel<<<MROWS / 4, 256, 0, stream>>>(x, ln1g, ln1b, h, 1e-6f);
  gemm_kernel<1><<<dim3(8, 512), 256, 0, stream>>>(h, w_in, xcp, z, nullptr, nullptr,
                                                   MROWS, 512, 128);
  convfeat_kernel<<<MROWS, 256, 0, stream>>>(xcp, conv_w, xw, dtw, dtb, alogs,
                                             xs, dA, feat, Cs, ssq);
  gridw_kernel<<<MROWS, 256, 0, stream>>>(xs, ssq, wr, wd);
  mst_kernel<<<NB, 1024, 0, stream>>>(wr, wd, par, levn, levs);
  scan_kernel<<<dim3(NB, 8), 1024, 0, stream>>>(feat, dA, par, levn, levs);
  post_kernel<<<MROWS, 256, 0, stream>>>(feat, Cs, xs, dsv, hng, hnb, ong, onb, z);
  gemm_kernel<2><<<dim3(2, 512), 256, 0, stream>>>(z, w_out, x1, nullptr, nullptr, x,
                                                   MROWS, 128, 256);
  ln128_kernel<<<MROWS / 4, 256, 0, stream>>>(x1, ln2g, ln2b, h2, 1e-6f);
  gemm_kernel<3><<<dim3(8, 512), 256, 0, stream>>>(h2, mw1, midg, nullptr, mb1, nullptr,
                                                   MROWS, 512, 128);
  gemm_kernel<4><<<dim3(2, 512), 256, 0, stream>>>(midg, mw2, (float*)d_out, nullptr,
                                                   mb2, x1, MROWS, 128, 512);
}

// Round 5
// 1573.185 us; speedup vs baseline: 4.3679x; 1.0753x over previous
//
#include <hip/hip_runtime.h>
#include <hip/hip_bf16.h>
#include <cstdint>

#define BIGF 1e30f
constexpr int LB   = 4096;           // L = H*W
constexpr int NB   = 8;              // batch
constexpr int MROWS = NB * LB;       // 32768 pixel rows
constexpr int LSP  = 4104;           // level-start stride per batch

// ---------------- helpers ----------------
__device__ __forceinline__ float warp_sum(float v) {
#pragma unroll
  for (int off = 32; off; off >>= 1) v += __shfl_xor(v, off);
  return v;
}

__device__ __forceinline__ float block_sum256(float v) {
  __shared__ float sm[4];
  v = warp_sum(v);
  __syncthreads();
  if ((threadIdx.x & 63) == 0) sm[threadIdx.x >> 6] = v;
  __syncthreads();
  return sm[0] + sm[1] + sm[2] + sm[3];
}

// ---------------- LayerNorm over last dim 128 ----------------
__global__ __launch_bounds__(256) void ln128_kernel(
    const float* __restrict__ X, const float* __restrict__ g,
    const float* __restrict__ bb, float* __restrict__ O, float eps) {
  int wave = threadIdx.x >> 6, lane = threadIdx.x & 63;
  int row = blockIdx.x * 4 + wave;
  const float* xr = X + (size_t)row * 128;
  float x0 = xr[lane], x1 = xr[lane + 64];
  float mu = warp_sum(x0 + x1) * (1.0f / 128.0f);
  float d0 = x0 - mu, d1 = x1 - mu;
  float var = warp_sum(d0 * d0 + d1 * d1) * (1.0f / 128.0f);
  float s = 1.0f / sqrtf(var + eps);
  float* orow = O + (size_t)row * 128;
  orow[lane]      = d0 * s * g[lane]      + bb[lane];
  orow[lane + 64] = d1 * s * g[lane + 64] + bb[lane + 64];
}

// ---------------- generic f32 GEMM: C = A[M,K] @ W[N,K]^T, fused epilogues ----------------
template<int EPI>
__global__ __launch_bounds__(256) void gemm_kernel(
    const float* __restrict__ A, const float* __restrict__ W,
    float* __restrict__ C, float* __restrict__ C2,
    const float* __restrict__ bias, const float* __restrict__ addsrc,
    int M, int N, int K) {
  __shared__ float As[32][68];
  __shared__ float Bs[32][68];
  int t = threadIdx.x;
  int tx = t & 15, ty = t >> 4;
  int bm = blockIdx.y * 64, bn = blockIdx.x * 64;
  float acc[4][4] = {};
  for (int k0 = 0; k0 < K; k0 += 32) {
#pragma unroll
    for (int hh = 0; hh < 2; ++hh) {
      int q = t + hh * 256;
      int r = q >> 3, kc = q & 7;
      float4 a4 = reinterpret_cast<const float4*>(A + (size_t)(bm + r) * K + k0)[kc];
      float4 b4 = reinterpret_cast<const float4*>(W + (size_t)(bn + r) * K + k0)[kc];
      As[kc * 4 + 0][r] = a4.x; As[kc * 4 + 1][r] = a4.y;
      As[kc * 4 + 2][r] = a4.z; As[kc * 4 + 3][r] = a4.w;
      Bs[kc * 4 + 0][r] = b4.x; Bs[kc * 4 + 1][r] = b4.y;
      Bs[kc * 4 + 2][r] = b4.z; Bs[kc * 4 + 3][r] = b4.w;
    }
    __syncthreads();
#pragma unroll
    for (int kk = 0; kk < 32; ++kk) {
      float4 av = *reinterpret_cast<const float4*>(&As[kk][ty * 4]);
      float4 bv = *reinterpret_cast<const float4*>(&Bs[kk][tx * 4]);
      float aa[4] = {av.x, av.y, av.z, av.w};
      float bbv[4] = {bv.x, bv.y, bv.z, bv.w};
#pragma unroll
      for (int i = 0; i < 4; ++i)
#pragma unroll
        for (int j = 0; j < 4; ++j) acc[i][j] += aa[i] * bbv[j];
    }
    __syncthreads();
  }
#pragma unroll
  for (int i = 0; i < 4; ++i) {
    int m = bm + ty * 4 + i;
#pragma unroll
    for (int j = 0; j < 4; ++j) {
      int n = bn + tx * 4 + j;
      float v = acc[i][j];
      if (EPI == 1) {
        if (n < 256) C[(size_t)m * 256 + n] = v;
        else C2[(size_t)m * 256 + (n - 256)] = v / (1.0f + expf(-v));
      } else if (EPI == 2) {
        C[(size_t)m * N + n] = v + addsrc[(size_t)m * N + n];
      } else if (EPI == 3) {
        float u = v + bias[n];
        C[(size_t)m * N + n] =
            0.5f * u * (1.0f + tanhf(0.7978845608028654f * (u + 0.044715f * u * u * u)));
      } else if (EPI == 4) {
        C[(size_t)m * N + n] = v + bias[n] + addsrc[(size_t)m * N + n];
      }
    }
  }
}

// ---------------- depthwise conv3x3 + silu + x_dbl/dts/deltaA/feat ----------------
__global__ __launch_bounds__(256) void convfeat_kernel(
    const float* __restrict__ xcpre, const float* __restrict__ cw,
    const float* __restrict__ xw, const float* __restrict__ dtw,
    const float* __restrict__ dtb, const float* __restrict__ alogs,
    float* __restrict__ xs, float* __restrict__ dA, float* __restrict__ feat,
    float* __restrict__ Cs, float* __restrict__ ssq) {
  int m = blockIdx.x;
  int d = threadIdx.x;
  int l = m & (LB - 1), b = m >> 12;
  int r = l >> 6, c = l & 63;
  float acc = 0.f;
#pragma unroll
  for (int ky = 0; ky < 3; ++ky) {
    int rr = r + ky - 1;
    if (rr < 0 || rr > 63) continue;
#pragma unroll
    for (int kx = 0; kx < 3; ++kx) {
      int cc = c + kx - 1;
      if (cc < 0 || cc > 63) continue;
      int ml = (b << 12) + (rr << 6) + cc;
      acc += xcpre[(size_t)ml * 256 + d] * cw[d * 9 + ky * 3 + kx];
    }
  }
  float xv = acc / (1.0f + expf(-acc));        // silu
  xs[(size_t)m * 256 + d] = xv;
  float p[11];
#pragma unroll
  for (int i = 0; i < 10; ++i) p[i] = xv * xw[i * 256 + d];
  p[10] = xv * xv;
  __shared__ float sm[4][11];
#pragma unroll
  for (int i = 0; i < 11; ++i) p[i] = warp_sum(p[i]);
  int wv = d >> 6;
  if ((d & 63) == 0) {
    for (int i = 0; i < 11; ++i) sm[wv][i] = p[i];
  }
  __syncthreads();
  float red[11];
#pragma unroll
  for (int i = 0; i < 11; ++i) red[i] = sm[0][i] + sm[1][i] + sm[2][i] + sm[3][i];
  float xdt = dtb[d];
#pragma unroll
  for (int rr2 = 0; rr2 < 8; ++rr2) xdt += red[rr2] * dtw[d * 8 + rr2];
  float sp = fmaxf(xdt, 0.f) + log1pf(expf(-fabsf(xdt)));   // softplus
  float As_ = -expf(alogs[d]);
  dA[(size_t)m * 256 + d] = expf(sp * As_);
  feat[(size_t)m * 256 + d] = sp * red[8] * xv;
  if (d == 0) { Cs[m] = red[9]; ssq[m] = red[10]; }
}

// ---------------- grid edge weights wr/wd ----------------
__global__ __launch_bounds__(256) void gridw_kernel(
    const float* __restrict__ xs, const float* __restrict__ ssq,
    float* __restrict__ wrg, float* __restrict__ wdg) {
  int m = blockIdx.x, d = threadIdx.x;
  int l = m & (LB - 1);
  int r = l >> 6, c = l & 63;
  float a = xs[(size_t)m * 256 + d];
  float br = (c < 63) ? xs[(size_t)(m + 1) * 256 + d] : 0.f;
  float bd = (r < 63) ? xs[(size_t)(m + 64) * 256 + d] : 0.f;
  float s1 = warp_sum(a * br);
  float s2 = warp_sum(a * bd);
  __shared__ float sm[4][2];
  int wv = d >> 6;
  if ((d & 63) == 0) { sm[wv][0] = s1; sm[wv][1] = s2; }
  __syncthreads();
  if (d == 0) {
    float dotr = sm[0][0] + sm[1][0] + sm[2][0] + sm[3][0];
    float dotd = sm[0][1] + sm[1][1] + sm[2][1] + sm[3][1];
    float na = sqrtf(ssq[m]);
    float wrv = BIGF, wdv = BIGF;
    if (c < 63) { float den = fmaxf(na * sqrtf(ssq[m + 1]), 1e-8f);  wrv = expf(-(dotr / den)); }
    if (r < 63) { float den = fmaxf(na * sqrtf(ssq[m + 64]), 1e-8f); wdv = expf(-(dotd / den)); }
    wrg[m] = wrv; wdg[m] = wdv;
  }
}

// ---------------- Boruvka MST (unique MST == Prim's tree) + BFS root + levels ----------------
// One 1024-thread block per batch. Edge ids: e<4096 -> right edge at v=e (c<63),
// e>=4096 -> down edge at v=e-4096 (r<63).
__global__ __launch_bounds__(1024) void mst_kernel(
    const float* __restrict__ wr_g, const float* __restrict__ wd_g,
    int* __restrict__ par_g, int* __restrict__ levn_g, int* __restrict__ levs_g) {
  __shared__ float wrs[4096];
  __shared__ float wds[4096];
  __shared__ int comp[4096];
  __shared__ int lnk[4096];
  __shared__ unsigned int bestw[4096];
  __shared__ int beste[4096];
  __shared__ unsigned char flagR[4096];
  __shared__ unsigned char flagD[4096];
  __shared__ int ncomp_s, nlab_s;
  __shared__ int wred[16];
  int b = blockIdx.x, tid = threadIdx.x;
  const float* wrb = wr_g + b * 4096;
  const float* wdb = wd_g + b * 4096;
  for (int k = 0; k < 4; ++k) {
    int i = tid + k * 1024;
    wrs[i] = wrb[i]; wds[i] = wdb[i];
    comp[i] = i; flagR[i] = 0; flagD[i] = 0;
  }
  __syncthreads();
  // ---- Boruvka phases ----
  for (int phase = 0; phase < 13; ++phase) {
    for (int k = 0; k < 4; ++k) {
      int c = tid + k * 1024;
      bestw[c] = 0xFFFFFFFFu; beste[c] = 0x7FFFFFFF; lnk[c] = c;
    }
    if (tid == 0) ncomp_s = 0;
    __syncthreads();
    // pass A: per-component min weight
    for (int k = 0; k < 8; ++k) {
      int e = tid + k * 1024;
      int v = e & 4095;
      bool isR = e < 4096;
      int c = v & 63, r = v >> 6;
      bool valid = isR ? (c < 63) : (r < 63);
      if (valid) {
        int u = isR ? v + 1 : v + 64;
        int ca = comp[v], cb = comp[u];
        if (ca != cb) {
          unsigned wbits = __float_as_uint(isR ? wrs[v] : wds[v]);
          atomicMin(&bestw[ca], wbits);
          atomicMin(&bestw[cb], wbits);
        }
      }
    }
    __syncthreads();
    // pass B: min edge id among tied-min weights (deterministic)
    for (int k = 0; k < 8; ++k) {
      int e = tid + k * 1024;
      int v = e & 4095;
      bool isR = e < 4096;
      int c = v & 63, r = v >> 6;
      bool valid = isR ? (c < 63) : (r < 63);
      if (valid) {
        int u = isR ? v + 1 : v + 64;
        int ca = comp[v], cb = comp[u];
        if (ca != cb) {
          unsigned wbits = __float_as_uint(isR ? wrs[v] : wds[v]);
          if (wbits == bestw[ca]) atomicMin(&beste[ca], e);
          if (wbits == bestw[cb]) atomicMin(&beste[cb], e);
        }
      }
    }
    __syncthreads();
    // hook + flag chosen edges
    for (int k = 0; k < 4; ++k) {
      int cc = tid + k * 1024;
      int e = beste[cc];
      if (e != 0x7FFFFFFF) {
        int v = e & 4095;
        bool isR = e < 4096;
        int u = isR ? v + 1 : v + 64;
        if (isR) flagR[v] = 1; else flagD[v] = 1;
        int ca = comp[v], cb = comp[u];
        lnk[cc] = (ca == cc) ? cb : ca;
      }
    }
    __syncthreads();
    // break 2-cycles (smaller label becomes root)
    for (int k = 0; k < 4; ++k) {
      int cc = tid + k * 1024;
      int l = lnk[cc];
      if (l != cc && lnk[l] == cc && cc < l) lnk[cc] = cc;
    }
    __syncthreads();
    // pointer jumping
    for (int it = 0; it < 12; ++it) {
      for (int k = 0; k < 4; ++k) {
        int cc = tid + k * 1024;
        lnk[cc] = lnk[lnk[cc]];
      }
      __syncthreads();
    }
    // relabel + count roots
    for (int k = 0; k < 4; ++k) {
      int i = tid + k * 1024;
      comp[i] = lnk[comp[i]];
      if (comp[i] == i) atomicAdd(&ncomp_s, 1);
    }
    __syncthreads();
    if (ncomp_s <= 1) break;
    __syncthreads();
  }
  // ---- BFS rooting at node 0 (level-synchronous, race-free) ----
  int* dep = (int*)bestw;
  int* par = beste;
  for (int k = 0; k < 4; ++k) {
    int i = tid + k * 1024;
    dep[i] = (i == 0) ? 0 : -1;
    par[i] = 0;
  }
  if (tid == 0) nlab_s = 1;
  __syncthreads();
  for (int lev = 0; lev < 4096; ++lev) {
    for (int k = 0; k < 4; ++k) {
      int v = tid + k * 1024;
      if (dep[v] == -1) {
        int c = v & 63, r = v >> 6;
        int pu = -1;
        if (c < 63 && flagR[v]      && dep[v + 1]  == lev) pu = v + 1;
        if (c > 0  && flagR[v - 1]  && dep[v - 1]  == lev) pu = v - 1;
        if (r < 63 && flagD[v]      && dep[v + 64] == lev) pu = v + 64;
        if (r > 0  && flagD[v - 64] && dep[v - 64] == lev) pu = v - 64;
        if (pu >= 0) { dep[v] = lev + 1; par[v] = pu; atomicAdd(&nlab_s, 1); }
      }
    }
    __syncthreads();
    if (nlab_s == 4096) break;
    __syncthreads();
  }
  // ---- max depth ----
  int md = 0;
  for (int k = 0; k < 4; ++k) md = max(md, dep[tid + k * 1024]);
#pragma unroll
  for (int off = 32; off; off >>= 1) md = max(md, __shfl_xor(md, off));
  if ((tid & 63) == 0) wred[tid >> 6] = md;
  __syncthreads();
  if (tid == 0) {
    int m = 0;
    for (int i = 0; i < 16; ++i) m = max(m, wred[i]);
    wred[0] = m;
  }
  __syncthreads();
  int maxd = wred[0];
  __syncthreads();
  // ---- histogram + exclusive prefix over 4096 depth buckets ----
  int* cnt = comp;
  int* offs = lnk;
  for (int k = 0; k < 4; ++k) cnt[tid + k * 1024] = 0;
  __syncthreads();
  for (int k = 0; k < 4; ++k) atomicAdd(&cnt[dep[tid + k * 1024]], 1);
  __syncthreads();
  int base4 = tid * 4;
  int c0 = cnt[base4], c1 = cnt[base4 + 1], c2 = cnt[base4 + 2], c3 = cnt[base4 + 3];
  int tsum = c0 + c1 + c2 + c3;
  int lane = tid & 63, wid = tid >> 6;
  int iv = tsum;
  for (int off = 1; off < 64; off <<= 1) {
    int n = __shfl_up(iv, off);
    if (lane >= off) iv += n;
  }
  if (lane == 63) wred[wid] = iv;
  __syncthreads();
  if (tid == 0) {
    int acc = 0;
    for (int i = 0; i < 16; ++i) { int t = wred[i]; wred[i] = acc; acc += t; }
  }
  __syncthreads();
  int excl = iv - tsum + wred[wid];
  offs[base4]     = excl;
  offs[base4 + 1] = excl + c0;
  offs[base4 + 2] = excl + c0 + c1;
  offs[base4 + 3] = excl + c0 + c1 + c2;
  __syncthreads();
  for (int idx = tid; idx <= maxd; idx += 1024) levs_g[b * LSP + idx] = offs[idx];
  if (tid == 0) {
    levs_g[b * LSP + maxd + 1] = 4096;
    levs_g[b * LSP + 4098] = maxd + 1;
  }
  __syncthreads();   // levs_g copy must finish reading offs before scatter mutates it
  // ---- scatter nodes by level ----
  for (int k = 0; k < 4; ++k) {
    int v2 = tid + k * 1024;
    int pos = atomicAdd(&offs[dep[v2]], 1);
    levn_g[b * 4096 + pos] = v2;
  }
  for (int k = 0; k < 4; ++k) {
    int i = tid + k * 1024;
    par_g[b * 4096 + i] = par[i];
  }
}

// ---------------- LDS-resident level-parallel tree scan ----------------
// grid (NB, 64): block (b, cg) owns channels [cg*4, cg*4+4) for all 4096 nodes.
// buf/ew/par staged in LDS (64+64+16 = 144 KB); all level iterations run out of LDS.
__global__ __launch_bounds__(1024) void scan_kernel(
    float* __restrict__ buf, const float* __restrict__ ew,
    const int* __restrict__ par_g, const int* __restrict__ levn_g,
    const int* __restrict__ levs_g) {
  __shared__ float bl[4096 * 4];
  __shared__ float el[4096 * 4];
  __shared__ int   pl[4096];
  int b = blockIdx.x;
  int cb = blockIdx.y * 4;
  int tid = threadIdx.x;
  const int* levs = levs_g + b * LSP;
  const int* levn = levn_g + b * 4096;
  int nlev = levs[4098];
  size_t base = (size_t)b * 4096;
  // stage: 16B per node per array
  for (int i = tid; i < 16384; i += 1024) {
    int node = i >> 2, ch = i & 3;
    size_t g = (base + node) * 256 + cb + ch;
    bl[i] = buf[g];
    el[i] = ew[g];
  }
  for (int i = tid; i < 4096; i += 1024) pl[i] = par_g[b * 4096 + i];
  __syncthreads();
  int ch = tid & 3;
  int slot = tid >> 2;   // 0..255
  // up: parents at level L gather children (level L+1); child u of p iff par[u]==p
  for (int lev = nlev - 2; lev >= 0; --lev) {
    int s = levs[lev], e = levs[lev + 1];
    for (int j = s + slot; j < e; j += 256) {
      int p = levn[j];
      int r = p >> 6, c = p & 63;
      float acc = bl[p * 4 + ch];
      if (r > 0)  { int u = p - 64; if (pl[u] == p && u != 0) acc += el[u * 4 + ch] * bl[u * 4 + ch]; }
      if (c > 0)  { int u = p - 1;  if (pl[u] == p && u != 0) acc += el[u * 4 + ch] * bl[u * 4 + ch]; }
      if (c < 63) { int u = p + 1;  if (pl[u] == p && u != 0) acc += el[u * 4 + ch] * bl[u * 4 + ch]; }
      if (r < 63) { int u = p + 64; if (pl[u] == p && u != 0) acc += el[u * 4 + ch] * bl[u * 4 + ch]; }
      bl[p * 4 + ch] = acc;
    }
    __syncthreads();
  }
  // down: out[v] = up[v] + w*(out[p] - w*up[v]); in-place, root keeps up[root]
  for (int lev = 1; lev < nlev; ++lev) {
    int s = levs[lev], e = levs[lev + 1];
    for (int j = s + slot; j < e; j += 256) {
      int v = levn[j];
      int p = pl[v];
      float w = el[v * 4 + ch];
      float uv = bl[v * 4 + ch];
      bl[v * 4 + ch] = uv + w * (bl[p * 4 + ch] - w * uv);
    }
    __syncthreads();
  }
  // write back
  for (int i = tid; i < 16384; i += 1024) {
    int node = i >> 2, ch2 = i & 3;
    buf[(base + node) * 256 + cb + ch2] = bl[i];
  }
}

// ---------------- post-scan: LN(d=256) -> *Cs + ds*xs -> LN -> *z ----------------
__global__ __launch_bounds__(256) void post_kernel(
    const float* __restrict__ buf, const float* __restrict__ Cs,
    const float* __restrict__ xs, const float* __restrict__ ds,
    const float* __restrict__ hng, const float* __restrict__ hnb,
    const float* __restrict__ ong, const float* __restrict__ onb,
    float* __restrict__ zya) {
  int m = blockIdx.x, d = threadIdx.x;
  size_t idx = (size_t)m * 256 + d;
  float fo = buf[idx];
  float mu = block_sum256(fo) * (1.f / 256.f);
  float dv = fo - mu;
  float var = block_sum256(dv * dv) * (1.f / 256.f);
  float ho = dv * (1.0f / sqrtf(var + 1e-5f)) * hng[d] + hnb[d];
  float y = ho * Cs[m] + ds[d] * xs[idx];
  float mu2 = block_sum256(y) * (1.f / 256.f);
  float dy = y - mu2;
  float var2 = block_sum256(dy * dy) * (1.f / 256.f);
  float y2 = dy * (1.0f / sqrtf(var2 + 1e-5f)) * ong[d] + onb[d];
  zya[idx] = y2 * zya[idx];     // ya = y * z (in place over z)
}

// ---------------- launcher ----------------
extern "C" void kernel_launch(void* const* d_in, const int* in_sizes, int n_in,
                              void* d_out, int out_size, void* d_ws, size_t ws_size,
                              hipStream_t stream) {
  (void)in_sizes; (void)n_in; (void)out_size; (void)ws_size;
  const float* x      = (const float*)d_in[0];
  const float* ln1g   = (const float*)d_in[1];
  const float* ln1b   = (const float*)d_in[2];
  const float* ln2g   = (const float*)d_in[3];
  const float* ln2b   = (const float*)d_in[4];
  const float* w_in   = (const float*)d_in[5];
  const float* conv_w = (const float*)d_in[6];
  const float* xw     = (const float*)d_in[7];
  const float* dtw    = (const float*)d_in[8];
  const float* dtb    = (const float*)d_in[9];
  const float* alogs  = (const float*)d_in[10];
  const float* dsv    = (const float*)d_in[11];
  const float* hng    = (const float*)d_in[12];
  const float* hnb    = (const float*)d_in[13];
  const float* ong    = (const float*)d_in[14];
  const float* onb    = (const float*)d_in[15];
  const float* w_out  = (const float*)d_in[16];
  const float* mw1    = (const float*)d_in[17];
  const float* mb1    = (const float*)d_in[18];
  const float* mw2    = (const float*)d_in[19];
  const float* mb2    = (const float*)d_in[20];

  char* ws = (char*)d_ws;
  float* h    = (float*)(ws + 0);            // 16MB (h, later x1)
  float* z    = (float*)(ws + 16777216);     // 33.5MB (z, later ya in-place)
  float* xcp  = (float*)(ws + 50331648);     // 33.5MB (xc_pre, later h2)
  float* xs   = (float*)(ws + 83886080);     // 33.5MB
  float* dA   = (float*)(ws + 117440512);    // 33.5MB
  float* feat = (float*)(ws + 150994944);    // 33.5MB (feat -> up/out buf)
  float* Cs   = (float*)(ws + 184549376);
  float* ssq  = (float*)(ws + 184680448);
  float* wr   = (float*)(ws + 184811520);
  float* wd   = (float*)(ws + 184942592);
  int*   par  = (int*)(ws + 185073664);
  int*   levn = (int*)(ws + 185204736);
  int*   levs = (int*)(ws + 185335808);
  float* midg = xs;      // 67MB spans xs+dA (both dead by then)
  float* x1   = h;
  float* h2   = xcp;

  ln128_kernel<<<MROWS / 4, 256, 0, stream>>>(x, ln1g, ln1b, h, 1e-6f);
  gemm_kernel<1><<<dim3(8, 512), 256, 0, stream>>>(h, w_in, xcp, z, nullptr, nullptr,
                                                   MROWS, 512, 128);
  convfeat_kernel<<<MROWS, 256, 0, stream>>>(xcp, conv_w, xw, dtw, dtb, alogs,
                                             xs, dA, feat, Cs, ssq);
  gridw_kernel<<<MROWS, 256, 0, stream>>>(xs, ssq, wr, wd);
  mst_kernel<<<NB, 1024, 0, stream>>>(wr, wd, par, levn, levs);
  scan_kernel<<<dim3(NB, 64), 1024, 0, stream>>>(feat, dA, par, levn, levs);
  post_kernel<<<MROWS, 256, 0, stream>>>(feat, Cs, xs, dsv, hng, hnb, ong, onb, z);
  gemm_kernel<2><<<dim3(2, 512), 256, 0, stream>>>(z, w_out, x1, nullptr, nullptr, x,
                                                   MROWS, 128, 256);
  ln128_kernel<<<MROWS / 4, 256, 0, stream>>>(x1, ln2g, ln2b, h2, 1e-6f);
  gemm_kernel<3><<<dim3(8, 512), 256, 0, stream>>>(h2, mw1, midg, nullptr, mb1, nullptr,
                                                   MROWS, 512, 128);
  gemm_kernel<4><<<dim3(2, 512), 256, 0, stream>>>(midg, mw2, (float*)d_out, nullptr,
                                                   mb2, x1, MROWS, 128, 512);
}

// Round 6
// 1480.718 us; speedup vs baseline: 4.6407x; 1.0624x over previous
//
#include <hip/hip_runtime.h>
#include <hip/hip_bf16.h>
#include <cstdint>

#define BIGF 1e30f
constexpr int LB   = 4096;           // L = H*W
constexpr int NB   = 8;              // batch
constexpr int MROWS = NB * LB;       // 32768 pixel rows
constexpr int LSP  = 4104;           // level-start stride per batch

// ---------------- helpers ----------------
__device__ __forceinline__ float warp_sum(float v) {
#pragma unroll
  for (int off = 32; off; off >>= 1) v += __shfl_xor(v, off);
  return v;
}

__device__ __forceinline__ float block_sum256(float v) {
  __shared__ float sm[4];
  v = warp_sum(v);
  __syncthreads();
  if ((threadIdx.x & 63) == 0) sm[threadIdx.x >> 6] = v;
  __syncthreads();
  return sm[0] + sm[1] + sm[2] + sm[3];
}

// ---------------- LayerNorm over last dim 128 ----------------
__global__ __launch_bounds__(256) void ln128_kernel(
    const float* __restrict__ X, const float* __restrict__ g,
    const float* __restrict__ bb, float* __restrict__ O, float eps) {
  int wave = threadIdx.x >> 6, lane = threadIdx.x & 63;
  int row = blockIdx.x * 4 + wave;
  const float* xr = X + (size_t)row * 128;
  float x0 = xr[lane], x1 = xr[lane + 64];
  float mu = warp_sum(x0 + x1) * (1.0f / 128.0f);
  float d0 = x0 - mu, d1 = x1 - mu;
  float var = warp_sum(d0 * d0 + d1 * d1) * (1.0f / 128.0f);
  float s = 1.0f / sqrtf(var + eps);
  float* orow = O + (size_t)row * 128;
  orow[lane]      = d0 * s * g[lane]      + bb[lane];
  orow[lane + 64] = d1 * s * g[lane + 64] + bb[lane + 64];
}

// ---------------- generic f32 GEMM: C = A[M,K] @ W[N,K]^T, fused epilogues ----------------
template<int EPI>
__global__ __launch_bounds__(256) void gemm_kernel(
    const float* __restrict__ A, const float* __restrict__ W,
    float* __restrict__ C, float* __restrict__ C2,
    const float* __restrict__ bias, const float* __restrict__ addsrc,
    int M, int N, int K) {
  __shared__ float As[32][68];
  __shared__ float Bs[32][68];
  int t = threadIdx.x;
  int tx = t & 15, ty = t >> 4;
  int bm = blockIdx.y * 64, bn = blockIdx.x * 64;
  float acc[4][4] = {};
  for (int k0 = 0; k0 < K; k0 += 32) {
#pragma unroll
    for (int hh = 0; hh < 2; ++hh) {
      int q = t + hh * 256;
      int r = q >> 3, kc = q & 7;
      float4 a4 = reinterpret_cast<const float4*>(A + (size_t)(bm + r) * K + k0)[kc];
      float4 b4 = reinterpret_cast<const float4*>(W + (size_t)(bn + r) * K + k0)[kc];
      As[kc * 4 + 0][r] = a4.x; As[kc * 4 + 1][r] = a4.y;
      As[kc * 4 + 2][r] = a4.z; As[kc * 4 + 3][r] = a4.w;
      Bs[kc * 4 + 0][r] = b4.x; Bs[kc * 4 + 1][r] = b4.y;
      Bs[kc * 4 + 2][r] = b4.z; Bs[kc * 4 + 3][r] = b4.w;
    }
    __syncthreads();
#pragma unroll
    for (int kk = 0; kk < 32; ++kk) {
      float4 av = *reinterpret_cast<const float4*>(&As[kk][ty * 4]);
      float4 bv = *reinterpret_cast<const float4*>(&Bs[kk][tx * 4]);
      float aa[4] = {av.x, av.y, av.z, av.w};
      float bbv[4] = {bv.x, bv.y, bv.z, bv.w};
#pragma unroll
      for (int i = 0; i < 4; ++i)
#pragma unroll
        for (int j = 0; j < 4; ++j) acc[i][j] += aa[i] * bbv[j];
    }
    __syncthreads();
  }
#pragma unroll
  for (int i = 0; i < 4; ++i) {
    int m = bm + ty * 4 + i;
#pragma unroll
    for (int j = 0; j < 4; ++j) {
      int n = bn + tx * 4 + j;
      float v = acc[i][j];
      if (EPI == 1) {
        if (n < 256) C[(size_t)m * 256 + n] = v;
        else C2[(size_t)m * 256 + (n - 256)] = v / (1.0f + expf(-v));
      } else if (EPI == 2) {
        C[(size_t)m * N + n] = v + addsrc[(size_t)m * N + n];
      } else if (EPI == 3) {
        float u = v + bias[n];
        C[(size_t)m * N + n] =
            0.5f * u * (1.0f + tanhf(0.7978845608028654f * (u + 0.044715f * u * u * u)));
      } else if (EPI == 4) {
        C[(size_t)m * N + n] = v + bias[n] + addsrc[(size_t)m * N + n];
      }
    }
  }
}

// ---------------- depthwise conv3x3 + silu + x_dbl/dts/deltaA/feat ----------------
__global__ __launch_bounds__(256) void convfeat_kernel(
    const float* __restrict__ xcpre, const float* __restrict__ cw,
    const float* __restrict__ xw, const float* __restrict__ dtw,
    const float* __restrict__ dtb, const float* __restrict__ alogs,
    float* __restrict__ xs, float* __restrict__ dA, float* __restrict__ feat,
    float* __restrict__ Cs, float* __restrict__ ssq) {
  int m = blockIdx.x;
  int d = threadIdx.x;
  int l = m & (LB - 1), b = m >> 12;
  int r = l >> 6, c = l & 63;
  float acc = 0.f;
#pragma unroll
  for (int ky = 0; ky < 3; ++ky) {
    int rr = r + ky - 1;
    if (rr < 0 || rr > 63) continue;
#pragma unroll
    for (int kx = 0; kx < 3; ++kx) {
      int cc = c + kx - 1;
      if (cc < 0 || cc > 63) continue;
      int ml = (b << 12) + (rr << 6) + cc;
      acc += xcpre[(size_t)ml * 256 + d] * cw[d * 9 + ky * 3 + kx];
    }
  }
  float xv = acc / (1.0f + expf(-acc));        // silu
  xs[(size_t)m * 256 + d] = xv;
  float p[11];
#pragma unroll
  for (int i = 0; i < 10; ++i) p[i] = xv * xw[i * 256 + d];
  p[10] = xv * xv;
  __shared__ float sm[4][11];
#pragma unroll
  for (int i = 0; i < 11; ++i) p[i] = warp_sum(p[i]);
  int wv = d >> 6;
  if ((d & 63) == 0) {
    for (int i = 0; i < 11; ++i) sm[wv][i] = p[i];
  }
  __syncthreads();
  float red[11];
#pragma unroll
  for (int i = 0; i < 11; ++i) red[i] = sm[0][i] + sm[1][i] + sm[2][i] + sm[3][i];
  float xdt = dtb[d];
#pragma unroll
  for (int rr2 = 0; rr2 < 8; ++rr2) xdt += red[rr2] * dtw[d * 8 + rr2];
  float sp = fmaxf(xdt, 0.f) + log1pf(expf(-fabsf(xdt)));   // softplus
  float As_ = -expf(alogs[d]);
  dA[(size_t)m * 256 + d] = expf(sp * As_);
  feat[(size_t)m * 256 + d] = sp * red[8] * xv;
  if (d == 0) { Cs[m] = red[9]; ssq[m] = red[10]; }
}

// ---------------- grid edge weights wr/wd ----------------
__global__ __launch_bounds__(256) void gridw_kernel(
    const float* __restrict__ xs, const float* __restrict__ ssq,
    float* __restrict__ wrg, float* __restrict__ wdg) {
  int m = blockIdx.x, d = threadIdx.x;
  int l = m & (LB - 1);
  int r = l >> 6, c = l & 63;
  float a = xs[(size_t)m * 256 + d];
  float br = (c < 63) ? xs[(size_t)(m + 1) * 256 + d] : 0.f;
  float bd = (r < 63) ? xs[(size_t)(m + 64) * 256 + d] : 0.f;
  float s1 = warp_sum(a * br);
  float s2 = warp_sum(a * bd);
  __shared__ float sm[4][2];
  int wv = d >> 6;
  if ((d & 63) == 0) { sm[wv][0] = s1; sm[wv][1] = s2; }
  __syncthreads();
  if (d == 0) {
    float dotr = sm[0][0] + sm[1][0] + sm[2][0] + sm[3][0];
    float dotd = sm[0][1] + sm[1][1] + sm[2][1] + sm[3][1];
    float na = sqrtf(ssq[m]);
    float wrv = BIGF, wdv = BIGF;
    if (c < 63) { float den = fmaxf(na * sqrtf(ssq[m + 1]), 1e-8f);  wrv = expf(-(dotr / den)); }
    if (r < 63) { float den = fmaxf(na * sqrtf(ssq[m + 64]), 1e-8f); wdv = expf(-(dotd / den)); }
    wrg[m] = wrv; wdg[m] = wdv;
  }
}

// ---------------- Boruvka MST (unique MST == Prim's tree) + BFS root + levels ----------------
// Outputs position-space arrays for the scan:
//   levn16[pos] = node | childmask<<12   (mask bits: 1=N(v-64),2=W(v-1),4=E(v+1),8=S(v+64))
//   parn16[pos] = par[node]
__global__ __launch_bounds__(1024) void mst_kernel(
    const float* __restrict__ wr_g, const float* __restrict__ wd_g,
    unsigned short* __restrict__ levn16_g, unsigned short* __restrict__ parn16_g,
    int* __restrict__ levs_g) {
  __shared__ float wrs[4096];
  __shared__ float wds[4096];
  __shared__ int comp[4096];
  __shared__ int lnk[4096];
  __shared__ unsigned int bestw[4096];
  __shared__ int beste[4096];
  __shared__ unsigned char flagR[4096];
  __shared__ unsigned char flagD[4096];
  __shared__ int ncomp_s, nlab_s;
  __shared__ int wred[16];
  int b = blockIdx.x, tid = threadIdx.x;
  const float* wrb = wr_g + b * 4096;
  const float* wdb = wd_g + b * 4096;
  for (int k = 0; k < 4; ++k) {
    int i = tid + k * 1024;
    wrs[i] = wrb[i]; wds[i] = wdb[i];
    comp[i] = i; flagR[i] = 0; flagD[i] = 0;
  }
  __syncthreads();
  // ---- Boruvka phases ----
  for (int phase = 0; phase < 13; ++phase) {
    for (int k = 0; k < 4; ++k) {
      int c = tid + k * 1024;
      bestw[c] = 0xFFFFFFFFu; beste[c] = 0x7FFFFFFF; lnk[c] = c;
    }
    if (tid == 0) ncomp_s = 0;
    __syncthreads();
    // pass A: per-component min weight
    for (int k = 0; k < 8; ++k) {
      int e = tid + k * 1024;
      int v = e & 4095;
      bool isR = e < 4096;
      int c = v & 63, r = v >> 6;
      bool valid = isR ? (c < 63) : (r < 63);
      if (valid) {
        int u = isR ? v + 1 : v + 64;
        int ca = comp[v], cb = comp[u];
        if (ca != cb) {
          unsigned wbits = __float_as_uint(isR ? wrs[v] : wds[v]);
          atomicMin(&bestw[ca], wbits);
          atomicMin(&bestw[cb], wbits);
        }
      }
    }
    __syncthreads();
    // pass B: min edge id among tied-min weights (deterministic)
    for (int k = 0; k < 8; ++k) {
      int e = tid + k * 1024;
      int v = e & 4095;
      bool isR = e < 4096;
      int c = v & 63, r = v >> 6;
      bool valid = isR ? (c < 63) : (r < 63);
      if (valid) {
        int u = isR ? v + 1 : v + 64;
        int ca = comp[v], cb = comp[u];
        if (ca != cb) {
          unsigned wbits = __float_as_uint(isR ? wrs[v] : wds[v]);
          if (wbits == bestw[ca]) atomicMin(&beste[ca], e);
          if (wbits == bestw[cb]) atomicMin(&beste[cb], e);
        }
      }
    }
    __syncthreads();
    // hook + flag chosen edges
    for (int k = 0; k < 4; ++k) {
      int cc = tid + k * 1024;
      int e = beste[cc];
      if (e != 0x7FFFFFFF) {
        int v = e & 4095;
        bool isR = e < 4096;
        int u = isR ? v + 1 : v + 64;
        if (isR) flagR[v] = 1; else flagD[v] = 1;
        int ca = comp[v], cb = comp[u];
        lnk[cc] = (ca == cc) ? cb : ca;
      }
    }
    __syncthreads();
    // break 2-cycles (smaller label becomes root)
    for (int k = 0; k < 4; ++k) {
      int cc = tid + k * 1024;
      int l = lnk[cc];
      if (l != cc && lnk[l] == cc && cc < l) lnk[cc] = cc;
    }
    __syncthreads();
    // pointer jumping
    for (int it = 0; it < 12; ++it) {
      for (int k = 0; k < 4; ++k) {
        int cc = tid + k * 1024;
        lnk[cc] = lnk[lnk[cc]];
      }
      __syncthreads();
    }
    // relabel + count roots
    for (int k = 0; k < 4; ++k) {
      int i = tid + k * 1024;
      comp[i] = lnk[comp[i]];
      if (comp[i] == i) atomicAdd(&ncomp_s, 1);
    }
    __syncthreads();
    if (ncomp_s <= 1) break;
    __syncthreads();
  }
  // ---- BFS rooting at node 0 (level-synchronous, race-free) ----
  int* dep = (int*)bestw;
  int* par = beste;
  for (int k = 0; k < 4; ++k) {
    int i = tid + k * 1024;
    dep[i] = (i == 0) ? 0 : -1;
    par[i] = 0;
  }
  if (tid == 0) nlab_s = 1;
  __syncthreads();
  for (int lev = 0; lev < 4096; ++lev) {
    for (int k = 0; k < 4; ++k) {
      int v = tid + k * 1024;
      if (dep[v] == -1) {
        int c = v & 63, r = v >> 6;
        int pu = -1;
        if (c < 63 && flagR[v]      && dep[v + 1]  == lev) pu = v + 1;
        if (c > 0  && flagR[v - 1]  && dep[v - 1]  == lev) pu = v - 1;
        if (r < 63 && flagD[v]      && dep[v + 64] == lev) pu = v + 64;
        if (r > 0  && flagD[v - 64] && dep[v - 64] == lev) pu = v - 64;
        if (pu >= 0) { dep[v] = lev + 1; par[v] = pu; atomicAdd(&nlab_s, 1); }
      }
    }
    __syncthreads();
    if (nlab_s == 4096) break;
    __syncthreads();
  }
  // ---- max depth ----
  int md = 0;
  for (int k = 0; k < 4; ++k) md = max(md, dep[tid + k * 1024]);
#pragma unroll
  for (int off = 32; off; off >>= 1) md = max(md, __shfl_xor(md, off));
  if ((tid & 63) == 0) wred[tid >> 6] = md;
  __syncthreads();
  if (tid == 0) {
    int m = 0;
    for (int i = 0; i < 16; ++i) m = max(m, wred[i]);
    wred[0] = m;
  }
  __syncthreads();
  int maxd = wred[0];
  __syncthreads();
  // ---- histogram + exclusive prefix over 4096 depth buckets ----
  int* cnt = comp;
  int* offs = lnk;
  for (int k = 0; k < 4; ++k) cnt[tid + k * 1024] = 0;
  __syncthreads();
  for (int k = 0; k < 4; ++k) atomicAdd(&cnt[dep[tid + k * 1024]], 1);
  __syncthreads();
  int base4 = tid * 4;
  int c0 = cnt[base4], c1 = cnt[base4 + 1], c2 = cnt[base4 + 2], c3 = cnt[base4 + 3];
  int tsum = c0 + c1 + c2 + c3;
  int lane = tid & 63, wid = tid >> 6;
  int iv = tsum;
  for (int off = 1; off < 64; off <<= 1) {
    int n = __shfl_up(iv, off);
    if (lane >= off) iv += n;
  }
  if (lane == 63) wred[wid] = iv;
  __syncthreads();
  if (tid == 0) {
    int acc = 0;
    for (int i = 0; i < 16; ++i) { int t = wred[i]; wred[i] = acc; acc += t; }
  }
  __syncthreads();
  int excl = iv - tsum + wred[wid];
  offs[base4]     = excl;
  offs[base4 + 1] = excl + c0;
  offs[base4 + 2] = excl + c0 + c1;
  offs[base4 + 3] = excl + c0 + c1 + c2;
  __syncthreads();
  for (int idx = tid; idx <= maxd; idx += 1024) levs_g[b * LSP + idx] = offs[idx];
  if (tid == 0) {
    levs_g[b * LSP + maxd + 1] = 4096;
    levs_g[b * LSP + 4098] = maxd + 1;
  }
  __syncthreads();   // levs_g copy must finish reading offs before scatter mutates it
  // ---- scatter nodes by level: write node|childmask and parent-node by position ----
  for (int k = 0; k < 4; ++k) {
    int v2 = tid + k * 1024;
    int pos = atomicAdd(&offs[dep[v2]], 1);
    int c = v2 & 63, r = v2 >> 6;
    unsigned msk = 0;
    if (r > 0  && par[v2 - 64] == v2) msk |= 1;
    if (c > 0  && par[v2 - 1]  == v2) msk |= 2;
    if (c < 63 && par[v2 + 1]  == v2) msk |= 4;
    if (r < 63 && par[v2 + 64] == v2) msk |= 8;
    levn16_g[b * 4096 + pos] = (unsigned short)(v2 | (msk << 12));
    parn16_g[b * 4096 + pos] = (unsigned short)par[v2];
  }
}

// ---------------- LDS-resident level-parallel tree scan (2-hop levels) ----------------
// grid (NB, 64): block (b, cg) owns channels [cg*4, cg*4+4).
// All level-loop state in LDS; small consecutive levels run on wave 0 with no barrier.
__global__ __launch_bounds__(1024) void scan_kernel(
    float* __restrict__ buf, const float* __restrict__ ew,
    const unsigned short* __restrict__ levn16_g,
    const unsigned short* __restrict__ parn16_g,
    const int* __restrict__ levs_g) {
  __shared__ float bl[16384];
  __shared__ float el[16384];
  __shared__ unsigned short lv[4096];    // node | childmask<<12, by position
  __shared__ unsigned short pn[4096];    // parent node id, by position
  __shared__ unsigned short lvs[4104];   // level starts
  int b = blockIdx.x;
  int cb = blockIdx.y * 4;
  int tid = threadIdx.x;
  int nlev = levs_g[b * LSP + 4098];
  size_t base = (size_t)b * 4096;
  // stage (float4 per node)
  for (int i = tid; i < 4096; i += 1024) {
    size_t g = (base + i) * 64 + (cb >> 2);
    reinterpret_cast<float4*>(bl)[i] = reinterpret_cast<const float4*>(buf)[g];
    reinterpret_cast<float4*>(el)[i] = reinterpret_cast<const float4*>(ew)[g];
    lv[i] = levn16_g[b * 4096 + i];
    pn[i] = parn16_g[b * 4096 + i];
  }
  for (int i = tid; i <= nlev; i += 1024) lvs[i] = (unsigned short)levs_g[b * LSP + i];
  __syncthreads();
  int ch = tid & 3, slot = tid >> 2;
  // ---- up: parent gathers children via childmask (order N,W,E,S = prior kernel) ----
  bool prev_small = true;   // staging barrier just happened
  for (int lev = nlev - 2; lev >= 0; --lev) {
    int s = lvs[lev], e = lvs[lev + 1];
    bool small = (e - s) <= 16;
    if (!(small && prev_small)) __syncthreads();
    for (int j = s + slot; j < e; j += 256) {
      unsigned vm = lv[j];
      int p = vm & 4095;
      unsigned msk = vm >> 12;
      float acc = bl[p * 4 + ch];
      if (msk & 1) { int u = p - 64; acc += el[u * 4 + ch] * bl[u * 4 + ch]; }
      if (msk & 2) { int u = p - 1;  acc += el[u * 4 + ch] * bl[u * 4 + ch]; }
      if (msk & 4) { int u = p + 1;  acc += el[u * 4 + ch] * bl[u * 4 + ch]; }
      if (msk & 8) { int u = p + 64; acc += el[u * 4 + ch] * bl[u * 4 + ch]; }
      bl[p * 4 + ch] = acc;
    }
    prev_small = small;
  }
  __syncthreads();
  prev_small = true;
  // ---- down: out[v] = up[v] + w*(out[p] - w*up[v]) ----
  for (int lev = 1; lev < nlev; ++lev) {
    int s = lvs[lev], e = lvs[lev + 1];
    bool small = (e - s) <= 16;
    if (!(small && prev_small)) __syncthreads();
    for (int j = s + slot; j < e; j += 256) {
      int v = lv[j] & 4095;
      int p = pn[j];
      float w = el[v * 4 + ch];
      float uv = bl[v * 4 + ch];
      bl[v * 4 + ch] = uv + w * (bl[p * 4 + ch] - w * uv);
    }
    prev_small = small;
  }
  __syncthreads();
  // write back
  for (int i = tid; i < 4096; i += 1024) {
    size_t g = (base + i) * 64 + (cb >> 2);
    reinterpret_cast<float4*>(buf)[g] = reinterpret_cast<const float4*>(bl)[i];
  }
}

// ---------------- post-scan: LN(d=256) -> *Cs + ds*xs -> LN -> *z ----------------
__global__ __launch_bounds__(256) void post_kernel(
    const float* __restrict__ buf, const float* __restrict__ Cs,
    const float* __restrict__ xs, const float* __restrict__ ds,
    const float* __restrict__ hng, const float* __restrict__ hnb,
    const float* __restrict__ ong, const float* __restrict__ onb,
    float* __restrict__ zya) {
  int m = blockIdx.x, d = threadIdx.x;
  size_t idx = (size_t)m * 256 + d;
  float fo = buf[idx];
  float mu = block_sum256(fo) * (1.f / 256.f);
  float dv = fo - mu;
  float var = block_sum256(dv * dv) * (1.f / 256.f);
  float ho = dv * (1.0f / sqrtf(var + 1e-5f)) * hng[d] + hnb[d];
  float y = ho * Cs[m] + ds[d] * xs[idx];
  float mu2 = block_sum256(y) * (1.f / 256.f);
  float dy = y - mu2;
  float var2 = block_sum256(dy * dy) * (1.f / 256.f);
  float y2 = dy * (1.0f / sqrtf(var2 + 1e-5f)) * ong[d] + onb[d];
  zya[idx] = y2 * zya[idx];     // ya = y * z (in place over z)
}

// ---------------- launcher ----------------
extern "C" void kernel_launch(void* const* d_in, const int* in_sizes, int n_in,
                              void* d_out, int out_size, void* d_ws, size_t ws_size,
                              hipStream_t stream) {
  (void)in_sizes; (void)n_in; (void)out_size; (void)ws_size;
  const float* x      = (const float*)d_in[0];
  const float* ln1g   = (const float*)d_in[1];
  const float* ln1b   = (const float*)d_in[2];
  const float* ln2g   = (const float*)d_in[3];
  const float* ln2b   = (const float*)d_in[4];
  const float* w_in   = (const float*)d_in[5];
  const float* conv_w = (const float*)d_in[6];
  const float* xw     = (const float*)d_in[7];
  const float* dtw    = (const float*)d_in[8];
  const float* dtb    = (const float*)d_in[9];
  const float* alogs  = (const float*)d_in[10];
  const float* dsv    = (const float*)d_in[11];
  const float* hng    = (const float*)d_in[12];
  const float* hnb    = (const float*)d_in[13];
  const float* ong    = (const float*)d_in[14];
  const float* onb    = (const float*)d_in[15];
  const float* w_out  = (const float*)d_in[16];
  const float* mw1    = (const float*)d_in[17];
  const float* mb1    = (const float*)d_in[18];
  const float* mw2    = (const float*)d_in[19];
  const float* mb2    = (const float*)d_in[20];

  char* ws = (char*)d_ws;
  float* h    = (float*)(ws + 0);            // 16MB (h, later x1)
  float* z    = (float*)(ws + 16777216);     // 33.5MB (z, later ya in-place)
  float* xcp  = (float*)(ws + 50331648);     // 33.5MB (xc_pre, later h2)
  float* xs   = (float*)(ws + 83886080);     // 33.5MB
  float* dA   = (float*)(ws + 117440512);    // 33.5MB
  float* feat = (float*)(ws + 150994944);    // 33.5MB (feat -> up/out buf)
  float* Cs   = (float*)(ws + 184549376);
  float* ssq  = (float*)(ws + 184680448);
  float* wr   = (float*)(ws + 184811520);
  float* wd   = (float*)(ws + 184942592);
  unsigned short* levn16 = (unsigned short*)(ws + 185073664);   // 64KB
  unsigned short* parn16 = (unsigned short*)(ws + 185204736);   // 64KB
  int*   levs = (int*)(ws + 185335808);
  float* midg = xs;      // 67MB spans xs+dA (both dead by then)
  float* x1   = h;
  float* h2   = xcp;

  ln128_kernel<<<MROWS / 4, 256, 0, stream>>>(x, ln1g, ln1b, h, 1e-6f);
  gemm_kernel<1><<<dim3(8, 512), 256, 0, stream>>>(h, w_in, xcp, z, nullptr, nullptr,
                                                   MROWS, 512, 128);
  convfeat_kernel<<<MROWS, 256, 0, stream>>>(xcp, conv_w, xw, dtw, dtb, alogs,
                                             xs, dA, feat, Cs, ssq);
  gridw_kernel<<<MROWS, 256, 0, stream>>>(xs, ssq, wr, wd);
  mst_kernel<<<NB, 1024, 0, stream>>>(wr, wd, levn16, parn16, levs);
  scan_kernel<<<dim3(NB, 64), 1024, 0, stream>>>(feat, dA, levn16, parn16, levs);
  post_kernel<<<MROWS, 256, 0, stream>>>(feat, Cs, xs, dsv, hng, hnb, ong, onb, z);
  gemm_kernel<2><<<dim3(2, 512), 256, 0, stream>>>(z, w_out, x1, nullptr, nullptr, x,
                                                   MROWS, 128, 256);
  ln128_kernel<<<MROWS / 4, 256, 0, stream>>>(x1, ln2g, ln2b, h2, 1e-6f);
  gemm_kernel<3><<<dim3(8, 512), 256, 0, stream>>>(h2, mw1, midg, nullptr, mb1, nullptr,
                                                   MROWS, 512, 128);
  gemm_kernel<4><<<dim3(2, 512), 256, 0, stream>>>(midg, mw2, (float*)d_out, nullptr,
                                                   mb2, x1, MROWS, 128, 512);
}

// Round 7
// 1096.535 us; speedup vs baseline: 6.2666x; 1.3504x over previous
//
#include <hip/hip_runtime.h>
#include <hip/hip_bf16.h>
#include <cstdint>

#define BIGF 1e30f
constexpr int LB   = 4096;           // L = H*W
constexpr int NB   = 8;              // batch
constexpr int MROWS = NB * LB;       // 32768 pixel rows
constexpr int LSP  = 4104;           // level-start stride per batch

// ---------------- helpers ----------------
__device__ __forceinline__ float warp_sum(float v) {
#pragma unroll
  for (int off = 32; off; off >>= 1) v += __shfl_xor(v, off);
  return v;
}

__device__ __forceinline__ float block_sum256(float v) {
  __shared__ float sm[4];
  v = warp_sum(v);
  __syncthreads();
  if ((threadIdx.x & 63) == 0) sm[threadIdx.x >> 6] = v;
  __syncthreads();
  return sm[0] + sm[1] + sm[2] + sm[3];
}

// ---------------- LayerNorm over last dim 128 ----------------
__global__ __launch_bounds__(256) void ln128_kernel(
    const float* __restrict__ X, const float* __restrict__ g,
    const float* __restrict__ bb, float* __restrict__ O, float eps) {
  int wave = threadIdx.x >> 6, lane = threadIdx.x & 63;
  int row = blockIdx.x * 4 + wave;
  const float* xr = X + (size_t)row * 128;
  float x0 = xr[lane], x1 = xr[lane + 64];
  float mu = warp_sum(x0 + x1) * (1.0f / 128.0f);
  float d0 = x0 - mu, d1 = x1 - mu;
  float var = warp_sum(d0 * d0 + d1 * d1) * (1.0f / 128.0f);
  float s = 1.0f / sqrtf(var + eps);
  float* orow = O + (size_t)row * 128;
  orow[lane]      = d0 * s * g[lane]      + bb[lane];
  orow[lane + 64] = d1 * s * g[lane + 64] + bb[lane + 64];
}

// ---------------- generic f32 GEMM: C = A[M,K] @ W[N,K]^T, fused epilogues ----------------
template<int EPI>
__global__ __launch_bounds__(256) void gemm_kernel(
    const float* __restrict__ A, const float* __restrict__ W,
    float* __restrict__ C, float* __restrict__ C2,
    const float* __restrict__ bias, const float* __restrict__ addsrc,
    int M, int N, int K) {
  __shared__ float As[32][68];
  __shared__ float Bs[32][68];
  int t = threadIdx.x;
  int tx = t & 15, ty = t >> 4;
  int bm = blockIdx.y * 64, bn = blockIdx.x * 64;
  float acc[4][4] = {};
  for (int k0 = 0; k0 < K; k0 += 32) {
#pragma unroll
    for (int hh = 0; hh < 2; ++hh) {
      int q = t + hh * 256;
      int r = q >> 3, kc = q & 7;
      float4 a4 = reinterpret_cast<const float4*>(A + (size_t)(bm + r) * K + k0)[kc];
      float4 b4 = reinterpret_cast<const float4*>(W + (size_t)(bn + r) * K + k0)[kc];
      As[kc * 4 + 0][r] = a4.x; As[kc * 4 + 1][r] = a4.y;
      As[kc * 4 + 2][r] = a4.z; As[kc * 4 + 3][r] = a4.w;
      Bs[kc * 4 + 0][r] = b4.x; Bs[kc * 4 + 1][r] = b4.y;
      Bs[kc * 4 + 2][r] = b4.z; Bs[kc * 4 + 3][r] = b4.w;
    }
    __syncthreads();
#pragma unroll
    for (int kk = 0; kk < 32; ++kk) {
      float4 av = *reinterpret_cast<const float4*>(&As[kk][ty * 4]);
      float4 bv = *reinterpret_cast<const float4*>(&Bs[kk][tx * 4]);
      float aa[4] = {av.x, av.y, av.z, av.w};
      float bbv[4] = {bv.x, bv.y, bv.z, bv.w};
#pragma unroll
      for (int i = 0; i < 4; ++i)
#pragma unroll
        for (int j = 0; j < 4; ++j) acc[i][j] += aa[i] * bbv[j];
    }
    __syncthreads();
  }
#pragma unroll
  for (int i = 0; i < 4; ++i) {
    int m = bm + ty * 4 + i;
#pragma unroll
    for (int j = 0; j < 4; ++j) {
      int n = bn + tx * 4 + j;
      float v = acc[i][j];
      if (EPI == 1) {
        if (n < 256) C[(size_t)m * 256 + n] = v;
        else C2[(size_t)m * 256 + (n - 256)] = v / (1.0f + expf(-v));
      } else if (EPI == 2) {
        C[(size_t)m * N + n] = v + addsrc[(size_t)m * N + n];
      } else if (EPI == 3) {
        float u = v + bias[n];
        C[(size_t)m * N + n] =
            0.5f * u * (1.0f + tanhf(0.7978845608028654f * (u + 0.044715f * u * u * u)));
      } else if (EPI == 4) {
        C[(size_t)m * N + n] = v + bias[n] + addsrc[(size_t)m * N + n];
      }
    }
  }
}

// ---------------- depthwise conv3x3 + silu + x_dbl/dts/deltaA/feat ----------------
__global__ __launch_bounds__(256) void convfeat_kernel(
    const float* __restrict__ xcpre, const float* __restrict__ cw,
    const float* __restrict__ xw, const float* __restrict__ dtw,
    const float* __restrict__ dtb, const float* __restrict__ alogs,
    float* __restrict__ xs, float* __restrict__ dA, float* __restrict__ feat,
    float* __restrict__ Cs, float* __restrict__ ssq) {
  int m = blockIdx.x;
  int d = threadIdx.x;
  int l = m & (LB - 1), b = m >> 12;
  int r = l >> 6, c = l & 63;
  float acc = 0.f;
#pragma unroll
  for (int ky = 0; ky < 3; ++ky) {
    int rr = r + ky - 1;
    if (rr < 0 || rr > 63) continue;
#pragma unroll
    for (int kx = 0; kx < 3; ++kx) {
      int cc = c + kx - 1;
      if (cc < 0 || cc > 63) continue;
      int ml = (b << 12) + (rr << 6) + cc;
      acc += xcpre[(size_t)ml * 256 + d] * cw[d * 9 + ky * 3 + kx];
    }
  }
  float xv = acc / (1.0f + expf(-acc));        // silu
  xs[(size_t)m * 256 + d] = xv;
  float p[11];
#pragma unroll
  for (int i = 0; i < 10; ++i) p[i] = xv * xw[i * 256 + d];
  p[10] = xv * xv;
  __shared__ float sm[4][11];
#pragma unroll
  for (int i = 0; i < 11; ++i) p[i] = warp_sum(p[i]);
  int wv = d >> 6;
  if ((d & 63) == 0) {
    for (int i = 0; i < 11; ++i) sm[wv][i] = p[i];
  }
  __syncthreads();
  float red[11];
#pragma unroll
  for (int i = 0; i < 11; ++i) red[i] = sm[0][i] + sm[1][i] + sm[2][i] + sm[3][i];
  float xdt = dtb[d];
#pragma unroll
  for (int rr2 = 0; rr2 < 8; ++rr2) xdt += red[rr2] * dtw[d * 8 + rr2];
  float sp = fmaxf(xdt, 0.f) + log1pf(expf(-fabsf(xdt)));   // softplus
  float As_ = -expf(alogs[d]);
  dA[(size_t)m * 256 + d] = expf(sp * As_);
  feat[(size_t)m * 256 + d] = sp * red[8] * xv;
  if (d == 0) { Cs[m] = red[9]; ssq[m] = red[10]; }
}

// ---------------- grid edge weights wr/wd ----------------
__global__ __launch_bounds__(256) void gridw_kernel(
    const float* __restrict__ xs, const float* __restrict__ ssq,
    float* __restrict__ wrg, float* __restrict__ wdg) {
  int m = blockIdx.x, d = threadIdx.x;
  int l = m & (LB - 1);
  int r = l >> 6, c = l & 63;
  float a = xs[(size_t)m * 256 + d];
  float br = (c < 63) ? xs[(size_t)(m + 1) * 256 + d] : 0.f;
  float bd = (r < 63) ? xs[(size_t)(m + 64) * 256 + d] : 0.f;
  float s1 = warp_sum(a * br);
  float s2 = warp_sum(a * bd);
  __shared__ float sm[4][2];
  int wv = d >> 6;
  if ((d & 63) == 0) { sm[wv][0] = s1; sm[wv][1] = s2; }
  __syncthreads();
  if (d == 0) {
    float dotr = sm[0][0] + sm[1][0] + sm[2][0] + sm[3][0];
    float dotd = sm[0][1] + sm[1][1] + sm[2][1] + sm[3][1];
    float na = sqrtf(ssq[m]);
    float wrv = BIGF, wdv = BIGF;
    if (c < 63) { float den = fmaxf(na * sqrtf(ssq[m + 1]), 1e-8f);  wrv = expf(-(dotr / den)); }
    if (r < 63) { float den = fmaxf(na * sqrtf(ssq[m + 64]), 1e-8f); wdv = expf(-(dotd / den)); }
    wrg[m] = wrv; wdg[m] = wdv;
  }
}

// ---------------- Boruvka MST + Euler-tour rooting (O(log V)) + levels ----------------
// Outputs position-space arrays for the scan:
//   levn16[pos] = node | childmask<<12   (mask bits: 1=N,2=W,4=E,8=S)
//   parn16[pos] = par[node]
// Directions: 0=N(-64), 1=W(-1), 2=E(+1), 3=S(+64); rev(d)=3-d.
__global__ __launch_bounds__(1024) void mst_kernel(
    const float* __restrict__ wr_g, const float* __restrict__ wd_g,
    unsigned short* __restrict__ levn16_g, unsigned short* __restrict__ parn16_g,
    int* __restrict__ levs_g) {
  __shared__ int pool[24592];          // 98.4 KB, phase-overlaid
  __shared__ unsigned char flagR[4096];
  __shared__ unsigned char flagD[4096];
  __shared__ int ncomp_s;
  __shared__ int wred[16];
  int b = blockIdx.x, tid = threadIdx.x;
  // ---- phase A layout (Boruvka) ----
  float* wrs = (float*)pool;
  float* wds = (float*)(pool + 4096);
  int* comp = pool + 8192;
  int* lnk  = pool + 12288;
  unsigned int* bestw = (unsigned int*)(pool + 16384);
  int* beste = pool + 20480;
  const float* wrb = wr_g + b * 4096;
  const float* wdb = wd_g + b * 4096;
  for (int k = 0; k < 4; ++k) {
    int i = tid + k * 1024;
    wrs[i] = wrb[i]; wds[i] = wdb[i];
    comp[i] = i; flagR[i] = 0; flagD[i] = 0;
  }
  __syncthreads();
  for (int phase = 0; phase < 13; ++phase) {
    for (int k = 0; k < 4; ++k) {
      int c = tid + k * 1024;
      bestw[c] = 0xFFFFFFFFu; beste[c] = 0x7FFFFFFF; lnk[c] = c;
    }
    if (tid == 0) ncomp_s = 0;
    __syncthreads();
    // pass A: per-component min weight
    for (int k = 0; k < 8; ++k) {
      int e = tid + k * 1024;
      int v = e & 4095;
      bool isR = e < 4096;
      int c = v & 63, r = v >> 6;
      bool valid = isR ? (c < 63) : (r < 63);
      if (valid) {
        int u = isR ? v + 1 : v + 64;
        int ca = comp[v], cb = comp[u];
        if (ca != cb) {
          unsigned wbits = __float_as_uint(isR ? wrs[v] : wds[v]);
          atomicMin(&bestw[ca], wbits);
          atomicMin(&bestw[cb], wbits);
        }
      }
    }
    __syncthreads();
    // pass B: min edge id among tied-min weights
    for (int k = 0; k < 8; ++k) {
      int e = tid + k * 1024;
      int v = e & 4095;
      bool isR = e < 4096;
      int c = v & 63, r = v >> 6;
      bool valid = isR ? (c < 63) : (r < 63);
      if (valid) {
        int u = isR ? v + 1 : v + 64;
        int ca = comp[v], cb = comp[u];
        if (ca != cb) {
          unsigned wbits = __float_as_uint(isR ? wrs[v] : wds[v]);
          if (wbits == bestw[ca]) atomicMin(&beste[ca], e);
          if (wbits == bestw[cb]) atomicMin(&beste[cb], e);
        }
      }
    }
    __syncthreads();
    // hook + flag chosen edges
    for (int k = 0; k < 4; ++k) {
      int cc = tid + k * 1024;
      int e = beste[cc];
      if (e != 0x7FFFFFFF) {
        int v = e & 4095;
        bool isR = e < 4096;
        int u = isR ? v + 1 : v + 64;
        if (isR) flagR[v] = 1; else flagD[v] = 1;
        int ca = comp[v], cb = comp[u];
        lnk[cc] = (ca == cc) ? cb : ca;
      }
    }
    __syncthreads();
    // break 2-cycles
    for (int k = 0; k < 4; ++k) {
      int cc = tid + k * 1024;
      int l = lnk[cc];
      if (l != cc && lnk[l] == cc && cc < l) lnk[cc] = cc;
    }
    __syncthreads();
    // pointer jumping
    for (int it = 0; it < 12; ++it) {
      for (int k = 0; k < 4; ++k) {
        int cc = tid + k * 1024;
        lnk[cc] = lnk[lnk[cc]];
      }
      __syncthreads();
    }
    // relabel + count roots
    for (int k = 0; k < 4; ++k) {
      int i = tid + k * 1024;
      comp[i] = lnk[comp[i]];
      if (comp[i] == i) atomicAdd(&ncomp_s, 1);
    }
    __syncthreads();
    if (ncomp_s <= 1) break;
    __syncthreads();
  }
  // ---- phase B layout (Euler tour; overlays dead Boruvka arrays) ----
  unsigned short* nxt = (unsigned short*)pool;        // [16400]
  short*          dsv = (short*)(pool + 8200);        // [16400]
  int* par = pool + 16400;                            // [4096]
  int* dep = pool + 20496;                            // [4096]
  const int NIL = 16384;
  unsigned short rn[16];
  int rd[16];
  int validm = 0;
  // pass-1 build: next pointers + unit weights; init par/dep
  for (int k = 0; k < 4; ++k) { int i = tid + k * 1024; par[i] = 0; dep[i] = 0; }
#pragma unroll
  for (int k = 0; k < 16; ++k) {
    int a = tid + k * 1024;
    int u = a >> 2, d = a & 3;
    int c = u & 63, r = u >> 6;
    int mu = 0;
    if (r > 0  && flagD[u - 64]) mu |= 1;
    if (c > 0  && flagR[u - 1])  mu |= 2;
    if (c < 63 && flagR[u])      mu |= 4;
    if (r < 63 && flagD[u])      mu |= 8;
    unsigned short nx = NIL; short dv = 0;
    if (mu & (1 << d)) {
      validm |= 1 << k;
      int v = u + ((d == 0) ? -64 : (d == 1) ? -1 : (d == 2) ? 1 : 64);
      int cv = v & 63, rv = v >> 6;
      int mv = 0;
      if (rv > 0  && flagD[v - 64]) mv |= 1;
      if (cv > 0  && flagR[v - 1])  mv |= 2;
      if (cv < 63 && flagR[v])      mv |= 4;
      if (rv < 63 && flagD[v])      mv |= 8;
      int din = 3 - d;
      int hi = mv >> (din + 1);
      int dn = hi ? (din + __ffs(hi)) : (__ffs(mv) - 1);
      int nxv = v * 4 + dn;
      int m0 = (flagR[0] ? 4 : 0) | (flagD[0] ? 8 : 0);
      int a0 = __ffs(m0) - 1;                 // start arc (root node 0)
      if (v == 0 && nxv == a0) nxv = NIL;     // break circuit before start
      nx = (unsigned short)nxv;
      dv = 1;
    }
    nxt[a] = nx; dsv[a] = dv;
    rn[k] = nx; rd[k] = dv;
  }
  if (tid == 0) { nxt[NIL] = NIL; dsv[NIL] = 0; }
  __syncthreads();
  // pass-1 list ranking: dsv -> suffix length (pos smaller <=> dsv larger)
#pragma unroll 1
  for (int it = 0; it < 13; ++it) {
    unsigned short nn[16]; short nd[16];
#pragma unroll
    for (int k = 0; k < 16; ++k) { nn[k] = nxt[rn[k]]; nd[k] = dsv[rn[k]]; }
    __syncthreads();
#pragma unroll
    for (int k = 0; k < 16; ++k) {
      int a = tid + k * 1024;
      rd[k] += nd[k];
      rn[k] = nn[k];
      nxt[a] = rn[k]; dsv[a] = (short)rd[k];
    }
    __syncthreads();
  }
  // orientation: par[v] = u iff arc u->v earlier than v->u (dsv larger)
#pragma unroll
  for (int k = 0; k < 16; ++k) if (validm & (1 << k)) {
    int a = tid + k * 1024;
    int u = a >> 2, d = a & 3;
    int v = u + ((d == 0) ? -64 : (d == 1) ? -1 : (d == 2) ? 1 : 64);
    int rb = v * 4 + (3 - d);
    if (rd[k] > (int)dsv[rb]) par[v] = u;
  }
  __syncthreads();
  // pass-2 build: same next pointers, weights +1 (down) / -1 (up)
#pragma unroll
  for (int k = 0; k < 16; ++k) {
    int a = tid + k * 1024;
    int u = a >> 2, d = a & 3;
    unsigned short nx = NIL; short dv = 0;
    if (validm & (1 << k)) {
      int v = u + ((d == 0) ? -64 : (d == 1) ? -1 : (d == 2) ? 1 : 64);
      int cv = v & 63, rv = v >> 6;
      int mv = 0;
      if (rv > 0  && flagD[v - 64]) mv |= 1;
      if (cv > 0  && flagR[v - 1])  mv |= 2;
      if (cv < 63 && flagR[v])      mv |= 4;
      if (rv < 63 && flagD[v])      mv |= 8;
      int din = 3 - d;
      int hi = mv >> (din + 1);
      int dn = hi ? (din + __ffs(hi)) : (__ffs(mv) - 1);
      int nxv = v * 4 + dn;
      int m0 = (flagR[0] ? 4 : 0) | (flagD[0] ? 8 : 0);
      int a0 = __ffs(m0) - 1;
      if (v == 0 && nxv == a0) nxv = NIL;
      nx = (unsigned short)nxv;
      dv = (par[v] == u) ? (short)1 : (short)-1;
    }
    nxt[a] = nx; dsv[a] = dv;
    rn[k] = nx; rd[k] = dv;
  }
  __syncthreads();
  // pass-2 weighted ranking: dsv -> suffix sum S(a)
#pragma unroll 1
  for (int it = 0; it < 13; ++it) {
    unsigned short nn[16]; short nd[16];
#pragma unroll
    for (int k = 0; k < 16; ++k) { nn[k] = nxt[rn[k]]; nd[k] = dsv[rn[k]]; }
    __syncthreads();
#pragma unroll
    for (int k = 0; k < 16; ++k) {
      int a = tid + k * 1024;
      rd[k] += nd[k];
      rn[k] = nn[k];
      nxt[a] = rn[k]; dsv[a] = (short)rd[k];
    }
    __syncthreads();
  }
  // depth: dep[v] = 1 - S(par->v)
#pragma unroll
  for (int k = 0; k < 16; ++k) if (validm & (1 << k)) {
    int a = tid + k * 1024;
    int u = a >> 2, d = a & 3;
    int v = u + ((d == 0) ? -64 : (d == 1) ? -1 : (d == 2) ? 1 : 64);
    if (par[v] == u) dep[v] = 1 - rd[k];
  }
  __syncthreads();
  // ---- max depth ----
  int md = 0;
  for (int k = 0; k < 4; ++k) md = max(md, dep[tid + k * 1024]);
#pragma unroll
  for (int off = 32; off; off >>= 1) md = max(md, __shfl_xor(md, off));
  if ((tid & 63) == 0) wred[tid >> 6] = md;
  __syncthreads();
  if (tid == 0) {
    int m = 0;
    for (int i = 0; i < 16; ++i) m = max(m, wred[i]);
    wred[0] = m;
  }
  __syncthreads();
  int maxd = wred[0];
  __syncthreads();
  // ---- histogram + exclusive prefix over depth buckets (cnt/offs overlay dead nxt/dsv) ----
  int* cnt  = pool;
  int* offs = pool + 4096;
  for (int k = 0; k < 4; ++k) cnt[tid + k * 1024] = 0;
  __syncthreads();
  for (int k = 0; k < 4; ++k) atomicAdd(&cnt[dep[tid + k * 1024]], 1);
  __syncthreads();
  int base4 = tid * 4;
  int c0 = cnt[base4], c1 = cnt[base4 + 1], c2 = cnt[base4 + 2], c3 = cnt[base4 + 3];
  int tsum = c0 + c1 + c2 + c3;
  int lane = tid & 63, wid = tid >> 6;
  int iv = tsum;
  for (int off = 1; off < 64; off <<= 1) {
    int n = __shfl_up(iv, off);
    if (lane >= off) iv += n;
  }
  if (lane == 63) wred[wid] = iv;
  __syncthreads();
  if (tid == 0) {
    int acc = 0;
    for (int i = 0; i < 16; ++i) { int t = wred[i]; wred[i] = acc; acc += t; }
  }
  __syncthreads();
  int excl = iv - tsum + wred[wid];
  offs[base4]     = excl;
  offs[base4 + 1] = excl + c0;
  offs[base4 + 2] = excl + c0 + c1;
  offs[base4 + 3] = excl + c0 + c1 + c2;
  __syncthreads();
  for (int idx = tid; idx <= maxd; idx += 1024) levs_g[b * LSP + idx] = offs[idx];
  if (tid == 0) {
    levs_g[b * LSP + maxd + 1] = 4096;
    levs_g[b * LSP + 4098] = maxd + 1;
  }
  __syncthreads();   // levs_g copy must finish reading offs before scatter mutates it
  // ---- scatter nodes by level: node|childmask and parent node, by position ----
  for (int k = 0; k < 4; ++k) {
    int v2 = tid + k * 1024;
    int pos = atomicAdd(&offs[dep[v2]], 1);
    int c = v2 & 63, r = v2 >> 6;
    unsigned msk = 0;
    if (r > 0  && par[v2 - 64] == v2) msk |= 1;
    if (c > 0  && par[v2 - 1]  == v2) msk |= 2;
    if (c < 63 && par[v2 + 1]  == v2) msk |= 4;
    if (r < 63 && par[v2 + 64] == v2) msk |= 8;
    levn16_g[b * 4096 + pos] = (unsigned short)(v2 | (msk << 12));
    parn16_g[b * 4096 + pos] = (unsigned short)par[v2];
  }
}

// ---------------- LDS-resident level-parallel tree scan (2-hop levels) ----------------
__global__ __launch_bounds__(1024) void scan_kernel(
    float* __restrict__ buf, const float* __restrict__ ew,
    const unsigned short* __restrict__ levn16_g,
    const unsigned short* __restrict__ parn16_g,
    const int* __restrict__ levs_g) {
  __shared__ float bl[16384];
  __shared__ float el[16384];
  __shared__ unsigned short lv[4096];
  __shared__ unsigned short pn[4096];
  __shared__ unsigned short lvs[4104];
  int b = blockIdx.x;
  int cb = blockIdx.y * 4;
  int tid = threadIdx.x;
  int nlev = levs_g[b * LSP + 4098];
  size_t base = (size_t)b * 4096;
  for (int i = tid; i < 4096; i += 1024) {
    size_t g = (base + i) * 64 + (cb >> 2);
    reinterpret_cast<float4*>(bl)[i] = reinterpret_cast<const float4*>(buf)[g];
    reinterpret_cast<float4*>(el)[i] = reinterpret_cast<const float4*>(ew)[g];
    lv[i] = levn16_g[b * 4096 + i];
    pn[i] = parn16_g[b * 4096 + i];
  }
  for (int i = tid; i <= nlev; i += 1024) lvs[i] = (unsigned short)levs_g[b * LSP + i];
  __syncthreads();
  int ch = tid & 3, slot = tid >> 2;
  bool prev_small = true;
  for (int lev = nlev - 2; lev >= 0; --lev) {
    int s = lvs[lev], e = lvs[lev + 1];
    bool small = (e - s) <= 16;
    if (!(small && prev_small)) __syncthreads();
    for (int j = s + slot; j < e; j += 256) {
      unsigned vm = lv[j];
      int p = vm & 4095;
      unsigned msk = vm >> 12;
      float acc = bl[p * 4 + ch];
      if (msk & 1) { int u = p - 64; acc += el[u * 4 + ch] * bl[u * 4 + ch]; }
      if (msk & 2) { int u = p - 1;  acc += el[u * 4 + ch] * bl[u * 4 + ch]; }
      if (msk & 4) { int u = p + 1;  acc += el[u * 4 + ch] * bl[u * 4 + ch]; }
      if (msk & 8) { int u = p + 64; acc += el[u * 4 + ch] * bl[u * 4 + ch]; }
      bl[p * 4 + ch] = acc;
    }
    prev_small = small;
  }
  __syncthreads();
  prev_small = true;
  for (int lev = 1; lev < nlev; ++lev) {
    int s = lvs[lev], e = lvs[lev + 1];
    bool small = (e - s) <= 16;
    if (!(small && prev_small)) __syncthreads();
    for (int j = s + slot; j < e; j += 256) {
      int v = lv[j] & 4095;
      int p = pn[j];
      float w = el[v * 4 + ch];
      float uv = bl[v * 4 + ch];
      bl[v * 4 + ch] = uv + w * (bl[p * 4 + ch] - w * uv);
    }
    prev_small = small;
  }
  __syncthreads();
  for (int i = tid; i < 4096; i += 1024) {
    size_t g = (base + i) * 64 + (cb >> 2);
    reinterpret_cast<float4*>(buf)[g] = reinterpret_cast<const float4*>(bl)[i];
  }
}

// ---------------- post-scan: LN(d=256) -> *Cs + ds*xs -> LN -> *z ----------------
__global__ __launch_bounds__(256) void post_kernel(
    const float* __restrict__ buf, const float* __restrict__ Cs,
    const float* __restrict__ xs, const float* __restrict__ ds,
    const float* __restrict__ hng, const float* __restrict__ hnb,
    const float* __restrict__ ong, const float* __restrict__ onb,
    float* __restrict__ zya) {
  int m = blockIdx.x, d = threadIdx.x;
  size_t idx = (size_t)m * 256 + d;
  float fo = buf[idx];
  float mu = block_sum256(fo) * (1.f / 256.f);
  float dv = fo - mu;
  float var = block_sum256(dv * dv) * (1.f / 256.f);
  float ho = dv * (1.0f / sqrtf(var + 1e-5f)) * hng[d] + hnb[d];
  float y = ho * Cs[m] + ds[d] * xs[idx];
  float mu2 = block_sum256(y) * (1.f / 256.f);
  float dy = y - mu2;
  float var2 = block_sum256(dy * dy) * (1.f / 256.f);
  float y2 = dy * (1.0f / sqrtf(var2 + 1e-5f)) * ong[d] + onb[d];
  zya[idx] = y2 * zya[idx];     // ya = y * z (in place over z)
}

// ---------------- launcher ----------------
extern "C" void kernel_launch(void* const* d_in, const int* in_sizes, int n_in,
                              void* d_out, int out_size, void* d_ws, size_t ws_size,
                              hipStream_t stream) {
  (void)in_sizes; (void)n_in; (void)out_size; (void)ws_size;
  const float* x      = (const float*)d_in[0];
  const float* ln1g   = (const float*)d_in[1];
  const float* ln1b   = (const float*)d_in[2];
  const float* ln2g   = (const float*)d_in[3];
  const float* ln2b   = (const float*)d_in[4];
  const float* w_in   = (const float*)d_in[5];
  const float* conv_w = (const float*)d_in[6];
  const float* xw     = (const float*)d_in[7];
  const float* dtw    = (const float*)d_in[8];
  const float* dtb    = (const float*)d_in[9];
  const float* alogs  = (const float*)d_in[10];
  const float* dsv    = (const float*)d_in[11];
  const float* hng    = (const float*)d_in[12];
  const float* hnb    = (const float*)d_in[13];
  const float* ong    = (const float*)d_in[14];
  const float* onb    = (const float*)d_in[15];
  const float* w_out  = (const float*)d_in[16];
  const float* mw1    = (const float*)d_in[17];
  const float* mb1    = (const float*)d_in[18];
  const float* mw2    = (const float*)d_in[19];
  const float* mb2    = (const float*)d_in[20];

  char* ws = (char*)d_ws;
  float* h    = (float*)(ws + 0);            // 16MB (h, later x1)
  float* z    = (float*)(ws + 16777216);     // 33.5MB (z, later ya in-place)
  float* xcp  = (float*)(ws + 50331648);     // 33.5MB (xc_pre, later h2)
  float* xs   = (float*)(ws + 83886080);     // 33.5MB
  float* dA   = (float*)(ws + 117440512);    // 33.5MB
  float* feat = (float*)(ws + 150994944);    // 33.5MB (feat -> up/out buf)
  float* Cs   = (float*)(ws + 184549376);
  float* ssq  = (float*)(ws + 184680448);
  float* wr   = (float*)(ws + 184811520);
  float* wd   = (float*)(ws + 184942592);
  unsigned short* levn16 = (unsigned short*)(ws + 185073664);   // 64KB
  unsigned short* parn16 = (unsigned short*)(ws + 185204736);   // 64KB
  int*   levs = (int*)(ws + 185335808);
  float* midg = xs;      // 67MB spans xs+dA (both dead by then)
  float* x1   = h;
  float* h2   = xcp;

  ln128_kernel<<<MROWS / 4, 256, 0, stream>>>(x, ln1g, ln1b, h, 1e-6f);
  gemm_kernel<1><<<dim3(8, 512), 256, 0, stream>>>(h, w_in, xcp, z, nullptr, nullptr,
                                                   MROWS, 512, 128);
  convfeat_kernel<<<MROWS, 256, 0, stream>>>(xcp, conv_w, xw, dtw, dtb, alogs,
                                             xs, dA, feat, Cs, ssq);
  gridw_kernel<<<MROWS, 256, 0, stream>>>(xs, ssq, wr, wd);
  mst_kernel<<<NB, 1024, 0, stream>>>(wr, wd, levn16, parn16, levs);
  scan_kernel<<<dim3(NB, 64), 1024, 0, stream>>>(feat, dA, levn16, parn16, levs);
  post_kernel<<<MROWS, 256, 0, stream>>>(feat, Cs, xs, dsv, hng, hnb, ong, onb, z);
  gemm_kernel<2><<<dim3(2, 512), 256, 0, stream>>>(z, w_out, x1, nullptr, nullptr, x,
                                                   MROWS, 128, 256);
  ln128_kernel<<<MROWS / 4, 256, 0, stream>>>(x1, ln2g, ln2b, h2, 1e-6f);
  gemm_kernel<3><<<dim3(8, 512), 256, 0, stream>>>(h2, mw1, midg, nullptr, mb1, nullptr,
                                                   MROWS, 512, 128);
  gemm_kernel<4><<<dim3(2, 512), 256, 0, stream>>>(midg, mw2, (float*)d_out, nullptr,
                                                   mb2, x1, MROWS, 128, 512);
}

// Round 8
// 997.188 us; speedup vs baseline: 6.8909x; 1.0996x over previous
//
#include <hip/hip_runtime.h>
#include <hip/hip_bf16.h>
#include <cstdint>

#define BIGF 1e30f
constexpr int LB   = 4096;           // L = H*W
constexpr int NB   = 8;              // batch
constexpr int MROWS = NB * LB;       // 32768 pixel rows
constexpr int LSP  = 4104;           // level-start stride per batch

// ---------------- helpers ----------------
__device__ __forceinline__ float warp_sum(float v) {
#pragma unroll
  for (int off = 32; off; off >>= 1) v += __shfl_xor(v, off);
  return v;
}

__device__ __forceinline__ float block_sum256(float v) {
  __shared__ float sm[4];
  v = warp_sum(v);
  __syncthreads();
  if ((threadIdx.x & 63) == 0) sm[threadIdx.x >> 6] = v;
  __syncthreads();
  return sm[0] + sm[1] + sm[2] + sm[3];
}

// ---------------- LayerNorm over last dim 128 ----------------
__global__ __launch_bounds__(256) void ln128_kernel(
    const float* __restrict__ X, const float* __restrict__ g,
    const float* __restrict__ bb, float* __restrict__ O, float eps) {
  int wave = threadIdx.x >> 6, lane = threadIdx.x & 63;
  int row = blockIdx.x * 4 + wave;
  const float* xr = X + (size_t)row * 128;
  float x0 = xr[lane], x1 = xr[lane + 64];
  float mu = warp_sum(x0 + x1) * (1.0f / 128.0f);
  float d0 = x0 - mu, d1 = x1 - mu;
  float var = warp_sum(d0 * d0 + d1 * d1) * (1.0f / 128.0f);
  float s = 1.0f / sqrtf(var + eps);
  float* orow = O + (size_t)row * 128;
  orow[lane]      = d0 * s * g[lane]      + bb[lane];
  orow[lane + 64] = d1 * s * g[lane + 64] + bb[lane + 64];
}

// ---------------- generic f32 GEMM: C = A[M,K] @ W[N,K]^T, fused epilogues ----------------
template<int EPI>
__global__ __launch_bounds__(256) void gemm_kernel(
    const float* __restrict__ A, const float* __restrict__ W,
    float* __restrict__ C, float* __restrict__ C2,
    const float* __restrict__ bias, const float* __restrict__ addsrc,
    int M, int N, int K) {
  __shared__ float As[32][68];
  __shared__ float Bs[32][68];
  int t = threadIdx.x;
  int tx = t & 15, ty = t >> 4;
  int bm = blockIdx.y * 64, bn = blockIdx.x * 64;
  float acc[4][4] = {};
  for (int k0 = 0; k0 < K; k0 += 32) {
#pragma unroll
    for (int hh = 0; hh < 2; ++hh) {
      int q = t + hh * 256;
      int r = q >> 3, kc = q & 7;
      float4 a4 = reinterpret_cast<const float4*>(A + (size_t)(bm + r) * K + k0)[kc];
      float4 b4 = reinterpret_cast<const float4*>(W + (size_t)(bn + r) * K + k0)[kc];
      As[kc * 4 + 0][r] = a4.x; As[kc * 4 + 1][r] = a4.y;
      As[kc * 4 + 2][r] = a4.z; As[kc * 4 + 3][r] = a4.w;
      Bs[kc * 4 + 0][r] = b4.x; Bs[kc * 4 + 1][r] = b4.y;
      Bs[kc * 4 + 2][r] = b4.z; Bs[kc * 4 + 3][r] = b4.w;
    }
    __syncthreads();
#pragma unroll
    for (int kk = 0; kk < 32; ++kk) {
      float4 av = *reinterpret_cast<const float4*>(&As[kk][ty * 4]);
      float4 bv = *reinterpret_cast<const float4*>(&Bs[kk][tx * 4]);
      float aa[4] = {av.x, av.y, av.z, av.w};
      float bbv[4] = {bv.x, bv.y, bv.z, bv.w};
#pragma unroll
      for (int i = 0; i < 4; ++i)
#pragma unroll
        for (int j = 0; j < 4; ++j) acc[i][j] += aa[i] * bbv[j];
    }
    __syncthreads();
  }
#pragma unroll
  for (int i = 0; i < 4; ++i) {
    int m = bm + ty * 4 + i;
#pragma unroll
    for (int j = 0; j < 4; ++j) {
      int n = bn + tx * 4 + j;
      float v = acc[i][j];
      if (EPI == 1) {
        if (n < 256) C[(size_t)m * 256 + n] = v;
        else C2[(size_t)m * 256 + (n - 256)] = v / (1.0f + expf(-v));
      } else if (EPI == 2) {
        C[(size_t)m * N + n] = v + addsrc[(size_t)m * N + n];
      } else if (EPI == 3) {
        float u = v + bias[n];
        C[(size_t)m * N + n] =
            0.5f * u * (1.0f + tanhf(0.7978845608028654f * (u + 0.044715f * u * u * u)));
      } else if (EPI == 4) {
        C[(size_t)m * N + n] = v + bias[n] + addsrc[(size_t)m * N + n];
      }
    }
  }
}

// ---------------- depthwise conv3x3 + silu + x_dbl/dts/deltaA/feat ----------------
__global__ __launch_bounds__(256) void convfeat_kernel(
    const float* __restrict__ xcpre, const float* __restrict__ cw,
    const float* __restrict__ xw, const float* __restrict__ dtw,
    const float* __restrict__ dtb, const float* __restrict__ alogs,
    float* __restrict__ xs, float* __restrict__ dA, float* __restrict__ feat,
    float* __restrict__ Cs, float* __restrict__ ssq) {
  int m = blockIdx.x;
  int d = threadIdx.x;
  int l = m & (LB - 1), b = m >> 12;
  int r = l >> 6, c = l & 63;
  float acc = 0.f;
#pragma unroll
  for (int ky = 0; ky < 3; ++ky) {
    int rr = r + ky - 1;
    if (rr < 0 || rr > 63) continue;
#pragma unroll
    for (int kx = 0; kx < 3; ++kx) {
      int cc = c + kx - 1;
      if (cc < 0 || cc > 63) continue;
      int ml = (b << 12) + (rr << 6) + cc;
      acc += xcpre[(size_t)ml * 256 + d] * cw[d * 9 + ky * 3 + kx];
    }
  }
  float xv = acc / (1.0f + expf(-acc));        // silu
  xs[(size_t)m * 256 + d] = xv;
  float p[11];
#pragma unroll
  for (int i = 0; i < 10; ++i) p[i] = xv * xw[i * 256 + d];
  p[10] = xv * xv;
  __shared__ float sm[4][11];
#pragma unroll
  for (int i = 0; i < 11; ++i) p[i] = warp_sum(p[i]);
  int wv = d >> 6;
  if ((d & 63) == 0) {
    for (int i = 0; i < 11; ++i) sm[wv][i] = p[i];
  }
  __syncthreads();
  float red[11];
#pragma unroll
  for (int i = 0; i < 11; ++i) red[i] = sm[0][i] + sm[1][i] + sm[2][i] + sm[3][i];
  float xdt = dtb[d];
#pragma unroll
  for (int rr2 = 0; rr2 < 8; ++rr2) xdt += red[rr2] * dtw[d * 8 + rr2];
  float sp = fmaxf(xdt, 0.f) + log1pf(expf(-fabsf(xdt)));   // softplus
  float As_ = -expf(alogs[d]);
  dA[(size_t)m * 256 + d] = expf(sp * As_);
  feat[(size_t)m * 256 + d] = sp * red[8] * xv;
  if (d == 0) { Cs[m] = red[9]; ssq[m] = red[10]; }
}

// ---------------- grid edge weights wr/wd ----------------
__global__ __launch_bounds__(256) void gridw_kernel(
    const float* __restrict__ xs, const float* __restrict__ ssq,
    float* __restrict__ wrg, float* __restrict__ wdg) {
  int m = blockIdx.x, d = threadIdx.x;
  int l = m & (LB - 1);
  int r = l >> 6, c = l & 63;
  float a = xs[(size_t)m * 256 + d];
  float br = (c < 63) ? xs[(size_t)(m + 1) * 256 + d] : 0.f;
  float bd = (r < 63) ? xs[(size_t)(m + 64) * 256 + d] : 0.f;
  float s1 = warp_sum(a * br);
  float s2 = warp_sum(a * bd);
  __shared__ float sm[4][2];
  int wv = d >> 6;
  if ((d & 63) == 0) { sm[wv][0] = s1; sm[wv][1] = s2; }
  __syncthreads();
  if (d == 0) {
    float dotr = sm[0][0] + sm[1][0] + sm[2][0] + sm[3][0];
    float dotd = sm[0][1] + sm[1][1] + sm[2][1] + sm[3][1];
    float na = sqrtf(ssq[m]);
    float wrv = BIGF, wdv = BIGF;
    if (c < 63) { float den = fmaxf(na * sqrtf(ssq[m + 1]), 1e-8f);  wrv = expf(-(dotr / den)); }
    if (r < 63) { float den = fmaxf(na * sqrtf(ssq[m + 64]), 1e-8f); wdv = expf(-(dotd / den)); }
    wrg[m] = wrv; wdg[m] = wdv;
  }
}

// ---------------- Boruvka MST + Euler-tour rooting (O(log V)) + levels ----------------
// Outputs position-space arrays for the scan:
//   levn16[pos] = node | childmask<<12   (mask bits: 1=N,2=W,4=E,8=S)
//   parn16[pos] = par[node]
// Directions: 0=N(-64), 1=W(-1), 2=E(+1), 3=S(+64); rev(d)=3-d.
__global__ __launch_bounds__(1024) void mst_kernel(
    const float* __restrict__ wr_g, const float* __restrict__ wd_g,
    unsigned short* __restrict__ levn16_g, unsigned short* __restrict__ parn16_g,
    int* __restrict__ levs_g) {
  __shared__ int pool[24592];          // 98.4 KB, phase-overlaid
  __shared__ unsigned char flagR[4096];
  __shared__ unsigned char flagD[4096];
  __shared__ int ncomp_s;
  __shared__ int wred[16];
  int b = blockIdx.x, tid = threadIdx.x;
  // ---- phase A layout (Boruvka) ----
  float* wrs = (float*)pool;
  float* wds = (float*)(pool + 4096);
  int* comp = pool + 8192;
  int* lnk  = pool + 12288;
  unsigned int* bestw = (unsigned int*)(pool + 16384);
  int* beste = pool + 20480;
  const float* wrb = wr_g + b * 4096;
  const float* wdb = wd_g + b * 4096;
  for (int k = 0; k < 4; ++k) {
    int i = tid + k * 1024;
    wrs[i] = wrb[i]; wds[i] = wdb[i];
    comp[i] = i; flagR[i] = 0; flagD[i] = 0;
  }
  __syncthreads();
  for (int phase = 0; phase < 13; ++phase) {
    for (int k = 0; k < 4; ++k) {
      int c = tid + k * 1024;
      bestw[c] = 0xFFFFFFFFu; beste[c] = 0x7FFFFFFF; lnk[c] = c;
    }
    if (tid == 0) ncomp_s = 0;
    __syncthreads();
    // pass A: per-component min weight
    for (int k = 0; k < 8; ++k) {
      int e = tid + k * 1024;
      int v = e & 4095;
      bool isR = e < 4096;
      int c = v & 63, r = v >> 6;
      bool valid = isR ? (c < 63) : (r < 63);
      if (valid) {
        int u = isR ? v + 1 : v + 64;
        int ca = comp[v], cb = comp[u];
        if (ca != cb) {
          unsigned wbits = __float_as_uint(isR ? wrs[v] : wds[v]);
          atomicMin(&bestw[ca], wbits);
          atomicMin(&bestw[cb], wbits);
        }
      }
    }
    __syncthreads();
    // pass B: min edge id among tied-min weights
    for (int k = 0; k < 8; ++k) {
      int e = tid + k * 1024;
      int v = e & 4095;
      bool isR = e < 4096;
      int c = v & 63, r = v >> 6;
      bool valid = isR ? (c < 63) : (r < 63);
      if (valid) {
        int u = isR ? v + 1 : v + 64;
        int ca = comp[v], cb = comp[u];
        if (ca != cb) {
          unsigned wbits = __float_as_uint(isR ? wrs[v] : wds[v]);
          if (wbits == bestw[ca]) atomicMin(&beste[ca], e);
          if (wbits == bestw[cb]) atomicMin(&beste[cb], e);
        }
      }
    }
    __syncthreads();
    // hook + flag chosen edges
    for (int k = 0; k < 4; ++k) {
      int cc = tid + k * 1024;
      int e = beste[cc];
      if (e != 0x7FFFFFFF) {
        int v = e & 4095;
        bool isR = e < 4096;
        int u = isR ? v + 1 : v + 64;
        if (isR) flagR[v] = 1; else flagD[v] = 1;
        int ca = comp[v], cb = comp[u];
        lnk[cc] = (ca == cc) ? cb : ca;
      }
    }
    __syncthreads();
    // break 2-cycles
    for (int k = 0; k < 4; ++k) {
      int cc = tid + k * 1024;
      int l = lnk[cc];
      if (l != cc && lnk[l] == cc && cc < l) lnk[cc] = cc;
    }
    __syncthreads();
    // pointer jumping
    for (int it = 0; it < 12; ++it) {
      for (int k = 0; k < 4; ++k) {
        int cc = tid + k * 1024;
        lnk[cc] = lnk[lnk[cc]];
      }
      __syncthreads();
    }
    // relabel + count roots
    for (int k = 0; k < 4; ++k) {
      int i = tid + k * 1024;
      comp[i] = lnk[comp[i]];
      if (comp[i] == i) atomicAdd(&ncomp_s, 1);
    }
    __syncthreads();
    if (ncomp_s <= 1) break;
    __syncthreads();
  }
  // ---- phase B layout (Euler tour; overlays dead Boruvka arrays) ----
  unsigned short* nxt = (unsigned short*)pool;        // [16400]
  short*          dsv = (short*)(pool + 8200);        // [16400]
  int* par = pool + 16400;                            // [4096]
  int* dep = pool + 20496;                            // [4096]
  const int NIL = 16384;
  unsigned short rn[16];
  int rd[16];
  int validm = 0;
  // pass-1 build: next pointers + unit weights; init par/dep
  for (int k = 0; k < 4; ++k) { int i = tid + k * 1024; par[i] = 0; dep[i] = 0; }
#pragma unroll
  for (int k = 0; k < 16; ++k) {
    int a = tid + k * 1024;
    int u = a >> 2, d = a & 3;
    int c = u & 63, r = u >> 6;
    int mu = 0;
    if (r > 0  && flagD[u - 64]) mu |= 1;
    if (c > 0  && flagR[u - 1])  mu |= 2;
    if (c < 63 && flagR[u])      mu |= 4;
    if (r < 63 && flagD[u])      mu |= 8;
    unsigned short nx = NIL; short dv = 0;
    if (mu & (1 << d)) {
      validm |= 1 << k;
      int v = u + ((d == 0) ? -64 : (d == 1) ? -1 : (d == 2) ? 1 : 64);
      int cv = v & 63, rv = v >> 6;
      int mv = 0;
      if (rv > 0  && flagD[v - 64]) mv |= 1;
      if (cv > 0  && flagR[v - 1])  mv |= 2;
      if (cv < 63 && flagR[v])      mv |= 4;
      if (rv < 63 && flagD[v])      mv |= 8;
      int din = 3 - d;
      int hi = mv >> (din + 1);
      int dn = hi ? (din + __ffs(hi)) : (__ffs(mv) - 1);
      int nxv = v * 4 + dn;
      int m0 = (flagR[0] ? 4 : 0) | (flagD[0] ? 8 : 0);
      int a0 = __ffs(m0) - 1;                 // start arc (root node 0)
      if (v == 0 && nxv == a0) nxv = NIL;     // break circuit before start
      nx = (unsigned short)nxv;
      dv = 1;
    }
    nxt[a] = nx; dsv[a] = dv;
    rn[k] = nx; rd[k] = dv;
  }
  if (tid == 0) { nxt[NIL] = NIL; dsv[NIL] = 0; }
  __syncthreads();
  // pass-1 list ranking: dsv -> suffix length (pos smaller <=> dsv larger)
#pragma unroll 1
  for (int it = 0; it < 13; ++it) {
    unsigned short nn[16]; short nd[16];
#pragma unroll
    for (int k = 0; k < 16; ++k) { nn[k] = nxt[rn[k]]; nd[k] = dsv[rn[k]]; }
    __syncthreads();
#pragma unroll
    for (int k = 0; k < 16; ++k) {
      int a = tid + k * 1024;
      rd[k] += nd[k];
      rn[k] = nn[k];
      nxt[a] = rn[k]; dsv[a] = (short)rd[k];
    }
    __syncthreads();
  }
  // orientation: par[v] = u iff arc u->v earlier than v->u (dsv larger)
#pragma unroll
  for (int k = 0; k < 16; ++k) if (validm & (1 << k)) {
    int a = tid + k * 1024;
    int u = a >> 2, d = a & 3;
    int v = u + ((d == 0) ? -64 : (d == 1) ? -1 : (d == 2) ? 1 : 64);
    int rb = v * 4 + (3 - d);
    if (rd[k] > (int)dsv[rb]) par[v] = u;
  }
  __syncthreads();
  // pass-2 build: same next pointers, weights +1 (down) / -1 (up)
#pragma unroll
  for (int k = 0; k < 16; ++k) {
    int a = tid + k * 1024;
    int u = a >> 2, d = a & 3;
    unsigned short nx = NIL; short dv = 0;
    if (validm & (1 << k)) {
      int v = u + ((d == 0) ? -64 : (d == 1) ? -1 : (d == 2) ? 1 : 64);
      int cv = v & 63, rv = v >> 6;
      int mv = 0;
      if (rv > 0  && flagD[v - 64]) mv |= 1;
      if (cv > 0  && flagR[v - 1])  mv |= 2;
      if (cv < 63 && flagR[v])      mv |= 4;
      if (rv < 63 && flagD[v])      mv |= 8;
      int din = 3 - d;
      int hi = mv >> (din + 1);
      int dn = hi ? (din + __ffs(hi)) : (__ffs(mv) - 1);
      int nxv = v * 4 + dn;
      int m0 = (flagR[0] ? 4 : 0) | (flagD[0] ? 8 : 0);
      int a0 = __ffs(m0) - 1;
      if (v == 0 && nxv == a0) nxv = NIL;
      nx = (unsigned short)nxv;
      dv = (par[v] == u) ? (short)1 : (short)-1;
    }
    nxt[a] = nx; dsv[a] = dv;
    rn[k] = nx; rd[k] = dv;
  }
  __syncthreads();
  // pass-2 weighted ranking: dsv -> suffix sum S(a)
#pragma unroll 1
  for (int it = 0; it < 13; ++it) {
    unsigned short nn[16]; short nd[16];
#pragma unroll
    for (int k = 0; k < 16; ++k) { nn[k] = nxt[rn[k]]; nd[k] = dsv[rn[k]]; }
    __syncthreads();
#pragma unroll
    for (int k = 0; k < 16; ++k) {
      int a = tid + k * 1024;
      rd[k] += nd[k];
      rn[k] = nn[k];
      nxt[a] = rn[k]; dsv[a] = (short)rd[k];
    }
    __syncthreads();
  }
  // depth: dep[v] = 1 - S(par->v)
#pragma unroll
  for (int k = 0; k < 16; ++k) if (validm & (1 << k)) {
    int a = tid + k * 1024;
    int u = a >> 2, d = a & 3;
    int v = u + ((d == 0) ? -64 : (d == 1) ? -1 : (d == 2) ? 1 : 64);
    if (par[v] == u) dep[v] = 1 - rd[k];
  }
  __syncthreads();
  // ---- max depth ----
  int md = 0;
  for (int k = 0; k < 4; ++k) md = max(md, dep[tid + k * 1024]);
#pragma unroll
  for (int off = 32; off; off >>= 1) md = max(md, __shfl_xor(md, off));
  if ((tid & 63) == 0) wred[tid >> 6] = md;
  __syncthreads();
  if (tid == 0) {
    int m = 0;
    for (int i = 0; i < 16; ++i) m = max(m, wred[i]);
    wred[0] = m;
  }
  __syncthreads();
  int maxd = wred[0];
  __syncthreads();
  // ---- histogram + exclusive prefix over depth buckets (cnt/offs overlay dead nxt/dsv) ----
  int* cnt  = pool;
  int* offs = pool + 4096;
  for (int k = 0; k < 4; ++k) cnt[tid + k * 1024] = 0;
  __syncthreads();
  for (int k = 0; k < 4; ++k) atomicAdd(&cnt[dep[tid + k * 1024]], 1);
  __syncthreads();
  int base4 = tid * 4;
  int c0 = cnt[base4], c1 = cnt[base4 + 1], c2 = cnt[base4 + 2], c3 = cnt[base4 + 3];
  int tsum = c0 + c1 + c2 + c3;
  int lane = tid & 63, wid = tid >> 6;
  int iv = tsum;
  for (int off = 1; off < 64; off <<= 1) {
    int n = __shfl_up(iv, off);
    if (lane >= off) iv += n;
  }
  if (lane == 63) wred[wid] = iv;
  __syncthreads();
  if (tid == 0) {
    int acc = 0;
    for (int i = 0; i < 16; ++i) { int t = wred[i]; wred[i] = acc; acc += t; }
  }
  __syncthreads();
  int excl = iv - tsum + wred[wid];
  offs[base4]     = excl;
  offs[base4 + 1] = excl + c0;
  offs[base4 + 2] = excl + c0 + c1;
  offs[base4 + 3] = excl + c0 + c1 + c2;
  __syncthreads();
  for (int idx = tid; idx <= maxd; idx += 1024) levs_g[b * LSP + idx] = offs[idx];
  if (tid == 0) {
    levs_g[b * LSP + maxd + 1] = 4096;
    levs_g[b * LSP + 4098] = maxd + 1;
  }
  __syncthreads();   // levs_g copy must finish reading offs before scatter mutates it
  // ---- scatter nodes by level: node|childmask and parent node, by position ----
  for (int k = 0; k < 4; ++k) {
    int v2 = tid + k * 1024;
    int pos = atomicAdd(&offs[dep[v2]], 1);
    int c = v2 & 63, r = v2 >> 6;
    unsigned msk = 0;
    if (r > 0  && par[v2 - 64] == v2) msk |= 1;
    if (c > 0  && par[v2 - 1]  == v2) msk |= 2;
    if (c < 63 && par[v2 + 1]  == v2) msk |= 4;
    if (r < 63 && par[v2 + 64] == v2) msk |= 8;
    levn16_g[b * 4096 + pos] = (unsigned short)(v2 | (msk << 12));
    parn16_g[b * 4096 + pos] = (unsigned short)par[v2];
  }
}

// ---------------- single-wave LDS-resident tree scan (no barriers in level loops) ----------------
// 512 blocks x 64 threads; block -> (batch, 4-channel group) via XCD-aware swizzle.
// LDS: pair[node][ch][{bl,el}] 128KB + packed topo u32 16KB + lvs u16 8KB = 152KB.
__global__ __launch_bounds__(64) void scan_kernel(
    float* __restrict__ buf, const float* __restrict__ ew,
    const unsigned short* __restrict__ levn16_g,
    const unsigned short* __restrict__ parn16_g,
    const int* __restrict__ levs_g) {
  __shared__ float pr[32768];            // [node][4ch][2] = node*8 + ch*2 (+1 el)
  __shared__ unsigned int topo[4096];    // levn16 | parn16<<16, by position
  __shared__ unsigned short lvs[4104];
  int bid = blockIdx.x;
  int b = bid >> 6;
  // XCD swizzle: 4 blocks covering one 16-ch cacheline group share bid mod 16
  int group = (bid & 7) | (((bid >> 3) & 1) << 3);   // 0..15
  int within = (bid >> 4) & 3;                       // 0..3
  int cg = group * 4 + within;                       // channel-group 0..63 (4 ch each)
  int lane = threadIdx.x;
  int nlev = levs_g[b * LSP + 4098];
  size_t base = (size_t)b * 4096;
  // ---- stage ----
  const float4* buf4 = reinterpret_cast<const float4*>(buf);
  const float4* ew4  = reinterpret_cast<const float4*>(ew);
  float4* pr4 = reinterpret_cast<float4*>(pr);
  for (int n = lane; n < 4096; n += 64) {
    float4 bv = buf4[(base + n) * 64 + cg];
    float4 evv = ew4[(base + n) * 64 + cg];
    pr4[n * 2]     = make_float4(bv.x, evv.x, bv.y, evv.y);
    pr4[n * 2 + 1] = make_float4(bv.z, evv.z, bv.w, evv.w);
  }
  const unsigned int* lv32 = reinterpret_cast<const unsigned int*>(levn16_g + b * 4096);
  const unsigned int* pn32 = reinterpret_cast<const unsigned int*>(parn16_g + b * 4096);
  for (int i2 = lane; i2 < 2048; i2 += 64) {
    unsigned int a = lv32[i2], p = pn32[i2];
    topo[2 * i2]     = (a & 0xFFFFu) | (p << 16);
    topo[2 * i2 + 1] = (a >> 16) | (p & 0xFFFF0000u);
  }
  for (int i = lane; i <= nlev; i += 64) lvs[i] = (unsigned short)levs_g[b * LSP + i];
  __syncthreads();
  int ch2 = (lane & 3) * 2;        // float offset of {bl} within pair row
  int slot = lane >> 2;            // 0..15
  const float2* pr2 = reinterpret_cast<const float2*>(pr);
  // ---- up: parent gathers children via childmask (order N,W,E,S) ----
  {
    int s = lvs[nlev - 2], e = lvs[nlev - 1];
    int jn = s + slot;
    unsigned int pkn = topo[jn & 4095];
    for (int lev = nlev - 2; lev >= 0; --lev) {
      int ce = e;
      int j = jn;
      unsigned int pk = pkn;
      if (lev > 0) {                       // prefetch next level
        e = s; s = lvs[lev - 1];
        jn = s + slot;
        pkn = topo[jn & 4095];
      }
      bool first = true;
      while (j < ce) {
        if (!first) pk = topo[j];
        first = false;
        int p = pk & 4095;
        unsigned msk = (pk >> 12) & 15u;
        float acc = pr[p * 8 + ch2];
        if (msk & 1) { int u = p - 64; float2 cp = pr2[u * 4 + (ch2 >> 1)]; acc += cp.y * cp.x; }
        if (msk & 2) { int u = p - 1;  float2 cp = pr2[u * 4 + (ch2 >> 1)]; acc += cp.y * cp.x; }
        if (msk & 4) { int u = p + 1;  float2 cp = pr2[u * 4 + (ch2 >> 1)]; acc += cp.y * cp.x; }
        if (msk & 8) { int u = p + 64; float2 cp = pr2[u * 4 + (ch2 >> 1)]; acc += cp.y * cp.x; }
        pr[p * 8 + ch2] = acc;
        j += 16;
      }
      __builtin_amdgcn_wave_barrier();     // pin compile-time ordering between levels
    }
  }
  __builtin_amdgcn_wave_barrier();
  // ---- down: out[v] = up[v] + w*(out[p] - w*up[v]) ----
  if (nlev > 1) {
    int s = lvs[1], e = lvs[2];
    int jn = s + slot;
    unsigned int pkn = topo[jn & 4095];
    for (int lev = 1; lev < nlev; ++lev) {
      int cs = s, ce = e;
      int j = jn;
      unsigned int pk = pkn;
      if (lev + 1 < nlev) {
        s = e; e = lvs[lev + 2];
        jn = s + slot;
        pkn = topo[jn & 4095];
      }
      bool first = true;
      while (j < ce) {
        if (!first) pk = topo[j];
        first = false;
        int v = pk & 4095;
        int p = (pk >> 16) & 4095;
        float2 self = pr2[v * 4 + (ch2 >> 1)];   // {bl, el}
        float pb = pr[p * 8 + ch2];
        float w = self.y, uv = self.x;
        pr[v * 8 + ch2] = uv + w * (pb - w * uv);
        j += 16;
      }
      __builtin_amdgcn_wave_barrier();
      (void)cs;
    }
  }
  __syncthreads();
  // ---- write back ----
  float4* bufw = reinterpret_cast<float4*>(buf);
  for (int n = lane; n < 4096; n += 64) {
    float4 p0 = pr4[n * 2];
    float4 p1 = pr4[n * 2 + 1];
    bufw[(base + n) * 64 + cg] = make_float4(p0.x, p0.z, p1.x, p1.z);
  }
}

// ---------------- post-scan: LN(d=256) -> *Cs + ds*xs -> LN -> *z ----------------
__global__ __launch_bounds__(256) void post_kernel(
    const float* __restrict__ buf, const float* __restrict__ Cs,
    const float* __restrict__ xs, const float* __restrict__ ds,
    const float* __restrict__ hng, const float* __restrict__ hnb,
    const float* __restrict__ ong, const float* __restrict__ onb,
    float* __restrict__ zya) {
  int m = blockIdx.x, d = threadIdx.x;
  size_t idx = (size_t)m * 256 + d;
  float fo = buf[idx];
  float mu = block_sum256(fo) * (1.f / 256.f);
  float dv = fo - mu;
  float var = block_sum256(dv * dv) * (1.f / 256.f);
  float ho = dv * (1.0f / sqrtf(var + 1e-5f)) * hng[d] + hnb[d];
  float y = ho * Cs[m] + ds[d] * xs[idx];
  float mu2 = block_sum256(y) * (1.f / 256.f);
  float dy = y - mu2;
  float var2 = block_sum256(dy * dy) * (1.f / 256.f);
  float y2 = dy * (1.0f / sqrtf(var2 + 1e-5f)) * ong[d] + onb[d];
  zya[idx] = y2 * zya[idx];     // ya = y * z (in place over z)
}

// ---------------- launcher ----------------
extern "C" void kernel_launch(void* const* d_in, const int* in_sizes, int n_in,
                              void* d_out, int out_size, void* d_ws, size_t ws_size,
                              hipStream_t stream) {
  (void)in_sizes; (void)n_in; (void)out_size; (void)ws_size;
  const float* x      = (const float*)d_in[0];
  const float* ln1g   = (const float*)d_in[1];
  const float* ln1b   = (const float*)d_in[2];
  const float* ln2g   = (const float*)d_in[3];
  const float* ln2b   = (const float*)d_in[4];
  const float* w_in   = (const float*)d_in[5];
  const float* conv_w = (const float*)d_in[6];
  const float* xw     = (const float*)d_in[7];
  const float* dtw    = (const float*)d_in[8];
  const float* dtb    = (const float*)d_in[9];
  const float* alogs  = (const float*)d_in[10];
  const float* dsv    = (const float*)d_in[11];
  const float* hng    = (const float*)d_in[12];
  const float* hnb    = (const float*)d_in[13];
  const float* ong    = (const float*)d_in[14];
  const float* onb    = (const float*)d_in[15];
  const float* w_out  = (const float*)d_in[16];
  const float* mw1    = (const float*)d_in[17];
  const float* mb1    = (const float*)d_in[18];
  const float* mw2    = (const float*)d_in[19];
  const float* mb2    = (const float*)d_in[20];

  char* ws = (char*)d_ws;
  float* h    = (float*)(ws + 0);            // 16MB (h, later x1)
  float* z    = (float*)(ws + 16777216);     // 33.5MB (z, later ya in-place)
  float* xcp  = (float*)(ws + 50331648);     // 33.5MB (xc_pre, later h2)
  float* xs   = (float*)(ws + 83886080);     // 33.5MB
  float* dA   = (float*)(ws + 117440512);    // 33.5MB
  float* feat = (float*)(ws + 150994944);    // 33.5MB (feat -> up/out buf)
  float* Cs   = (float*)(ws + 184549376);
  float* ssq  = (float*)(ws + 184680448);
  float* wr   = (float*)(ws + 184811520);
  float* wd   = (float*)(ws + 184942592);
  unsigned short* levn16 = (unsigned short*)(ws + 185073664);   // 64KB
  unsigned short* parn16 = (unsigned short*)(ws + 185204736);   // 64KB
  int*   levs = (int*)(ws + 185335808);
  float* midg = xs;      // 67MB spans xs+dA (both dead by then)
  float* x1   = h;
  float* h2   = xcp;

  ln128_kernel<<<MROWS / 4, 256, 0, stream>>>(x, ln1g, ln1b, h, 1e-6f);
  gemm_kernel<1><<<dim3(8, 512), 256, 0, stream>>>(h, w_in, xcp, z, nullptr, nullptr,
                                                   MROWS, 512, 128);
  convfeat_kernel<<<MROWS, 256, 0, stream>>>(xcp, conv_w, xw, dtw, dtb, alogs,
                                             xs, dA, feat, Cs, ssq);
  gridw_kernel<<<MROWS, 256, 0, stream>>>(xs, ssq, wr, wd);
  mst_kernel<<<NB, 1024, 0, stream>>>(wr, wd, levn16, parn16, levs);
  scan_kernel<<<512, 64, 0, stream>>>(feat, dA, levn16, parn16, levs);
  post_kernel<<<MROWS, 256, 0, stream>>>(feat, Cs, xs, dsv, hng, hnb, ong, onb, z);
  gemm_kernel<2><<<dim3(2, 512), 256, 0, stream>>>(z, w_out, x1, nullptr, nullptr, x,
                                                   MROWS, 128, 256);
  ln128_kernel<<<MROWS / 4, 256, 0, stream>>>(x1, ln2g, ln2b, h2, 1e-6f);
  gemm_kernel<3><<<dim3(8, 512), 256, 0, stream>>>(h2, mw1, midg, nullptr, mb1, nullptr,
                                                   MROWS, 512, 128);
  gemm_kernel<4><<<dim3(2, 512), 256, 0, stream>>>(midg, mw2, (float*)d_out, nullptr,
                                                   mb2, x1, MROWS, 128, 512);
}

// Round 10
// 974.111 us; speedup vs baseline: 7.0541x; 1.0237x over previous
//
#include <hip/hip_runtime.h>
#include <hip/hip_bf16.h>
#include <cstdint>

#define BIGF 1e30f
constexpr int LB   = 4096;           // L = H*W
constexpr int NB   = 8;              // batch
constexpr int MROWS = NB * LB;       // 32768 pixel rows
constexpr int LSP  = 4104;           // level-start stride per batch

// ---------------- helpers ----------------
__device__ __forceinline__ float warp_sum(float v) {
#pragma unroll
  for (int off = 32; off; off >>= 1) v += __shfl_xor(v, off);
  return v;
}

__device__ __forceinline__ float block_sum256(float v) {
  __shared__ float sm[4];
  v = warp_sum(v);
  __syncthreads();
  if ((threadIdx.x & 63) == 0) sm[threadIdx.x >> 6] = v;
  __syncthreads();
  return sm[0] + sm[1] + sm[2] + sm[3];
}

// ---------------- LayerNorm over last dim 128 ----------------
__global__ __launch_bounds__(256) void ln128_kernel(
    const float* __restrict__ X, const float* __restrict__ g,
    const float* __restrict__ bb, float* __restrict__ O, float eps) {
  int wave = threadIdx.x >> 6, lane = threadIdx.x & 63;
  int row = blockIdx.x * 4 + wave;
  const float* xr = X + (size_t)row * 128;
  float x0 = xr[lane], x1 = xr[lane + 64];
  float mu = warp_sum(x0 + x1) * (1.0f / 128.0f);
  float d0 = x0 - mu, d1 = x1 - mu;
  float var = warp_sum(d0 * d0 + d1 * d1) * (1.0f / 128.0f);
  float s = 1.0f / sqrtf(var + eps);
  float* orow = O + (size_t)row * 128;
  orow[lane]      = d0 * s * g[lane]      + bb[lane];
  orow[lane + 64] = d1 * s * g[lane + 64] + bb[lane + 64];
}

// ---------------- generic f32 GEMM: C = A[M,K] @ W[N,K]^T, fused epilogues ----------------
template<int EPI>
__global__ __launch_bounds__(256) void gemm_kernel(
    const float* __restrict__ A, const float* __restrict__ W,
    float* __restrict__ C, float* __restrict__ C2,
    const float* __restrict__ bias, const float* __restrict__ addsrc,
    int M, int N, int K) {
  __shared__ float As[32][68];
  __shared__ float Bs[32][68];
  int t = threadIdx.x;
  int tx = t & 15, ty = t >> 4;
  int bm = blockIdx.y * 64, bn = blockIdx.x * 64;
  float acc[4][4] = {};
  for (int k0 = 0; k0 < K; k0 += 32) {
#pragma unroll
    for (int hh = 0; hh < 2; ++hh) {
      int q = t + hh * 256;
      int r = q >> 3, kc = q & 7;
      float4 a4 = reinterpret_cast<const float4*>(A + (size_t)(bm + r) * K + k0)[kc];
      float4 b4 = reinterpret_cast<const float4*>(W + (size_t)(bn + r) * K + k0)[kc];
      As[kc * 4 + 0][r] = a4.x; As[kc * 4 + 1][r] = a4.y;
      As[kc * 4 + 2][r] = a4.z; As[kc * 4 + 3][r] = a4.w;
      Bs[kc * 4 + 0][r] = b4.x; Bs[kc * 4 + 1][r] = b4.y;
      Bs[kc * 4 + 2][r] = b4.z; Bs[kc * 4 + 3][r] = b4.w;
    }
    __syncthreads();
#pragma unroll
    for (int kk = 0; kk < 32; ++kk) {
      float4 av = *reinterpret_cast<const float4*>(&As[kk][ty * 4]);
      float4 bv = *reinterpret_cast<const float4*>(&Bs[kk][tx * 4]);
      float aa[4] = {av.x, av.y, av.z, av.w};
      float bbv[4] = {bv.x, bv.y, bv.z, bv.w};
#pragma unroll
      for (int i = 0; i < 4; ++i)
#pragma unroll
        for (int j = 0; j < 4; ++j) acc[i][j] += aa[i] * bbv[j];
    }
    __syncthreads();
  }
#pragma unroll
  for (int i = 0; i < 4; ++i) {
    int m = bm + ty * 4 + i;
#pragma unroll
    for (int j = 0; j < 4; ++j) {
      int n = bn + tx * 4 + j;
      float v = acc[i][j];
      if (EPI == 1) {
        if (n < 256) C[(size_t)m * 256 + n] = v;
        else C2[(size_t)m * 256 + (n - 256)] = v / (1.0f + expf(-v));
      } else if (EPI == 2) {
        C[(size_t)m * N + n] = v + addsrc[(size_t)m * N + n];
      } else if (EPI == 3) {
        float u = v + bias[n];
        C[(size_t)m * N + n] =
            0.5f * u * (1.0f + tanhf(0.7978845608028654f * (u + 0.044715f * u * u * u)));
      } else if (EPI == 4) {
        C[(size_t)m * N + n] = v + bias[n] + addsrc[(size_t)m * N + n];
      }
    }
  }
}

// ---------------- depthwise conv3x3 + silu + x_dbl/dts/deltaA/feat ----------------
// feat/dA written TRANSPOSED: [b][group=d>>2][node][d&3]
__global__ __launch_bounds__(256) void convfeat_kernel(
    const float* __restrict__ xcpre, const float* __restrict__ cw,
    const float* __restrict__ xw, const float* __restrict__ dtw,
    const float* __restrict__ dtb, const float* __restrict__ alogs,
    float* __restrict__ xs, float* __restrict__ dAt, float* __restrict__ featt,
    float* __restrict__ Cs, float* __restrict__ ssq) {
  int m = blockIdx.x;
  int d = threadIdx.x;
  int l = m & (LB - 1), b = m >> 12;
  int r = l >> 6, c = l & 63;
  float acc = 0.f;
#pragma unroll
  for (int ky = 0; ky < 3; ++ky) {
    int rr = r + ky - 1;
    if (rr < 0 || rr > 63) continue;
#pragma unroll
    for (int kx = 0; kx < 3; ++kx) {
      int cc = c + kx - 1;
      if (cc < 0 || cc > 63) continue;
      int ml = (b << 12) + (rr << 6) + cc;
      acc += xcpre[(size_t)ml * 256 + d] * cw[d * 9 + ky * 3 + kx];
    }
  }
  float xv = acc / (1.0f + expf(-acc));        // silu
  xs[(size_t)m * 256 + d] = xv;
  float p[11];
#pragma unroll
  for (int i = 0; i < 10; ++i) p[i] = xv * xw[i * 256 + d];
  p[10] = xv * xv;
  __shared__ float sm[4][11];
#pragma unroll
  for (int i = 0; i < 11; ++i) p[i] = warp_sum(p[i]);
  int wv = d >> 6;
  if ((d & 63) == 0) {
    for (int i = 0; i < 11; ++i) sm[wv][i] = p[i];
  }
  __syncthreads();
  float red[11];
#pragma unroll
  for (int i = 0; i < 11; ++i) red[i] = sm[0][i] + sm[1][i] + sm[2][i] + sm[3][i];
  float xdt = dtb[d];
#pragma unroll
  for (int rr2 = 0; rr2 < 8; ++rr2) xdt += red[rr2] * dtw[d * 8 + rr2];
  float sp = fmaxf(xdt, 0.f) + log1pf(expf(-fabsf(xdt)));   // softplus
  float As_ = -expf(alogs[d]);
  size_t tidx = ((size_t)(b * 64 + (d >> 2)) * 4096 + l) * 4 + (d & 3);
  dAt[tidx]   = expf(sp * As_);
  featt[tidx] = sp * red[8] * xv;
  if (d == 0) { Cs[m] = red[9]; ssq[m] = red[10]; }
}

// ---------------- grid edge weights wr/wd ----------------
__global__ __launch_bounds__(256) void gridw_kernel(
    const float* __restrict__ xs, const float* __restrict__ ssq,
    float* __restrict__ wrg, float* __restrict__ wdg) {
  int m = blockIdx.x, d = threadIdx.x;
  int l = m & (LB - 1);
  int r = l >> 6, c = l & 63;
  float a = xs[(size_t)m * 256 + d];
  float br = (c < 63) ? xs[(size_t)(m + 1) * 256 + d] : 0.f;
  float bd = (r < 63) ? xs[(size_t)(m + 64) * 256 + d] : 0.f;
  float s1 = warp_sum(a * br);
  float s2 = warp_sum(a * bd);
  __shared__ float sm[4][2];
  int wv = d >> 6;
  if ((d & 63) == 0) { sm[wv][0] = s1; sm[wv][1] = s2; }
  __syncthreads();
  if (d == 0) {
    float dotr = sm[0][0] + sm[1][0] + sm[2][0] + sm[3][0];
    float dotd = sm[0][1] + sm[1][1] + sm[2][1] + sm[3][1];
    float na = sqrtf(ssq[m]);
    float wrv = BIGF, wdv = BIGF;
    if (c < 63) { float den = fmaxf(na * sqrtf(ssq[m + 1]), 1e-8f);  wrv = expf(-(dotr / den)); }
    if (r < 63) { float den = fmaxf(na * sqrtf(ssq[m + 64]), 1e-8f); wdv = expf(-(dotd / den)); }
    wrg[m] = wrv; wdg[m] = wdv;
  }
}

// ---------------- Boruvka MST + Euler-tour rooting (O(log V)) + levels ----------------
// Outputs position-space arrays for the scan:
//   levn16[pos] = node | childmask<<12   (mask bits: 1=N,2=W,4=E,8=S)
//   parn16[pos] = par[node]
// Directions: 0=N(-64), 1=W(-1), 2=E(+1), 3=S(+64); rev(d)=3-d.
__global__ __launch_bounds__(1024) void mst_kernel(
    const float* __restrict__ wr_g, const float* __restrict__ wd_g,
    unsigned short* __restrict__ levn16_g, unsigned short* __restrict__ parn16_g,
    int* __restrict__ levs_g) {
  __shared__ int pool[24592];          // 98.4 KB, phase-overlaid
  __shared__ unsigned char flagR[4096];
  __shared__ unsigned char flagD[4096];
  __shared__ int ncomp_s;
  __shared__ int wred[16];
  int b = blockIdx.x, tid = threadIdx.x;
  // ---- phase A layout (Boruvka) ----
  float* wrs = (float*)pool;
  float* wds = (float*)(pool + 4096);
  int* comp = pool + 8192;
  int* lnk  = pool + 12288;
  unsigned int* bestw = (unsigned int*)(pool + 16384);
  int* beste = pool + 20480;
  const float* wrb = wr_g + b * 4096;
  const float* wdb = wd_g + b * 4096;
  for (int k = 0; k < 4; ++k) {
    int i = tid + k * 1024;
    wrs[i] = wrb[i]; wds[i] = wdb[i];
    comp[i] = i; flagR[i] = 0; flagD[i] = 0;
  }
  __syncthreads();
  for (int phase = 0; phase < 13; ++phase) {
    for (int k = 0; k < 4; ++k) {
      int c = tid + k * 1024;
      bestw[c] = 0xFFFFFFFFu; beste[c] = 0x7FFFFFFF; lnk[c] = c;
    }
    if (tid == 0) ncomp_s = 0;
    __syncthreads();
    // pass A: per-component min weight
    for (int k = 0; k < 8; ++k) {
      int e = tid + k * 1024;
      int v = e & 4095;
      bool isR = e < 4096;
      int c = v & 63, r = v >> 6;
      bool valid = isR ? (c < 63) : (r < 63);
      if (valid) {
        int u = isR ? v + 1 : v + 64;
        int ca = comp[v], cb = comp[u];
        if (ca != cb) {
          unsigned wbits = __float_as_uint(isR ? wrs[v] : wds[v]);
          atomicMin(&bestw[ca], wbits);
          atomicMin(&bestw[cb], wbits);
        }
      }
    }
    __syncthreads();
    // pass B: min edge id among tied-min weights
    for (int k = 0; k < 8; ++k) {
      int e = tid + k * 1024;
      int v = e & 4095;
      bool isR = e < 4096;
      int c = v & 63, r = v >> 6;
      bool valid = isR ? (c < 63) : (r < 63);
      if (valid) {
        int u = isR ? v + 1 : v + 64;
        int ca = comp[v], cb = comp[u];
        if (ca != cb) {
          unsigned wbits = __float_as_uint(isR ? wrs[v] : wds[v]);
          if (wbits == bestw[ca]) atomicMin(&beste[ca], e);
          if (wbits == bestw[cb]) atomicMin(&beste[cb], e);
        }
      }
    }
    __syncthreads();
    // hook + flag chosen edges
    for (int k = 0; k < 4; ++k) {
      int cc = tid + k * 1024;
      int e = beste[cc];
      if (e != 0x7FFFFFFF) {
        int v = e & 4095;
        bool isR = e < 4096;
        int u = isR ? v + 1 : v + 64;
        if (isR) flagR[v] = 1; else flagD[v] = 1;
        int ca = comp[v], cb = comp[u];
        lnk[cc] = (ca == cc) ? cb : ca;
      }
    }
    __syncthreads();
    // break 2-cycles
    for (int k = 0; k < 4; ++k) {
      int cc = tid + k * 1024;
      int l = lnk[cc];
      if (l != cc && lnk[l] == cc && cc < l) lnk[cc] = cc;
    }
    __syncthreads();
    // pointer jumping
    for (int it = 0; it < 12; ++it) {
      for (int k = 0; k < 4; ++k) {
        int cc = tid + k * 1024;
        lnk[cc] = lnk[lnk[cc]];
      }
      __syncthreads();
    }
    // relabel + count roots
    for (int k = 0; k < 4; ++k) {
      int i = tid + k * 1024;
      comp[i] = lnk[comp[i]];
      if (comp[i] == i) atomicAdd(&ncomp_s, 1);
    }
    __syncthreads();
    if (ncomp_s <= 1) break;
    __syncthreads();
  }
  // ---- phase B layout (Euler tour; overlays dead Boruvka arrays) ----
  unsigned short* nxt = (unsigned short*)pool;        // [16400]
  short*          dsv = (short*)(pool + 8200);        // [16400]
  int* par = pool + 16400;                            // [4096]
  int* dep = pool + 20496;                            // [4096]
  const int NIL = 16384;
  unsigned short rn[16];
  int rd[16];
  int validm = 0;
  // pass-1 build: next pointers + unit weights; init par/dep
  for (int k = 0; k < 4; ++k) { int i = tid + k * 1024; par[i] = 0; dep[i] = 0; }
#pragma unroll
  for (int k = 0; k < 16; ++k) {
    int a = tid + k * 1024;
    int u = a >> 2, d = a & 3;
    int c = u & 63, r = u >> 6;
    int mu = 0;
    if (r > 0  && flagD[u - 64]) mu |= 1;
    if (c > 0  && flagR[u - 1])  mu |= 2;
    if (c < 63 && flagR[u])      mu |= 4;
    if (r < 63 && flagD[u])      mu |= 8;
    unsigned short nx = NIL; short dv = 0;
    if (mu & (1 << d)) {
      validm |= 1 << k;
      int v = u + ((d == 0) ? -64 : (d == 1) ? -1 : (d == 2) ? 1 : 64);
      int cv = v & 63, rv = v >> 6;
      int mv = 0;
      if (rv > 0  && flagD[v - 64]) mv |= 1;
      if (cv > 0  && flagR[v - 1])  mv |= 2;
      if (cv < 63 && flagR[v])      mv |= 4;
      if (rv < 63 && flagD[v])      mv |= 8;
      int din = 3 - d;
      int hi = mv >> (din + 1);
      int dn = hi ? (din + __ffs(hi)) : (__ffs(mv) - 1);
      int nxv = v * 4 + dn;
      int m0 = (flagR[0] ? 4 : 0) | (flagD[0] ? 8 : 0);
      int a0 = __ffs(m0) - 1;                 // start arc (root node 0)
      if (v == 0 && nxv == a0) nxv = NIL;     // break circuit before start
      nx = (unsigned short)nxv;
      dv = 1;
    }
    nxt[a] = nx; dsv[a] = dv;
    rn[k] = nx; rd[k] = dv;
  }
  if (tid == 0) { nxt[NIL] = NIL; dsv[NIL] = 0; }
  __syncthreads();
  // pass-1 list ranking: dsv -> suffix length (pos smaller <=> dsv larger)
#pragma unroll 1
  for (int it = 0; it < 13; ++it) {
    unsigned short nn[16]; short nd[16];
#pragma unroll
    for (int k = 0; k < 16; ++k) { nn[k] = nxt[rn[k]]; nd[k] = dsv[rn[k]]; }
    __syncthreads();
#pragma unroll
    for (int k = 0; k < 16; ++k) {
      int a = tid + k * 1024;
      rd[k] += nd[k];
      rn[k] = nn[k];
      nxt[a] = rn[k]; dsv[a] = (short)rd[k];
    }
    __syncthreads();
  }
  // orientation: par[v] = u iff arc u->v earlier than v->u (dsv larger)
#pragma unroll
  for (int k = 0; k < 16; ++k) if (validm & (1 << k)) {
    int a = tid + k * 1024;
    int u = a >> 2, d = a & 3;
    int v = u + ((d == 0) ? -64 : (d == 1) ? -1 : (d == 2) ? 1 : 64);
    int rb = v * 4 + (3 - d);
    if (rd[k] > (int)dsv[rb]) par[v] = u;
  }
  __syncthreads();
  // pass-2 build: same next pointers, weights +1 (down) / -1 (up)
#pragma unroll
  for (int k = 0; k < 16; ++k) {
    int a = tid + k * 1024;
    int u = a >> 2, d = a & 3;
    unsigned short nx = NIL; short dv = 0;
    if (validm & (1 << k)) {
      int v = u + ((d == 0) ? -64 : (d == 1) ? -1 : (d == 2) ? 1 : 64);
      int cv = v & 63, rv = v >> 6;
      int mv = 0;
      if (rv > 0  && flagD[v - 64]) mv |= 1;
      if (cv > 0  && flagR[v - 1])  mv |= 2;
      if (cv < 63 && flagR[v])      mv |= 4;
      if (rv < 63 && flagD[v])      mv |= 8;
      int din = 3 - d;
      int hi = mv >> (din + 1);
      int dn = hi ? (din + __ffs(hi)) : (__ffs(mv) - 1);
      int nxv = v * 4 + dn;
      int m0 = (flagR[0] ? 4 : 0) | (flagD[0] ? 8 : 0);
      int a0 = __ffs(m0) - 1;
      if (v == 0 && nxv == a0) nxv = NIL;
      nx = (unsigned short)nxv;
      dv = (par[v] == u) ? (short)1 : (short)-1;
    }
    nxt[a] = nx; dsv[a] = dv;
    rn[k] = nx; rd[k] = dv;
  }
  __syncthreads();
  // pass-2 weighted ranking: dsv -> suffix sum S(a)
#pragma unroll 1
  for (int it = 0; it < 13; ++it) {
    unsigned short nn[16]; short nd[16];
#pragma unroll
    for (int k = 0; k < 16; ++k) { nn[k] = nxt[rn[k]]; nd[k] = dsv[rn[k]]; }
    __syncthreads();
#pragma unroll
    for (int k = 0; k < 16; ++k) {
      int a = tid + k * 1024;
      rd[k] += nd[k];
      rn[k] = nn[k];
      nxt[a] = rn[k]; dsv[a] = (short)rd[k];
    }
    __syncthreads();
  }
  // depth: dep[v] = 1 - S(par->v)
#pragma unroll
  for (int k = 0; k < 16; ++k) if (validm & (1 << k)) {
    int a = tid + k * 1024;
    int u = a >> 2, d = a & 3;
    int v = u + ((d == 0) ? -64 : (d == 1) ? -1 : (d == 2) ? 1 : 64);
    if (par[v] == u) dep[v] = 1 - rd[k];
  }
  __syncthreads();
  // ---- max depth ----
  int md = 0;
  for (int k = 0; k < 4; ++k) md = max(md, dep[tid + k * 1024]);
#pragma unroll
  for (int off = 32; off; off >>= 1) md = max(md, __shfl_xor(md, off));
  if ((tid & 63) == 0) wred[tid >> 6] = md;
  __syncthreads();
  if (tid == 0) {
    int m = 0;
    for (int i = 0; i < 16; ++i) m = max(m, wred[i]);
    wred[0] = m;
  }
  __syncthreads();
  int maxd = wred[0];
  __syncthreads();
  // ---- histogram + exclusive prefix over depth buckets (cnt/offs overlay dead nxt/dsv) ----
  int* cnt  = pool;
  int* offs = pool + 4096;
  for (int k = 0; k < 4; ++k) cnt[tid + k * 1024] = 0;
  __syncthreads();
  for (int k = 0; k < 4; ++k) atomicAdd(&cnt[dep[tid + k * 1024]], 1);
  __syncthreads();
  int base4 = tid * 4;
  int c0 = cnt[base4], c1 = cnt[base4 + 1], c2 = cnt[base4 + 2], c3 = cnt[base4 + 3];
  int tsum = c0 + c1 + c2 + c3;
  int lane = tid & 63, wid = tid >> 6;
  int iv = tsum;
  for (int off = 1; off < 64; off <<= 1) {
    int n = __shfl_up(iv, off);
    if (lane >= off) iv += n;
  }
  if (lane == 63) wred[wid] = iv;
  __syncthreads();
  if (tid == 0) {
    int acc = 0;
    for (int i = 0; i < 16; ++i) { int t = wred[i]; wred[i] = acc; acc += t; }
  }
  __syncthreads();
  int excl = iv - tsum + wred[wid];
  offs[base4]     = excl;
  offs[base4 + 1] = excl + c0;
  offs[base4 + 2] = excl + c0 + c1;
  offs[base4 + 3] = excl + c0 + c1 + c2;
  __syncthreads();
  for (int idx = tid; idx <= maxd; idx += 1024) levs_g[b * LSP + idx] = offs[idx];
  if (tid == 0) {
    levs_g[b * LSP + maxd + 1] = 4096;
    levs_g[b * LSP + 4098] = maxd + 1;
  }
  __syncthreads();   // levs_g copy must finish reading offs before scatter mutates it
  // ---- scatter nodes by level: node|childmask and parent node, by position ----
  for (int k = 0; k < 4; ++k) {
    int v2 = tid + k * 1024;
    int pos = atomicAdd(&offs[dep[v2]], 1);
    int c = v2 & 63, r = v2 >> 6;
    unsigned msk = 0;
    if (r > 0  && par[v2 - 64] == v2) msk |= 1;
    if (c > 0  && par[v2 - 1]  == v2) msk |= 2;
    if (c < 63 && par[v2 + 1]  == v2) msk |= 4;
    if (r < 63 && par[v2 + 64] == v2) msk |= 8;
    levn16_g[b * 4096 + pos] = (unsigned short)(v2 | (msk << 12));
    parn16_g[b * 4096 + pos] = (unsigned short)par[v2];
  }
}

// ---------------- single-wave LDS-resident tree scan, transposed coalesced I/O ----------------
// 512 blocks x 64 threads; block bid -> (batch bid>>6, channel-group bid&63).
// featt/dAt layout: [(b*64+cg)*4096 + node] float4 (4 ch) -> contiguous 64KB per block.
// LDS planes: pr2[ch*4097 + node] = {bl, el}; plane stride 4097 float2 breaks bank alignment.
__global__ __launch_bounds__(64) void scan_kernel(
    float* __restrict__ buft, const float* __restrict__ ewt,
    const unsigned short* __restrict__ levn16_g,
    const unsigned short* __restrict__ parn16_g,
    const int* __restrict__ levs_g) {
  __shared__ float pr[32776];            // 4 planes x 4097 float2
  __shared__ unsigned int topo[4096];    // levn16 | parn16<<16, by position
  __shared__ unsigned short lvs[4104];
  int bid = blockIdx.x;
  int b = bid >> 6;
  int cg = bid & 63;
  int lane = threadIdx.x;
  int nlev = levs_g[b * LSP + 4098];
  size_t tbase = (size_t)(b * 64 + cg) * 4096;
  float2* pr2 = reinterpret_cast<float2*>(pr);
  // ---- stage (fully coalesced) ----
  const float4* bt4 = reinterpret_cast<const float4*>(buft) + tbase;
  const float4* et4 = reinterpret_cast<const float4*>(ewt) + tbase;
  for (int n = lane; n < 4096; n += 64) {
    float4 bv = bt4[n];
    float4 ev = et4[n];
    pr2[0 * 4097 + n] = make_float2(bv.x, ev.x);
    pr2[1 * 4097 + n] = make_float2(bv.y, ev.y);
    pr2[2 * 4097 + n] = make_float2(bv.z, ev.z);
    pr2[3 * 4097 + n] = make_float2(bv.w, ev.w);
  }
  const unsigned int* lv32 = reinterpret_cast<const unsigned int*>(levn16_g + b * 4096);
  const unsigned int* pn32 = reinterpret_cast<const unsigned int*>(parn16_g + b * 4096);
  for (int i2 = lane; i2 < 2048; i2 += 64) {
    unsigned int a = lv32[i2], p = pn32[i2];
    topo[2 * i2]     = (a & 0xFFFFu) | (p << 16);
    topo[2 * i2 + 1] = (a >> 16) | (p & 0xFFFF0000u);
  }
  for (int i = lane; i <= nlev; i += 64) lvs[i] = (unsigned short)levs_g[b * LSP + i];
  __syncthreads();
  int ch = lane & 3;
  int slot = lane >> 2;            // 0..15
  int cpl = ch * 4097;             // plane offset in float2
  // ---- up: parent gathers children via childmask (order N,W,E,S) ----
  {
    int s = lvs[nlev - 2], e = lvs[nlev - 1];
    int jn = s + slot;
    unsigned int pkn = topo[jn & 4095];
    for (int lev = nlev - 2; lev >= 0; --lev) {
      int ce = e;
      int j = jn;
      unsigned int pk = pkn;
      if (lev > 0) {                       // prefetch next level
        e = s; s = lvs[lev - 1];
        jn = s + slot;
        pkn = topo[jn & 4095];
      }
      bool first = true;
      while (j < ce) {
        if (!first) pk = topo[j];
        first = false;
        int p = pk & 4095;
        unsigned msk = (pk >> 12) & 15u;
        float acc = pr[(cpl + p) * 2];
        if (msk & 1) { float2 cp = pr2[cpl + p - 64]; acc += cp.y * cp.x; }
        if (msk & 2) { float2 cp = pr2[cpl + p - 1];  acc += cp.y * cp.x; }
        if (msk & 4) { float2 cp = pr2[cpl + p + 1];  acc += cp.y * cp.x; }
        if (msk & 8) { float2 cp = pr2[cpl + p + 64]; acc += cp.y * cp.x; }
        pr[(cpl + p) * 2] = acc;
        j += 16;
      }
      __builtin_amdgcn_wave_barrier();     // pin ordering between levels
    }
  }
  __builtin_amdgcn_wave_barrier();
  // ---- down: out[v] = up[v] + w*(out[p] - w*up[v]) ----
  if (nlev > 1) {
    int s = lvs[1], e = lvs[2];
    int jn = s + slot;
    unsigned int pkn = topo[jn & 4095];
    for (int lev = 1; lev < nlev; ++lev) {
      int ce = e;
      int j = jn;
      unsigned int pk = pkn;
      if (lev + 1 < nlev) {
        s = e; e = lvs[lev + 2];
        jn = s + slot;
        pkn = topo[jn & 4095];
      }
      bool first = true;
      while (j < ce) {
        if (!first) pk = topo[j];
        first = false;
        int v = pk & 4095;
        int p = (pk >> 16) & 4095;
        float2 self = pr2[cpl + v];          // {bl, el}
        float pb = pr[(cpl + p) * 2];
        float w = self.y, uv = self.x;
        pr[(cpl + v) * 2] = uv + w * (pb - w * uv);
        j += 16;
      }
      __builtin_amdgcn_wave_barrier();
    }
  }
  __syncthreads();
  // ---- write back (coalesced) ----
  float4* bw4 = reinterpret_cast<float4*>(buft) + tbase;
  for (int n = lane; n < 4096; n += 64) {
    float2 c0 = pr2[0 * 4097 + n];
    float2 c1 = pr2[1 * 4097 + n];
    float2 c2 = pr2[2 * 4097 + n];
    float2 c3 = pr2[3 * 4097 + n];
    bw4[n] = make_float4(c0.x, c1.x, c2.x, c3.x);
  }
}

// ---------------- post-scan: LN(d=256) -> *Cs + ds*xs -> LN -> *z ----------------
// buft is transposed: fo = buft[((b*64 + d/4)*4096 + l)*4 + d%4]
__global__ __launch_bounds__(256) void post_kernel(
    const float* __restrict__ buft, const float* __restrict__ Cs,
    const float* __restrict__ xs, const float* __restrict__ ds,
    const float* __restrict__ hng, const float* __restrict__ hnb,
    const float* __restrict__ ong, const float* __restrict__ onb,
    float* __restrict__ zya) {
  int m = blockIdx.x, d = threadIdx.x;
  int b = m >> 12, l = m & (LB - 1);
  size_t idx = (size_t)m * 256 + d;
  float fo = buft[((size_t)(b * 64 + (d >> 2)) * 4096 + l) * 4 + (d & 3)];
  float mu = block_sum256(fo) * (1.f / 256.f);
  float dv = fo - mu;
  float var = block_sum256(dv * dv) * (1.f / 256.f);
  float ho = dv * (1.0f / sqrtf(var + 1e-5f)) * hng[d] + hnb[d];
  float y = ho * Cs[m] + ds[d] * xs[idx];
  float mu2 = block_sum256(y) * (1.f / 256.f);
  float dy = y - mu2;
  float var2 = block_sum256(dy * dy) * (1.f / 256.f);
  float y2 = dy * (1.0f / sqrtf(var2 + 1e-5f)) * ong[d] + onb[d];
  zya[idx] = y2 * zya[idx];     // ya = y * z (in place over z)
}

// ---------------- launcher ----------------
extern "C" void kernel_launch(void* const* d_in, const int* in_sizes, int n_in,
                              void* d_out, int out_size, void* d_ws, size_t ws_size,
                              hipStream_t stream) {
  (void)in_sizes; (void)n_in; (void)out_size; (void)ws_size;
  const float* x      = (const float*)d_in[0];
  const float* ln1g   = (const float*)d_in[1];
  const float* ln1b   = (const float*)d_in[2];
  const float* ln2g   = (const float*)d_in[3];
  const float* ln2b   = (const float*)d_in[4];
  const float* w_in   = (const float*)d_in[5];
  const float* conv_w = (const float*)d_in[6];
  const float* xw     = (const float*)d_in[7];
  const float* dtw    = (const float*)d_in[8];
  const float* dtb    = (const float*)d_in[9];
  const float* alogs  = (const float*)d_in[10];
  const float* dsv    = (const float*)d_in[11];
  const float* hng    = (const float*)d_in[12];
  const float* hnb    = (const float*)d_in[13];
  const float* ong    = (const float*)d_in[14];
  const float* onb    = (const float*)d_in[15];
  const float* w_out  = (const float*)d_in[16];
  const float* mw1    = (const float*)d_in[17];
  const float* mb1    = (const float*)d_in[18];
  const float* mw2    = (const float*)d_in[19];
  const float* mb2    = (const float*)d_in[20];

  char* ws = (char*)d_ws;
  float* h    = (float*)(ws + 0);            // 16MB (h, later x1)
  float* z    = (float*)(ws + 16777216);     // 33.5MB (z, later ya in-place)
  float* xcp  = (float*)(ws + 50331648);     // 33.5MB (xc_pre, later h2)
  float* xs   = (float*)(ws + 83886080);     // 33.5MB
  float* dAt  = (float*)(ws + 117440512);    // 33.5MB transposed deltaA
  float* featt= (float*)(ws + 150994944);    // 33.5MB transposed feat -> scan buf
  float* Cs   = (float*)(ws + 184549376);
  float* ssq  = (float*)(ws + 184680448);
  float* wr   = (float*)(ws + 184811520);
  float* wd   = (float*)(ws + 184942592);
  unsigned short* levn16 = (unsigned short*)(ws + 185073664);   // 64KB
  unsigned short* parn16 = (unsigned short*)(ws + 185204736);   // 64KB
  int*   levs = (int*)(ws + 185335808);
  float* midg = xs;      // 67MB spans xs+dAt (both dead by then)
  float* x1   = h;
  float* h2   = xcp;

  ln128_kernel<<<MROWS / 4, 256, 0, stream>>>(x, ln1g, ln1b, h, 1e-6f);
  gemm_kernel<1><<<dim3(8, 512), 256, 0, stream>>>(h, w_in, xcp, z, nullptr, nullptr,
                                                   MROWS, 512, 128);
  convfeat_kernel<<<MROWS, 256, 0, stream>>>(xcp, conv_w, xw, dtw, dtb, alogs,
                                             xs, dAt, featt, Cs, ssq);
  gridw_kernel<<<MROWS, 256, 0, stream>>>(xs, ssq, wr, wd);
  mst_kernel<<<NB, 1024, 0, stream>>>(wr, wd, levn16, parn16, levs);
  scan_kernel<<<512, 64, 0, stream>>>(featt, dAt, levn16, parn16, levs);
  post_kernel<<<MROWS, 256, 0, stream>>>(featt, Cs, xs, dsv, hng, hnb, ong, onb, z);
  gemm_kernel<2><<<dim3(2, 512), 256, 0, stream>>>(z, w_out, x1, nullptr, nullptr, x,
                                                   MROWS, 128, 256);
  ln128_kernel<<<MROWS / 4, 256, 0, stream>>>(x1, ln2g, ln2b, h2, 1e-6f);
  gemm_kernel<3><<<dim3(8, 512), 256, 0, stream>>>(h2, mw1, midg, nullptr, mb1, nullptr,
                                                   MROWS, 512, 128);
  gemm_kernel<4><<<dim3(2, 512), 256, 0, stream>>>(midg, mw2, (float*)d_out, nullptr,
                                                   mb2, x1, MROWS, 128, 512);
}